// Round 3
// baseline (774.201 us; speedup 1.0000x reference)
//
#include <hip/hip_runtime.h>

typedef unsigned short u16;
typedef unsigned int u32;
typedef unsigned long long u64;

#define BB 8
#define LL 2048
#define DD 256
#define NB (BB * LL)      // 16384 rows
#define NCH 32
#define CHL (LL / NCH)    // 64
#define CAP 64

typedef __attribute__((ext_vector_type(8))) __bf16 bf16x8;
typedef __attribute__((ext_vector_type(4))) float f32x4;

__device__ __forceinline__ float b2f(u16 u) {
    union { u32 u; float f; } x; x.u = ((u32)u) << 16; return x.f;
}
__device__ __forceinline__ u16 f2b(float f) {
    union { float f; u32 u; } x; x.f = f;
    u32 r = (x.u >> 16) & 1u;
    x.u += 0x7FFFu + r;
    return (u16)(x.u >> 16);
}
__device__ __forceinline__ float sigm(float x) { return 1.f / (1.f + __expf(-x)); }

// ------------- weight transpose+cast: W[K,N] f32 -> Wt[N,K] bf16 ------------
__global__ void transpose_kernel(const float* __restrict__ W, u16* __restrict__ Wt, int K, int N) {
    int idx = blockIdx.x * 256 + threadIdx.x;
    if (idx >= K * N) return;
    int k = idx / N, n = idx - k * N;
    Wt[(size_t)n * K + k] = f2b(W[idx]);
}

// ---------------- CSR build from binary adjacency (f32, deterministic) ------
__global__ void csr_kernel(const float* __restrict__ Adj, int* __restrict__ csr,
                           int* __restrict__ cnt, float* __restrict__ deg) {
    int w = threadIdx.x >> 6, lane = threadIdx.x & 63;
    int row = blockIdx.x * 4 + w;                 // 0..NB-1
    const float* arow = Adj + (size_t)row * LL;
    int base = 0;
    for (int c = 0; c < LL / 64; ++c) {
        int j = c * 64 + lane;
        bool nz = (arow[j] != 0.f);
        u64 m = __ballot(nz);
        if (nz) {
            int pos = base + __popcll(m & ((1ull << lane) - 1ull));
            if (pos < CAP) csr[(size_t)row * CAP + pos] = j;
        }
        base += __popcll(m);
    }
    if (lane == 0) {
        cnt[row] = base < CAP ? base : CAP;
        deg[row] = (float)(base < 1 ? 1 : base);
    }
}

// ---------------- gather + mask: f32 X -> bf16 rows -------------------------
__global__ void gather_kernel(const float* __restrict__ X, const int* __restrict__ si,
                              const int* __restrict__ maskp, u16* __restrict__ out) {
    int g = blockIdx.x * 256 + threadIdx.x;       // NB*DD threads
    int d = g & (DD - 1), r = g >> 8;
    int b = r >> 11, l = r & (LL - 1);
    u16 val = 0;
    if (maskp[r]) {                                // mask is prefix: mask[r] <=> l < vc[b]
        int src = si ? si[r] : l;
        val = f2b(X[((size_t)(b << 11) + src) * DD + d]);
    }
    out[(size_t)r * DD + d] = val;
}

// ---------------- GEMM: C[M,N] = A[M,K] @ Bt[N,K]^T  (bf16 in, f32 acc) -----
// mode 0: f32 store; mode 1: bias(f32)+relu+bf16; mode 2: plain bf16
__global__ __launch_bounds__(256)
void gemm_kernel(const u16* __restrict__ A, const u16* __restrict__ Bt,
                 void* __restrict__ Cout, const float* __restrict__ bias,
                 int M, int N, int K, int mode)
{
    __shared__ __align__(16) u16 As[128 * 32];
    __shared__ __align__(16) u16 Bs[128 * 32];
    int tid = threadIdx.x;
    int lane = tid & 63;
    int w = tid >> 6, wm = w >> 1, wn = w & 1;
    int rowBase = blockIdx.x * 128, colBase = blockIdx.y * 128;

    f32x4 acc[4][4];
#pragma unroll
    for (int m = 0; m < 4; ++m)
#pragma unroll
        for (int n = 0; n < 4; ++n) acc[m][n] = (f32x4){0.f, 0.f, 0.f, 0.f};

    for (int k0 = 0; k0 < K; k0 += 32) {
        uint4 ra[2], rb[2];
#pragma unroll
        for (int rep = 0; rep < 2; ++rep) {
            int s = rep * 256 + tid;               // 16B segment id, 0..511
            int row = s >> 2, kk = (s & 3) << 3;
            ra[rep] = *(const uint4*)(A + (size_t)(rowBase + row) * K + (k0 + kk));
            rb[rep] = *(const uint4*)(Bt + (size_t)(colBase + row) * K + (k0 + kk));
        }
        __syncthreads();                           // prior iter's LDS reads done
#pragma unroll
        for (int rep = 0; rep < 2; ++rep) {
            int s = rep * 256 + tid;
            *(uint4*)(As + s * 8) = ra[rep];
            *(uint4*)(Bs + s * 8) = rb[rep];
        }
        __syncthreads();                           // staging visible
        int kq = (lane >> 4) << 3;                 // 0,8,16,24
        bf16x8 av[4], bw[4];
#pragma unroll
        for (int m = 0; m < 4; ++m) {
            int r = wm * 64 + m * 16 + (lane & 15);
            av[m] = *(const bf16x8*)(As + r * 32 + kq);
        }
#pragma unroll
        for (int n = 0; n < 4; ++n) {
            int c = wn * 64 + n * 16 + (lane & 15);
            bw[n] = *(const bf16x8*)(Bs + c * 32 + kq);
        }
#pragma unroll
        for (int m = 0; m < 4; ++m)
#pragma unroll
            for (int n = 0; n < 4; ++n)
                acc[m][n] = __builtin_amdgcn_mfma_f32_16x16x32_bf16(av[m], bw[n], acc[m][n], 0, 0, 0);
    }

    int cBase = colBase + wn * 64 + (lane & 15);
    int rBase = rowBase + wm * 64 + ((lane >> 4) << 2);
    if (mode == 0) {
        float* C = (float*)Cout;
#pragma unroll
        for (int m = 0; m < 4; ++m)
#pragma unroll
            for (int n = 0; n < 4; ++n)
#pragma unroll
                for (int r = 0; r < 4; ++r)
                    C[(size_t)(rBase + m * 16 + r) * N + (cBase + n * 16)] = acc[m][n][r];
    } else {
        u16* C = (u16*)Cout;
        float bz[4];
#pragma unroll
        for (int n = 0; n < 4; ++n) bz[n] = bias ? bias[cBase + n * 16] : 0.f;
#pragma unroll
        for (int m = 0; m < 4; ++m)
#pragma unroll
            for (int n = 0; n < 4; ++n)
#pragma unroll
                for (int r = 0; r < 4; ++r) {
                    float v = acc[m][n][r] + bz[n];
                    if (mode == 1) v = v > 0.f ? v : 0.f;
                    C[(size_t)(rBase + m * 16 + r) * N + (cBase + n * 16)] = f2b(v);
                }
    }
}

// ---------------- chunked EMA scan ------------------------------------------
// zg: bf16 [NB, 512] (z = [:,0:256], g = [:,256:512]); alog: f32 [256]
__global__ void scan_carry_kernel(const u16* __restrict__ zg, const float* __restrict__ alog,
                                  float* __restrict__ carry) {
    int g = blockIdx.x * 256 + threadIdx.x;        // B*NCH*DD threads
    int d = g & (DD - 1);
    int bc = g >> 8;                               // b*NCH + c
    int b = bc >> 5, c = bc & (NCH - 1);
    float a = sigm(alog[d]);
    float h = 0.f;
    const u16* zp = zg + ((size_t)(b * LL + c * CHL) * 512) + d;
    for (int t = 0; t < CHL; ++t) {
        float z = b2f(zp[(size_t)t * 512]);
        h = a * h + (1.f - a) * z;
    }
    carry[(size_t)bc * DD + d] = h;
}

__global__ void scan_combine_kernel(const float* __restrict__ carry, const float* __restrict__ alog,
                                    float* __restrict__ start) {
    int g = blockIdx.x * 256 + threadIdx.x;        // B*DD threads
    int d = g & (DD - 1), b = g >> 8;
    float a = sigm(alog[d]);
    float aP = a;
#pragma unroll
    for (int i = 0; i < 6; ++i) aP *= aP;          // a^64
    float h = 0.f;
    for (int c = 0; c < NCH; ++c) {
        start[(size_t)(b * NCH + c) * DD + d] = h;
        h = carry[(size_t)(b * NCH + c) * DD + d] + aP * h;
    }
}

__global__ void scan_apply_kernel(const u16* __restrict__ zg, const float* __restrict__ alog,
                                  const float* __restrict__ start, u16* __restrict__ U) {
    int g = blockIdx.x * 256 + threadIdx.x;
    int d = g & (DD - 1);
    int bc = g >> 8, b = bc >> 5, c = bc & (NCH - 1);
    float a = sigm(alog[d]);
    float h = start[(size_t)bc * DD + d];
    const u16* zp = zg + ((size_t)(b * LL + c * CHL) * 512) + d;
    u16* up = U + ((size_t)(b * LL + c * CHL) * DD) + d;
    for (int t = 0; t < CHL; ++t) {
        float z = b2f(zp[(size_t)t * 512]);
        float gv = b2f(zp[(size_t)t * 512 + 256]);
        h = a * h + (1.f - a) * z;
        up[(size_t)t * DD] = f2b(h * gv * sigm(gv));
    }
}

// ---------------- sparse aggregation (+ optional reverse gather) ------------
__global__ void agg_kernel(const float* __restrict__ srcF, const u16* __restrict__ srcB,
                           const int* __restrict__ ri, const int* __restrict__ csr,
                           const int* __restrict__ cnt, const float* __restrict__ deg,
                           u16* __restrict__ P) {
    int r = blockIdx.x;            // NB
    int d = threadIdx.x;           // DD
    int b = r >> 11;
    int n = cnt[r];
    float acc = 0.f;
    for (int i = 0; i < n; ++i) {
        int j = csr[(size_t)r * CAP + i];
        int srow = ri ? ri[(b << 11) + j] : j;
        size_t idx = ((size_t)(b << 11) + srow) * DD + d;
        acc += srcF ? srcF[idx] : b2f(srcB[idx]);
    }
    P[(size_t)r * DD + d] = f2b(acc / deg[r]);
}

// ---------------- relu+mask (+branch-3 mamba add) -> Yin slot ---------------
__global__ void postagg_kernel(const float* __restrict__ tmpWe, const float* __restrict__ mo3,
                               const int* __restrict__ maskp, u16* __restrict__ Yin, int slot) {
    int g = blockIdx.x * 256 + threadIdx.x;
    int d = g & (DD - 1), r = g >> 8;
    float v = tmpWe[(size_t)r * DD + d];
    v = v > 0.f ? v : 0.f;
    if (mo3) v += mo3[(size_t)r * DD + d];
    v = maskp[r] ? v : 0.f;
    Yin[(size_t)r * 1024 + slot * DD + d] = f2b(v);
}

// ---------------- layernorm (+bias fold, +residual) -------------------------
__device__ __forceinline__ float blk_sum(float v, float* sm) {
#pragma unroll
    for (int o = 32; o > 0; o >>= 1) v += __shfl_down(v, o, 64);
    int lane = threadIdx.x & 63, w = threadIdx.x >> 6;
    __syncthreads();
    if (lane == 0) sm[w] = v;
    __syncthreads();
    return sm[0] + sm[1] + sm[2] + sm[3];
}

__global__ void ln1_kernel(const float* __restrict__ Yt, const float* __restrict__ bvp,
                           const float* __restrict__ X, const float* __restrict__ gp,
                           const float* __restrict__ bp, float* __restrict__ X1f,
                           u16* __restrict__ X1b) {
    __shared__ float sm[4];
    int r = blockIdx.x, d = threadIdx.x;
    float x = Yt[(size_t)r * DD + d] + bvp[d];
    float mu = blk_sum(x, sm) * (1.f / DD);
    float dx = x - mu;
    float var = blk_sum(dx * dx, sm) * (1.f / DD);
    float y = dx * rsqrtf(var + 1e-5f) * gp[d] + bp[d];
    float x1 = X[(size_t)r * DD + d] + y;
    X1f[(size_t)r * DD + d] = x1;
    X1b[(size_t)r * DD + d] = f2b(x1);
}

__global__ void ln2_kernel(const float* __restrict__ Y2, const float* __restrict__ b2p,
                           const float* __restrict__ X1f, const float* __restrict__ gp,
                           const float* __restrict__ bp, float* __restrict__ Out) {
    __shared__ float sm[4];
    int r = blockIdx.x, d = threadIdx.x;
    float x = Y2[(size_t)r * DD + d] + b2p[d];
    float mu = blk_sum(x, sm) * (1.f / DD);
    float dx = x - mu;
    float var = blk_sum(dx * dx, sm) * (1.f / DD);
    float y = dx * rsqrtf(var + 1e-5f) * gp[d] + bp[d];
    Out[(size_t)r * DD + d] = X1f[(size_t)r * DD + d] + y;
}

// ============================================================================
extern "C" void kernel_launch(void* const* d_in, const int* in_sizes, int n_in,
                              void* d_out, int out_size, void* d_ws, size_t ws_size,
                              hipStream_t stream) {
    // setup_inputs() dict order (sorted/reverse interleaved). Floats are f32.
    const float* X      = (const float*)d_in[0];
    const int* maskp    = (const int*)d_in[1];
    const float* Adj    = (const float*)d_in[2];
    const int* si[3]    = { (const int*)d_in[3], (const int*)d_in[5], (const int*)d_in[7] };
    const int* ri[3]    = { (const int*)d_in[4], (const int*)d_in[6], (const int*)d_in[8] };
    const float* gm1_Win  = (const float*)d_in[9];
    const float* gm1_alog = (const float*)d_in[10];
    const float* gm1_Wout = (const float*)d_in[11];
    const float* gm2_We   = (const float*)d_in[12];
    const float* gm_Win   = (const float*)d_in[13];
    const float* gm_alog  = (const float*)d_in[14];
    const float* gm_Wout  = (const float*)d_in[15];
    const float* gm_We    = (const float*)d_in[16];
    const float* ln1_g    = (const float*)d_in[17];
    const float* ln1_b    = (const float*)d_in[18];
    const float* ln2_g    = (const float*)d_in[19];
    const float* ln2_b    = (const float*)d_in[20];
    const float* ffn_W1   = (const float*)d_in[21];
    const float* ffn_b1   = (const float*)d_in[22];
    const float* ffn_W2   = (const float*)d_in[23];
    const float* ffn_b2   = (const float*)d_in[24];
    const float* Wv       = (const float*)d_in[25];
    const float* bv       = (const float*)d_in[26];
    float* Out = (float*)d_out;

    char* ws = (char*)d_ws;
    size_t off = 0;
    auto alloc = [&](size_t bytes) { size_t o = off; off += (bytes + 255) & ~(size_t)255; return o; };

    size_t o_WinT1 = alloc((size_t)512 * 256 * 2);
    size_t o_WoutT1 = alloc((size_t)256 * 256 * 2);
    size_t o_WeT1 = alloc((size_t)256 * 256 * 2);
    size_t o_WinT = alloc((size_t)512 * 256 * 2);
    size_t o_WoutT = alloc((size_t)256 * 256 * 2);
    size_t o_WeT = alloc((size_t)256 * 256 * 2);
    size_t o_WvT = alloc((size_t)256 * 1024 * 2);
    size_t o_W1T = alloc((size_t)1024 * 256 * 2);
    size_t o_W2T = alloc((size_t)256 * 1024 * 2);
    size_t o_csr = alloc((size_t)NB * CAP * 4);
    size_t o_cnt = alloc((size_t)NB * 4);
    size_t o_deg = alloc((size_t)NB * 4);
    size_t o_carry = alloc((size_t)BB * NCH * DD * 4);
    size_t o_start = alloc((size_t)BB * NCH * DD * 4);
    size_t o_Sg = alloc((size_t)NB * DD * 2);
    size_t o_zg = alloc((size_t)NB * 512 * 2);       // 16.78 MB, reused as tmpY (f32)
    size_t o_U = alloc((size_t)NB * DD * 2);
    size_t o_mo = alloc((size_t)NB * DD * 4);        // mo+P+tmpWe region reused as H [NB,1024] bf16
    size_t o_P = alloc((size_t)NB * DD * 2);
    size_t o_tmpWe = alloc((size_t)NB * DD * 4);
    size_t o_Yin = alloc((size_t)NB * 1024 * 2);     // reused as X1f + tmpY2 (f32)
    (void)ws_size; (void)in_sizes; (void)n_in; (void)out_size;

    u16* WinT1 = (u16*)(ws + o_WinT1); u16* WoutT1 = (u16*)(ws + o_WoutT1); u16* WeT1 = (u16*)(ws + o_WeT1);
    u16* WinT = (u16*)(ws + o_WinT);   u16* WoutT = (u16*)(ws + o_WoutT);   u16* WeT = (u16*)(ws + o_WeT);
    u16* WvT = (u16*)(ws + o_WvT);     u16* W1T = (u16*)(ws + o_W1T);       u16* W2T = (u16*)(ws + o_W2T);
    int* csr = (int*)(ws + o_csr); int* cnt = (int*)(ws + o_cnt); float* deg = (float*)(ws + o_deg);
    float* carry = (float*)(ws + o_carry); float* start = (float*)(ws + o_start);
    u16* Sg = (u16*)(ws + o_Sg); u16* zg = (u16*)(ws + o_zg); u16* U = (u16*)(ws + o_U);
    float* mo = (float*)(ws + o_mo); u16* P = (u16*)(ws + o_P); float* tmpWe = (float*)(ws + o_tmpWe);
    u16* Yin = (u16*)(ws + o_Yin);
    float* tmpY = (float*)(ws + o_zg);
    u16* X1b = (u16*)(ws + o_Sg);
    float* X1f = (float*)(ws + o_Yin);
    float* tmpY2 = (float*)(ws + o_Yin + (size_t)NB * DD * 4);
    u16* H = (u16*)(ws + o_mo);

    // weight transposes (f32 -> bf16)
    auto tr = [&](const float* W, u16* Wt, int K, int N) {
        int tot = K * N;
        transpose_kernel<<<(tot + 255) / 256, 256, 0, stream>>>(W, Wt, K, N);
    };
    tr(gm1_Win, WinT1, 256, 512);
    tr(gm1_Wout, WoutT1, 256, 256);
    tr(gm2_We, WeT1, 256, 256);
    tr(gm_Win, WinT, 256, 512);
    tr(gm_Wout, WoutT, 256, 256);
    tr(gm_We, WeT, 256, 256);
    tr(Wv, WvT, 1024, 256);
    tr(ffn_W1, W1T, 256, 1024);
    tr(ffn_W2, W2T, 1024, 256);

    csr_kernel<<<NB / 4, 256, 0, stream>>>(Adj, csr, cnt, deg);

    for (int br = 0; br < 4; ++br) {
        const u16* WinSel = (br < 3) ? WinT1 : WinT;
        const u16* WoutSel = (br < 3) ? WoutT1 : WoutT;
        const u16* WeSel = (br < 3) ? WeT1 : WeT;
        const float* alogSel = (br < 3) ? gm1_alog : gm_alog;

        gather_kernel<<<NB, 256, 0, stream>>>(X, (br < 3) ? si[br] : nullptr, maskp, Sg);
        gemm_kernel<<<dim3(NB / 128, 512 / 128), 256, 0, stream>>>(Sg, WinSel, (void*)zg, nullptr,
                                                                   NB, 512, 256, 2);
        scan_carry_kernel<<<BB * NCH, 256, 0, stream>>>(zg, alogSel, carry);
        scan_combine_kernel<<<BB, 256, 0, stream>>>(carry, alogSel, start);
        scan_apply_kernel<<<BB * NCH, 256, 0, stream>>>(zg, alogSel, start, U);
        gemm_kernel<<<dim3(NB / 128, 256 / 128), 256, 0, stream>>>(U, WoutSel, (void*)mo, nullptr,
                                                                   NB, 256, 256, 0);
        if (br < 3)
            agg_kernel<<<NB, 256, 0, stream>>>(mo, nullptr, ri[br], csr, cnt, deg, P);
        else
            agg_kernel<<<NB, 256, 0, stream>>>(nullptr, Sg, nullptr, csr, cnt, deg, P);
        gemm_kernel<<<dim3(NB / 128, 256 / 128), 256, 0, stream>>>(P, WeSel, (void*)tmpWe, nullptr,
                                                                   NB, 256, 256, 0);
        postagg_kernel<<<NB, 256, 0, stream>>>(tmpWe, (br == 3) ? mo : nullptr, maskp, Yin, br);
    }

    // Y = Yin @ Wv (+bv folded into ln1)
    gemm_kernel<<<dim3(NB / 128, 256 / 128), 256, 0, stream>>>(Yin, WvT, (void*)tmpY, nullptr,
                                                               NB, 256, 1024, 0);
    ln1_kernel<<<NB, 256, 0, stream>>>(tmpY, bv, X, ln1_g, ln1_b, X1f, X1b);
    gemm_kernel<<<dim3(NB / 128, 1024 / 128), 256, 0, stream>>>(X1b, W1T, (void*)H, ffn_b1,
                                                                NB, 1024, 256, 1);
    gemm_kernel<<<dim3(NB / 128, 256 / 128), 256, 0, stream>>>(H, W2T, (void*)tmpY2, nullptr,
                                                               NB, 256, 1024, 0);
    ln2_kernel<<<NB, 256, 0, stream>>>(tmpY2, ffn_b2, X1f, ln2_g, ln2_b, Out);
}

// Round 4
// 436.742 us; speedup vs baseline: 1.7727x; 1.7727x over previous
//
#include <hip/hip_runtime.h>

typedef unsigned short u16;
typedef unsigned int u32;
typedef unsigned long long u64;

#define BB 8
#define LL 2048
#define DD 256
#define NB (BB * LL)      // 16384 rows per branch
#define NBR 4
#define NRT (NBR * NB)    // 65536 batched rows
#define NCH 32
#define CHL (LL / NCH)    // 64
#define CAP 64

typedef __attribute__((ext_vector_type(8))) __bf16 bf16x8;
typedef __attribute__((ext_vector_type(4))) float f32x4;

__device__ __forceinline__ float b2f(u16 u) {
    union { u32 u; float f; } x; x.u = ((u32)u) << 16; return x.f;
}
__device__ __forceinline__ u16 f2b(float f) {
    union { float f; u32 u; } x; x.f = f;
    u32 r = (x.u >> 16) & 1u;
    x.u += 0x7FFFu + r;
    return (u16)(x.u >> 16);
}
__device__ __forceinline__ float sigm(float x) { return 1.f / (1.f + __expf(-x)); }

// ------------- batched weight transpose+cast: W[K,N] f32 -> Wt[N,K] bf16 ----
struct TrArgs {
    const float* s[9];
    u16* d[9];
    int K[9], N[9];
    int beg[10];
};
__global__ void transpose_all(TrArgs a) {
    int blk = blockIdx.x;
    int i = 0;
    while (blk >= a.beg[i + 1]) ++i;
    int idx = (blk - a.beg[i]) * 256 + threadIdx.x;
    int K = a.K[i], N = a.N[i];
    if (idx >= K * N) return;
    int k = idx / N, n = idx - k * N;
    a.d[i][(size_t)n * K + k] = f2b(a.s[i][idx]);
}

// ---------------- CSR build from binary adjacency (f32, deterministic) ------
__global__ void csr_kernel(const float* __restrict__ Adj, int* __restrict__ csr,
                           int* __restrict__ cnt, float* __restrict__ deg) {
    int w = threadIdx.x >> 6, lane = threadIdx.x & 63;
    int row = blockIdx.x * 4 + w;                 // 0..NB-1
    const float* arow = Adj + (size_t)row * LL;
    int base = 0;
    for (int c = 0; c < LL / 64; ++c) {
        int j = c * 64 + lane;
        bool nz = (arow[j] != 0.f);
        u64 m = __ballot(nz);
        if (nz) {
            int pos = base + __popcll(m & ((1ull << lane) - 1ull));
            if (pos < CAP) csr[(size_t)row * CAP + pos] = j;
        }
        base += __popcll(m);
    }
    if (lane == 0) {
        cnt[row] = base < CAP ? base : CAP;
        deg[row] = (float)(base < 1 ? 1 : base);
    }
}

// -------- batched gather: f32 X -> bf16 Sg4 [4, NB, 256] (br3 = identity) ---
__global__ void gather4_kernel(const float* __restrict__ X,
                               const int* __restrict__ si0, const int* __restrict__ si1,
                               const int* __restrict__ si2, const int* __restrict__ maskp,
                               u16* __restrict__ Sg4) {
    int rg = blockIdx.x;           // 0..NRT-1
    int d = threadIdx.x;
    int br = rg >> 14, r = rg & (NB - 1);
    int b = r >> 11, l = r & (LL - 1);
    u16 val = 0;
    if (maskp[r]) {
        int src = l;
        if (br == 0) src = si0[r];
        else if (br == 1) src = si1[r];
        else if (br == 2) src = si2[r];
        val = f2b(X[((size_t)(b << 11) + src) * DD + d]);
    }
    Sg4[(size_t)rg * DD + d] = val;
}

// ---------------- GEMM: C[M,N] = A[M,K] @ Bt[N,K]^T  (bf16 in, f32 acc) -----
// Weight split: rows < splitRow use Bt1, else Bt2.
// mode 0: f32 store; mode 1: bias(f32)+relu+bf16; mode 2: plain bf16;
// mode 3: We epilogue (relu, br3 += mo4, row-mask, strided store to Yin[r,1024])
__global__ __launch_bounds__(256)
void gemm_kernel(const u16* __restrict__ A, const u16* __restrict__ Bt1,
                 const u16* __restrict__ Bt2, int splitRow,
                 void* __restrict__ Cout, const float* __restrict__ bias,
                 const int* __restrict__ maskp, const u16* __restrict__ mo4,
                 int N, int K, int mode)
{
    __shared__ __align__(16) u16 As[128 * 32];
    __shared__ __align__(16) u16 Bs[128 * 32];
    int tid = threadIdx.x;
    int lane = tid & 63;
    int w = tid >> 6, wm = w >> 1, wn = w & 1;
    int rowBase = blockIdx.x * 128, colBase = blockIdx.y * 128;
    const u16* Bt = (rowBase < splitRow) ? Bt1 : Bt2;

    f32x4 acc[4][4];
#pragma unroll
    for (int m = 0; m < 4; ++m)
#pragma unroll
        for (int n = 0; n < 4; ++n) acc[m][n] = (f32x4){0.f, 0.f, 0.f, 0.f};

    for (int k0 = 0; k0 < K; k0 += 32) {
#pragma unroll
        for (int rep = 0; rep < 2; ++rep) {
            int s = rep * 256 + tid;               // 16B segment id, 0..511
            int row = s >> 2, kk = (s & 3) << 3;
            const u16* ga = A + (size_t)(rowBase + row) * K + (k0 + kk);
            const u16* gb = Bt + (size_t)(colBase + row) * K + (k0 + kk);
            __builtin_amdgcn_global_load_lds((const __attribute__((address_space(1))) void*)ga,
                                             (__attribute__((address_space(3))) void*)(As + s * 8), 16, 0, 0);
            __builtin_amdgcn_global_load_lds((const __attribute__((address_space(1))) void*)gb,
                                             (__attribute__((address_space(3))) void*)(Bs + s * 8), 16, 0, 0);
        }
        __syncthreads();                           // drains vmcnt -> staging visible
        int kq = (lane >> 4) << 3;                 // 0,8,16,24
        bf16x8 av[4], bw[4];
#pragma unroll
        for (int m = 0; m < 4; ++m) {
            int r = wm * 64 + m * 16 + (lane & 15);
            av[m] = *(const bf16x8*)(As + r * 32 + kq);
        }
#pragma unroll
        for (int n = 0; n < 4; ++n) {
            int c = wn * 64 + n * 16 + (lane & 15);
            bw[n] = *(const bf16x8*)(Bs + c * 32 + kq);
        }
#pragma unroll
        for (int m = 0; m < 4; ++m)
#pragma unroll
            for (int n = 0; n < 4; ++n)
                acc[m][n] = __builtin_amdgcn_mfma_f32_16x16x32_bf16(av[m], bw[n], acc[m][n], 0, 0, 0);
        __syncthreads();                           // protect LDS before next stage
    }

    int cBase = colBase + wn * 64 + (lane & 15);
    int rBase = rowBase + wm * 64 + ((lane >> 4) << 2);
    if (mode == 0) {
        float* C = (float*)Cout;
#pragma unroll
        for (int m = 0; m < 4; ++m)
#pragma unroll
            for (int n = 0; n < 4; ++n)
#pragma unroll
                for (int r = 0; r < 4; ++r)
                    C[(size_t)(rBase + m * 16 + r) * N + (cBase + n * 16)] = acc[m][n][r];
    } else if (mode == 3) {
        u16* Yin = (u16*)Cout;
#pragma unroll
        for (int m = 0; m < 4; ++m)
#pragma unroll
            for (int r = 0; r < 4; ++r) {
                int gr = rBase + m * 16 + r;       // 0..NRT-1
                int br = gr >> 14, rr = gr & (NB - 1);
                int msk = maskp[rr];
#pragma unroll
                for (int n = 0; n < 4; ++n) {
                    int col = cBase + n * 16;
                    float v = acc[m][n][r];
                    v = v > 0.f ? v : 0.f;
                    if (br == 3) v += b2f(mo4[(size_t)gr * DD + col]);
                    v = msk ? v : 0.f;
                    Yin[(size_t)rr * 1024 + (br << 8) + col] = f2b(v);
                }
            }
    } else {
        u16* C = (u16*)Cout;
        float bz[4];
#pragma unroll
        for (int n = 0; n < 4; ++n) bz[n] = bias ? bias[cBase + n * 16] : 0.f;
#pragma unroll
        for (int m = 0; m < 4; ++m)
#pragma unroll
            for (int n = 0; n < 4; ++n)
#pragma unroll
                for (int r = 0; r < 4; ++r) {
                    float v = acc[m][n][r] + bz[n];
                    if (mode == 1) v = v > 0.f ? v : 0.f;
                    C[(size_t)(rBase + m * 16 + r) * N + (cBase + n * 16)] = f2b(v);
                }
    }
}

// ---------------- batched chunked EMA scan ----------------------------------
// zg4: bf16 [NRT, 512] (z = [:,0:256], g = [:,256:512])
__global__ void scan_carry_kernel(const u16* __restrict__ zg4, const float* __restrict__ alog1,
                                  const float* __restrict__ alog2, float* __restrict__ carry) {
    int bid = blockIdx.x;                          // 0..1023
    int br = bid >> 8, b = (bid >> 5) & 7, c = bid & 31;
    int d = threadIdx.x;
    float a = sigm((br < 3 ? alog1 : alog2)[d]);
    float h = 0.f;
    const u16* zp = zg4 + ((size_t)(br * NB + b * LL + c * CHL) * 512) + d;
    for (int t = 0; t < CHL; ++t) {
        float z = b2f(zp[(size_t)t * 512]);
        h = a * h + (1.f - a) * z;
    }
    carry[(size_t)bid * DD + d] = h;
}

__global__ void scan_combine_kernel(const float* __restrict__ carry, const float* __restrict__ alog1,
                                    const float* __restrict__ alog2, float* __restrict__ start) {
    int br = blockIdx.x >> 3, b = blockIdx.x & 7;  // grid 32
    int d = threadIdx.x;
    float a = sigm((br < 3 ? alog1 : alog2)[d]);
    float aP = a;
#pragma unroll
    for (int i = 0; i < 6; ++i) aP *= aP;          // a^64
    float h = 0.f;
    for (int c = 0; c < NCH; ++c) {
        size_t idx = ((size_t)(br * 256 + b * 32 + c)) * DD + d;
        start[idx] = h;
        h = carry[idx] + aP * h;
    }
}

__global__ void scan_apply_kernel(const u16* __restrict__ zg4, const float* __restrict__ alog1,
                                  const float* __restrict__ alog2, const float* __restrict__ start,
                                  u16* __restrict__ U4) {
    int bid = blockIdx.x;
    int br = bid >> 8, b = (bid >> 5) & 7, c = bid & 31;
    int d = threadIdx.x;
    float a = sigm((br < 3 ? alog1 : alog2)[d]);
    float h = start[(size_t)bid * DD + d];
    const u16* zp = zg4 + ((size_t)(br * NB + b * LL + c * CHL) * 512) + d;
    u16* up = U4 + ((size_t)(br * NB + b * LL + c * CHL) * DD) + d;
    for (int t = 0; t < CHL; ++t) {
        float z = b2f(zp[(size_t)t * 512]);
        float gv = b2f(zp[(size_t)t * 512 + 256]);
        h = a * h + (1.f - a) * z;
        up[(size_t)t * DD] = f2b(h * gv * sigm(gv));
    }
}

// ------- batched sparse aggregation (+ reverse gather for br<3) -------------
__global__ void agg4_kernel(const u16* __restrict__ mo4, const u16* __restrict__ Sg4,
                            const int* __restrict__ ri0, const int* __restrict__ ri1,
                            const int* __restrict__ ri2, const int* __restrict__ csr,
                            const int* __restrict__ cnt, const float* __restrict__ deg,
                            u16* __restrict__ P4) {
    int rg = blockIdx.x;           // 0..NRT-1
    int d = threadIdx.x;
    int br = rg >> 14, r = rg & (NB - 1);
    int b = r >> 11;
    const int* ri = (br == 0) ? ri0 : (br == 1) ? ri1 : ri2;
    int n = cnt[r];
    float acc = 0.f;
    for (int i = 0; i < n; ++i) {
        int j = csr[(size_t)r * CAP + i];
        size_t src;
        if (br < 3) src = ((size_t)(br * NB + (b << 11) + ri[(b << 11) + j])) * DD + d;
        else        src = ((size_t)(3 * NB + (b << 11) + j)) * DD + d;
        acc += b2f(br < 3 ? mo4[src] : Sg4[src]);
    }
    P4[(size_t)rg * DD + d] = f2b(acc / deg[r]);
}

// ---------------- layernorm (+bias fold, +residual) -------------------------
__device__ __forceinline__ float blk_sum(float v, float* sm) {
#pragma unroll
    for (int o = 32; o > 0; o >>= 1) v += __shfl_down(v, o, 64);
    int lane = threadIdx.x & 63, w = threadIdx.x >> 6;
    __syncthreads();
    if (lane == 0) sm[w] = v;
    __syncthreads();
    return sm[0] + sm[1] + sm[2] + sm[3];
}

__global__ void ln1_kernel(const float* __restrict__ Yt, const float* __restrict__ bvp,
                           const float* __restrict__ X, const float* __restrict__ gp,
                           const float* __restrict__ bp, float* __restrict__ X1f,
                           u16* __restrict__ X1b) {
    __shared__ float sm[4];
    int r = blockIdx.x, d = threadIdx.x;
    float x = Yt[(size_t)r * DD + d] + bvp[d];
    float mu = blk_sum(x, sm) * (1.f / DD);
    float dx = x - mu;
    float var = blk_sum(dx * dx, sm) * (1.f / DD);
    float y = dx * rsqrtf(var + 1e-5f) * gp[d] + bp[d];
    float x1 = X[(size_t)r * DD + d] + y;
    X1f[(size_t)r * DD + d] = x1;
    X1b[(size_t)r * DD + d] = f2b(x1);
}

__global__ void ln2_kernel(const float* __restrict__ Y2, const float* __restrict__ b2p,
                           const float* __restrict__ X1f, const float* __restrict__ gp,
                           const float* __restrict__ bp, float* __restrict__ Out) {
    __shared__ float sm[4];
    int r = blockIdx.x, d = threadIdx.x;
    float x = Y2[(size_t)r * DD + d] + b2p[d];
    float mu = blk_sum(x, sm) * (1.f / DD);
    float dx = x - mu;
    float var = blk_sum(dx * dx, sm) * (1.f / DD);
    float y = dx * rsqrtf(var + 1e-5f) * gp[d] + bp[d];
    Out[(size_t)r * DD + d] = X1f[(size_t)r * DD + d] + y;
}

// ============================================================================
extern "C" void kernel_launch(void* const* d_in, const int* in_sizes, int n_in,
                              void* d_out, int out_size, void* d_ws, size_t ws_size,
                              hipStream_t stream) {
    const float* X      = (const float*)d_in[0];
    const int* maskp    = (const int*)d_in[1];
    const float* Adj    = (const float*)d_in[2];
    const int* si[3]    = { (const int*)d_in[3], (const int*)d_in[5], (const int*)d_in[7] };
    const int* ri[3]    = { (const int*)d_in[4], (const int*)d_in[6], (const int*)d_in[8] };
    const float* gm1_Win  = (const float*)d_in[9];
    const float* gm1_alog = (const float*)d_in[10];
    const float* gm1_Wout = (const float*)d_in[11];
    const float* gm2_We   = (const float*)d_in[12];
    const float* gm_Win   = (const float*)d_in[13];
    const float* gm_alog  = (const float*)d_in[14];
    const float* gm_Wout  = (const float*)d_in[15];
    const float* gm_We    = (const float*)d_in[16];
    const float* ln1_g    = (const float*)d_in[17];
    const float* ln1_b    = (const float*)d_in[18];
    const float* ln2_g    = (const float*)d_in[19];
    const float* ln2_b    = (const float*)d_in[20];
    const float* ffn_W1   = (const float*)d_in[21];
    const float* ffn_b1   = (const float*)d_in[22];
    const float* ffn_W2   = (const float*)d_in[23];
    const float* ffn_b2   = (const float*)d_in[24];
    const float* Wv       = (const float*)d_in[25];
    const float* bv       = (const float*)d_in[26];
    float* Out = (float*)d_out;

    char* ws = (char*)d_ws;
    size_t off = 0;
    auto alloc = [&](size_t bytes) { size_t o = off; off += (bytes + 255) & ~(size_t)255; return o; };

    u16* WinT1 = (u16*)(ws + alloc((size_t)512 * 256 * 2));
    u16* WoutT1 = (u16*)(ws + alloc((size_t)256 * 256 * 2));
    u16* WeT1 = (u16*)(ws + alloc((size_t)256 * 256 * 2));
    u16* WinT = (u16*)(ws + alloc((size_t)512 * 256 * 2));
    u16* WoutT = (u16*)(ws + alloc((size_t)256 * 256 * 2));
    u16* WeT = (u16*)(ws + alloc((size_t)256 * 256 * 2));
    u16* WvT = (u16*)(ws + alloc((size_t)256 * 1024 * 2));
    u16* W1T = (u16*)(ws + alloc((size_t)1024 * 256 * 2));
    u16* W2T = (u16*)(ws + alloc((size_t)256 * 1024 * 2));
    int* csr = (int*)(ws + alloc((size_t)NB * CAP * 4));
    int* cnt = (int*)(ws + alloc((size_t)NB * 4));
    float* deg = (float*)(ws + alloc((size_t)NB * 4));
    float* carry = (float*)(ws + alloc((size_t)NBR * BB * NCH * DD * 4));
    float* start = (float*)(ws + alloc((size_t)NBR * BB * NCH * DD * 4));
    u16* Sg4 = (u16*)(ws + alloc((size_t)NRT * DD * 2));   // 33.6 MB
    u16* zg4 = (u16*)(ws + alloc((size_t)NRT * 512 * 2));  // 67.1 MB
    u16* U4  = (u16*)(ws + alloc((size_t)NRT * DD * 2));   // 33.6 MB
    u16* mo4 = (u16*)(ws + alloc((size_t)NRT * DD * 2));   // 33.6 MB
    (void)ws_size; (void)in_sizes; (void)n_in; (void)out_size;

    // Lifetime-safe aliases (see timeline in session notes):
    u16* P4     = (u16*)zg4;                         // after scan_apply, zg4 dead
    u16* Yin    = (u16*)Sg4;                         // after agg4, Sg4 dead
    float* tmpY = (float*)mo4;                       // after We-GEMM, mo4 dead
    float* X1f  = (float*)zg4;                       // after We-GEMM, P4 dead
    u16* X1b    = (u16*)((char*)zg4 + (size_t)NB * DD * 4);
    u16* H      = (u16*)U4;                          // after Wout-GEMM, U4 dead
    float* tmpY2 = (float*)Sg4;                      // after Wv-GEMM, Yin dead

    // 1. all weight transposes in one launch
    TrArgs ta;
    const float* srcs[9] = { gm1_Win, gm1_Wout, gm2_We, gm_Win, gm_Wout, gm_We, Wv, ffn_W1, ffn_W2 };
    u16* dsts[9] = { WinT1, WoutT1, WeT1, WinT, WoutT, WeT, WvT, W1T, W2T };
    int Ks[9] = { 256, 256, 256, 256, 256, 256, 1024, 256, 1024 };
    int Ns[9] = { 512, 256, 256, 512, 256, 256, 256, 1024, 256 };
    int cum = 0;
    for (int i = 0; i < 9; ++i) {
        ta.s[i] = srcs[i]; ta.d[i] = dsts[i]; ta.K[i] = Ks[i]; ta.N[i] = Ns[i];
        ta.beg[i] = cum; cum += (Ks[i] * Ns[i]) / 256;
    }
    ta.beg[9] = cum;
    transpose_all<<<cum, 256, 0, stream>>>(ta);

    // 2. CSR
    csr_kernel<<<NB / 4, 256, 0, stream>>>(Adj, csr, cnt, deg);

    // 3. batched gather (br3 = identity+mask)
    gather4_kernel<<<NRT, 256, 0, stream>>>(X, si[0], si[1], si[2], maskp, Sg4);

    // 4. Win GEMM: [NRT,256] @ [256,512] -> zg4 bf16
    gemm_kernel<<<dim3(NRT / 128, 512 / 128), 256, 0, stream>>>(
        Sg4, WinT1, WinT, 3 * NB, (void*)zg4, nullptr, nullptr, nullptr, 512, 256, 2);

    // 5-7. batched scan
    scan_carry_kernel<<<NBR * BB * NCH, 256, 0, stream>>>(zg4, gm1_alog, gm_alog, carry);
    scan_combine_kernel<<<NBR * BB, 256, 0, stream>>>(carry, gm1_alog, gm_alog, start);
    scan_apply_kernel<<<NBR * BB * NCH, 256, 0, stream>>>(zg4, gm1_alog, gm_alog, start, U4);

    // 8. Wout GEMM: [NRT,256] @ [256,256] -> mo4 bf16
    gemm_kernel<<<dim3(NRT / 128, 256 / 128), 256, 0, stream>>>(
        U4, WoutT1, WoutT, 3 * NB, (void*)mo4, nullptr, nullptr, nullptr, 256, 256, 2);

    // 9. batched aggregation -> P4 bf16
    agg4_kernel<<<NRT, 256, 0, stream>>>(mo4, Sg4, ri[0], ri[1], ri[2], csr, cnt, deg, P4);

    // 10. We GEMM + fused epilogue (relu, br3 += mo4, mask, slot-write) -> Yin
    gemm_kernel<<<dim3(NRT / 128, 256 / 128), 256, 0, stream>>>(
        P4, WeT1, WeT, 3 * NB, (void*)Yin, nullptr, maskp, mo4, 256, 256, 3);

    // 11. Wv GEMM: [NB,1024] @ [1024,256] -> tmpY f32
    gemm_kernel<<<dim3(NB / 128, 256 / 128), 256, 0, stream>>>(
        Yin, WvT, WvT, NB, (void*)tmpY, nullptr, nullptr, nullptr, 256, 1024, 0);

    // 12. LN1 (+bv fold, +X residual)
    ln1_kernel<<<NB, 256, 0, stream>>>(tmpY, bv, X, ln1_g, ln1_b, X1f, X1b);

    // 13. FFN1: [NB,256] @ [256,1024] +b1, relu -> H bf16
    gemm_kernel<<<dim3(NB / 128, 1024 / 128), 256, 0, stream>>>(
        X1b, W1T, W1T, NB, (void*)H, ffn_b1, nullptr, nullptr, 1024, 256, 1);

    // 14. FFN2: [NB,1024] @ [1024,256] -> tmpY2 f32
    gemm_kernel<<<dim3(NB / 128, 256 / 128), 256, 0, stream>>>(
        H, W2T, W2T, NB, (void*)tmpY2, nullptr, nullptr, nullptr, 256, 1024, 0);

    // 15. LN2 (+b2 fold, +X1 residual) -> Out f32
    ln2_kernel<<<NB, 256, 0, stream>>>(tmpY2, ffn_b2, X1f, ln2_g, ln2_b, Out);
}

// Round 5
// 335.037 us; speedup vs baseline: 2.3108x; 1.3036x over previous
//
#include <hip/hip_runtime.h>

typedef unsigned short u16;
typedef unsigned int u32;
typedef unsigned long long u64;

#define BB 8
#define LL 2048
#define DD 256
#define NB (BB * LL)      // 16384 rows per branch
#define NBR 4
#define NRT (NBR * NB)    // 65536 batched rows
#define NCH 32
#define CHL (LL / NCH)    // 64
#define CAP 64

typedef __attribute__((ext_vector_type(8))) __bf16 bf16x8;
typedef __attribute__((ext_vector_type(4))) float f32x4;

__device__ __forceinline__ float b2f(u16 u) {
    union { u32 u; float f; } x; x.u = ((u32)u) << 16; return x.f;
}
__device__ __forceinline__ u16 f2b(float f) {
    union { float f; u32 u; } x; x.f = f;
    u32 r = (x.u >> 16) & 1u;
    x.u += 0x7FFFu + r;
    return (u16)(x.u >> 16);
}
__device__ __forceinline__ float sigm(float x) { return 1.f / (1.f + __expf(-x)); }

// ------------- batched weight transpose+cast: W[K,N] f32 -> Wt[N,K] bf16 ----
struct TrArgs {
    const float* s[9];
    u16* d[9];
    int K[9], N[9];
    int beg[10];
};
__global__ void transpose_all(TrArgs a) {
    int blk = blockIdx.x;
    int i = 0;
    while (blk >= a.beg[i + 1]) ++i;
    int idx = (blk - a.beg[i]) * 256 + threadIdx.x;
    int K = a.K[i], N = a.N[i];
    if (idx >= K * N) return;
    int k = idx / N, n = idx - k * N;
    a.d[i][(size_t)n * K + k] = f2b(a.s[i][idx]);
}

// ---------------- CSR build from binary adjacency (f32, float4-vectorized) --
__global__ void csr_kernel(const float* __restrict__ Adj, int* __restrict__ csr,
                           int* __restrict__ cnt, float* __restrict__ deg) {
    int w = threadIdx.x >> 6, lane = threadIdx.x & 63;
    int row = blockIdx.x * 4 + w;                 // 0..NB-1
    const float* arow = Adj + (size_t)row * LL;
    int base = 0;
    for (int c = 0; c < LL / 256; ++c) {          // 8 iterations
        float4 v = *(const float4*)(arow + c * 256 + lane * 4);
#pragma unroll
        for (int e = 0; e < 4; ++e) {
            float f = (e == 0) ? v.x : (e == 1) ? v.y : (e == 2) ? v.z : v.w;
            bool nz = (f != 0.f);
            u64 m = __ballot(nz);
            if (nz) {
                int pos = base + __popcll(m & ((1ull << lane) - 1ull));
                if (pos < CAP) csr[(size_t)row * CAP + pos] = c * 256 + lane * 4 + e;
            }
            base += __popcll(m);
        }
    }
    if (lane == 0) {
        cnt[row] = base < CAP ? base : CAP;
        deg[row] = (float)(base < 1 ? 1 : base);
    }
}

// ------- Win GEMM with fused gather: A = permuted/masked X (f32->bf16) ------
// C[NRT,512] = A @ [Win]^T, planar store: cols 0-255 -> zbuf, 256-511 -> gbuf
__global__ __launch_bounds__(256)
void gemm_win_kernel(const float* __restrict__ X,
                     const int* __restrict__ si0, const int* __restrict__ si1,
                     const int* __restrict__ si2, const int* __restrict__ maskp,
                     const u16* __restrict__ Bt1, const u16* __restrict__ Bt2,
                     u16* __restrict__ zbuf, u16* __restrict__ gbuf)
{
    __shared__ __align__(16) u16 As[128 * 32];
    __shared__ __align__(16) u16 Bs[128 * 32];
    int tid = threadIdx.x, lane = tid & 63;
    int w = tid >> 6, wm = w >> 1, wn = w & 1;
    int rowBase = blockIdx.x * 128, colBase = blockIdx.y * 128;
    const u16* Bt = (rowBase < 3 * NB) ? Bt1 : Bt2;
    int kk = (tid & 3) << 3;

    // resolve the two staged source rows once (fixed across K-loop)
    const float* pr[2];
#pragma unroll
    for (int rep = 0; rep < 2; ++rep) {
        int rg = rowBase + rep * 64 + (tid >> 2);
        int br = rg >> 14, r = rg & (NB - 1), b = r >> 11, l = r & (LL - 1);
        const float* p = nullptr;
        if (maskp[r]) {
            int src = (br == 0) ? si0[r] : (br == 1) ? si1[r] : (br == 2) ? si2[r] : l;
            p = X + ((size_t)(b << 11) + src) * DD + kk;
        }
        pr[rep] = p;
    }

    f32x4 acc[4][4];
#pragma unroll
    for (int m = 0; m < 4; ++m)
#pragma unroll
        for (int n = 0; n < 4; ++n) acc[m][n] = (f32x4){0.f, 0.f, 0.f, 0.f};

    for (int k0 = 0; k0 < 256; k0 += 32) {
        float4 a0[2], a1[2];
#pragma unroll
        for (int rep = 0; rep < 2; ++rep) {
            if (pr[rep]) {
                a0[rep] = *(const float4*)(pr[rep] + k0);
                a1[rep] = *(const float4*)(pr[rep] + k0 + 4);
            } else {
                a0[rep] = (float4){0.f, 0.f, 0.f, 0.f};
                a1[rep] = (float4){0.f, 0.f, 0.f, 0.f};
            }
        }
#pragma unroll
        for (int rep = 0; rep < 2; ++rep) {
            int s = rep * 256 + tid;
            const u16* gb = Bt + (size_t)(colBase + (s >> 2)) * 256 + (k0 + ((s & 3) << 3));
            __builtin_amdgcn_global_load_lds((const __attribute__((address_space(1))) void*)gb,
                                             (__attribute__((address_space(3))) void*)(Bs + s * 8), 16, 0, 0);
        }
#pragma unroll
        for (int rep = 0; rep < 2; ++rep) {
            union { uint4 q; u16 h[8]; } pk;
            pk.h[0] = f2b(a0[rep].x); pk.h[1] = f2b(a0[rep].y);
            pk.h[2] = f2b(a0[rep].z); pk.h[3] = f2b(a0[rep].w);
            pk.h[4] = f2b(a1[rep].x); pk.h[5] = f2b(a1[rep].y);
            pk.h[6] = f2b(a1[rep].z); pk.h[7] = f2b(a1[rep].w);
            *(uint4*)(As + (rep * 256 + tid) * 8) = pk.q;
        }
        __syncthreads();                           // drains B DMA + A ds_write
        int kq = (lane >> 4) << 3;
        bf16x8 av[4], bw[4];
#pragma unroll
        for (int m = 0; m < 4; ++m)
            av[m] = *(const bf16x8*)(As + (wm * 64 + m * 16 + (lane & 15)) * 32 + kq);
#pragma unroll
        for (int n = 0; n < 4; ++n)
            bw[n] = *(const bf16x8*)(Bs + (wn * 64 + n * 16 + (lane & 15)) * 32 + kq);
#pragma unroll
        for (int m = 0; m < 4; ++m)
#pragma unroll
            for (int n = 0; n < 4; ++n)
                acc[m][n] = __builtin_amdgcn_mfma_f32_16x16x32_bf16(av[m], bw[n], acc[m][n], 0, 0, 0);
        __syncthreads();                           // protect LDS before next stage
    }

    u16* Cz;
    int cb;
    if (colBase < 256) { Cz = zbuf; cb = colBase; }
    else               { Cz = gbuf; cb = colBase - 256; }
    int cBase = cb + wn * 64 + (lane & 15);
    int rBase = rowBase + wm * 64 + ((lane >> 4) << 2);
#pragma unroll
    for (int m = 0; m < 4; ++m)
#pragma unroll
        for (int n = 0; n < 4; ++n)
#pragma unroll
            for (int r = 0; r < 4; ++r)
                Cz[(size_t)(rBase + m * 16 + r) * 256 + (cBase + n * 16)] = f2b(acc[m][n][r]);
}

// ---------------- generic GEMM: C[M,N] = A[M,K] @ Bt[N,K]^T -----------------
// mode 0: f32 store; mode 1: bias(f32)+relu+bf16; mode 2: plain bf16;
// mode 3: We epilogue (relu, br3 += mo4, row-mask, strided store to Yin[r,1024])
__global__ __launch_bounds__(256)
void gemm_kernel(const u16* __restrict__ A, const u16* __restrict__ Bt1,
                 const u16* __restrict__ Bt2, int splitRow,
                 void* __restrict__ Cout, const float* __restrict__ bias,
                 const int* __restrict__ maskp, const u16* __restrict__ mo4,
                 int N, int K, int mode)
{
    __shared__ __align__(16) u16 As[128 * 32];
    __shared__ __align__(16) u16 Bs[128 * 32];
    int tid = threadIdx.x;
    int lane = tid & 63;
    int w = tid >> 6, wm = w >> 1, wn = w & 1;
    int rowBase = blockIdx.x * 128, colBase = blockIdx.y * 128;
    const u16* Bt = (rowBase < splitRow) ? Bt1 : Bt2;

    f32x4 acc[4][4];
#pragma unroll
    for (int m = 0; m < 4; ++m)
#pragma unroll
        for (int n = 0; n < 4; ++n) acc[m][n] = (f32x4){0.f, 0.f, 0.f, 0.f};

    for (int k0 = 0; k0 < K; k0 += 32) {
#pragma unroll
        for (int rep = 0; rep < 2; ++rep) {
            int s = rep * 256 + tid;
            int row = s >> 2, kk = (s & 3) << 3;
            const u16* ga = A + (size_t)(rowBase + row) * K + (k0 + kk);
            const u16* gb = Bt + (size_t)(colBase + row) * K + (k0 + kk);
            __builtin_amdgcn_global_load_lds((const __attribute__((address_space(1))) void*)ga,
                                             (__attribute__((address_space(3))) void*)(As + s * 8), 16, 0, 0);
            __builtin_amdgcn_global_load_lds((const __attribute__((address_space(1))) void*)gb,
                                             (__attribute__((address_space(3))) void*)(Bs + s * 8), 16, 0, 0);
        }
        __syncthreads();
        int kq = (lane >> 4) << 3;
        bf16x8 av[4], bw[4];
#pragma unroll
        for (int m = 0; m < 4; ++m)
            av[m] = *(const bf16x8*)(As + (wm * 64 + m * 16 + (lane & 15)) * 32 + kq);
#pragma unroll
        for (int n = 0; n < 4; ++n)
            bw[n] = *(const bf16x8*)(Bs + (wn * 64 + n * 16 + (lane & 15)) * 32 + kq);
#pragma unroll
        for (int m = 0; m < 4; ++m)
#pragma unroll
            for (int n = 0; n < 4; ++n)
                acc[m][n] = __builtin_amdgcn_mfma_f32_16x16x32_bf16(av[m], bw[n], acc[m][n], 0, 0, 0);
        __syncthreads();
    }

    int cBase = colBase + wn * 64 + (lane & 15);
    int rBase = rowBase + wm * 64 + ((lane >> 4) << 2);
    if (mode == 0) {
        float* C = (float*)Cout;
#pragma unroll
        for (int m = 0; m < 4; ++m)
#pragma unroll
            for (int n = 0; n < 4; ++n)
#pragma unroll
                for (int r = 0; r < 4; ++r)
                    C[(size_t)(rBase + m * 16 + r) * N + (cBase + n * 16)] = acc[m][n][r];
    } else if (mode == 3) {
        u16* Yin = (u16*)Cout;
#pragma unroll
        for (int m = 0; m < 4; ++m)
#pragma unroll
            for (int r = 0; r < 4; ++r) {
                int gr = rBase + m * 16 + r;
                int br = gr >> 14, rr = gr & (NB - 1);
                int msk = maskp[rr];
#pragma unroll
                for (int n = 0; n < 4; ++n) {
                    int col = cBase + n * 16;
                    float v = acc[m][n][r];
                    v = v > 0.f ? v : 0.f;
                    if (br == 3) v += b2f(mo4[(size_t)gr * DD + col]);
                    v = msk ? v : 0.f;
                    Yin[(size_t)rr * 1024 + (br << 8) + col] = f2b(v);
                }
            }
    } else {
        u16* C = (u16*)Cout;
        float bz[4];
#pragma unroll
        for (int n = 0; n < 4; ++n) bz[n] = bias ? bias[cBase + n * 16] : 0.f;
#pragma unroll
        for (int m = 0; m < 4; ++m)
#pragma unroll
            for (int n = 0; n < 4; ++n)
#pragma unroll
                for (int r = 0; r < 4; ++r) {
                    float v = acc[m][n][r] + bz[n];
                    if (mode == 1) v = v > 0.f ? v : 0.f;
                    C[(size_t)(rBase + m * 16 + r) * N + (cBase + n * 16)] = f2b(v);
                }
    }
}

// ---------------- batched chunked EMA scan (planar z/g, 2 dims/thread) ------
__global__ void scan_carry_kernel(const u16* __restrict__ z4, const float* __restrict__ alog1,
                                  const float* __restrict__ alog2, float* __restrict__ carry) {
    int bid = blockIdx.x;                          // (br,b,c)
    int br = bid >> 8, b = (bid >> 5) & 7, c = bid & 31;
    int d0 = threadIdx.x * 2;                      // 128 threads
    const float* al = (br < 3) ? alog1 : alog2;
    float aA = sigm(al[d0]), aB = sigm(al[d0 + 1]);
    float hA = 0.f, hB = 0.f;
    const u16* zp = z4 + ((size_t)(br * NB + b * LL + c * CHL) * DD) + d0;
    for (int t = 0; t < CHL; ++t) {
        u32 v = *(const u32*)(zp + (size_t)t * DD);
        hA = aA * hA + (1.f - aA) * b2f((u16)v);
        hB = aB * hB + (1.f - aB) * b2f((u16)(v >> 16));
    }
    carry[(size_t)bid * DD + d0] = hA;
    carry[(size_t)bid * DD + d0 + 1] = hB;
}

__global__ void scan_combine_kernel(const float* __restrict__ carry, const float* __restrict__ alog1,
                                    const float* __restrict__ alog2, float* __restrict__ start) {
    int br = blockIdx.x >> 3, b = blockIdx.x & 7;  // grid 32
    int d0 = threadIdx.x * 2;
    const float* al = (br < 3) ? alog1 : alog2;
    float aA = sigm(al[d0]), aB = sigm(al[d0 + 1]);
    float aPA = aA, aPB = aB;
#pragma unroll
    for (int i = 0; i < 6; ++i) { aPA *= aPA; aPB *= aPB; }   // a^64
    float hA = 0.f, hB = 0.f;
    for (int c = 0; c < NCH; ++c) {
        size_t idx = ((size_t)(br * 256 + b * 32 + c)) * DD + d0;
        start[idx] = hA; start[idx + 1] = hB;
        hA = carry[idx] + aPA * hA;
        hB = carry[idx + 1] + aPB * hB;
    }
}

__global__ void scan_apply_kernel(const u16* __restrict__ z4, const u16* __restrict__ g4,
                                  const float* __restrict__ alog1, const float* __restrict__ alog2,
                                  const float* __restrict__ start, u16* __restrict__ U4) {
    int bid = blockIdx.x;
    int br = bid >> 8, b = (bid >> 5) & 7, c = bid & 31;
    int d0 = threadIdx.x * 2;
    const float* al = (br < 3) ? alog1 : alog2;
    float aA = sigm(al[d0]), aB = sigm(al[d0 + 1]);
    float hA = start[(size_t)bid * DD + d0];
    float hB = start[(size_t)bid * DD + d0 + 1];
    size_t rowOff = ((size_t)(br * NB + b * LL + c * CHL)) * DD + d0;
    const u16* zp = z4 + rowOff;
    const u16* gp = g4 + rowOff;
    u16* up = U4 + rowOff;
    for (int t = 0; t < CHL; ++t) {
        u32 zv = *(const u32*)(zp + (size_t)t * DD);
        u32 gv = *(const u32*)(gp + (size_t)t * DD);
        float gA = b2f((u16)gv), gB = b2f((u16)(gv >> 16));
        hA = aA * hA + (1.f - aA) * b2f((u16)zv);
        hB = aB * hB + (1.f - aB) * b2f((u16)(zv >> 16));
        u32 o = (u32)f2b(hA * gA * sigm(gA)) | ((u32)f2b(hB * gB * sigm(gB)) << 16);
        *(u32*)(up + (size_t)t * DD) = o;
    }
}

// ------- batched sparse aggregation, vectorized (16B loads, 8 rows/block) ---
__global__ void agg4_kernel(const u16* __restrict__ mo4, const float* __restrict__ X,
                            const int* __restrict__ ri0, const int* __restrict__ ri1,
                            const int* __restrict__ ri2, const int* __restrict__ csr,
                            const int* __restrict__ cnt, const float* __restrict__ deg,
                            u16* __restrict__ P4) {
    int tr = threadIdx.x & 31;        // dim group: dims 8*tr..8*tr+7
    int rsub = threadIdx.x >> 5;      // 0..7
    int rg = blockIdx.x * 8 + rsub;   // 0..NRT-1
    int br = rg >> 14, r = rg & (NB - 1), b = r >> 11;
    const int* ri = (br == 0) ? ri0 : (br == 1) ? ri1 : ri2;
    int n = cnt[r];
    float acc[8] = {0.f, 0.f, 0.f, 0.f, 0.f, 0.f, 0.f, 0.f};
    if (br < 3) {
        for (int i = 0; i < n; ++i) {
            int j = csr[(size_t)r * CAP + i];
            int srow = ri[(b << 11) + j];
            union { uint4 q; u16 h[8]; } v;
            v.q = *(const uint4*)(mo4 + ((size_t)(br * NB + (b << 11) + srow)) * DD + tr * 8);
#pragma unroll
            for (int k = 0; k < 8; ++k) acc[k] += b2f(v.h[k]);
        }
    } else {
        for (int i = 0; i < n; ++i) {
            int j = csr[(size_t)r * CAP + i];
            const float* src = X + ((size_t)(b << 11) + j) * DD + tr * 8;
            float4 v0 = *(const float4*)src;
            float4 v1 = *(const float4*)(src + 4);
            acc[0] += v0.x; acc[1] += v0.y; acc[2] += v0.z; acc[3] += v0.w;
            acc[4] += v1.x; acc[5] += v1.y; acc[6] += v1.z; acc[7] += v1.w;
        }
    }
    float inv = 1.f / deg[r];
    union { uint4 q; u16 h[8]; } o;
#pragma unroll
    for (int k = 0; k < 8; ++k) o.h[k] = f2b(acc[k] * inv);
    *(uint4*)(P4 + (size_t)rg * DD + tr * 8) = o.q;
}

// ---------------- layernorm (+bias fold, +residual) -------------------------
__device__ __forceinline__ float blk_sum(float v, float* sm) {
#pragma unroll
    for (int o = 32; o > 0; o >>= 1) v += __shfl_down(v, o, 64);
    int lane = threadIdx.x & 63, w = threadIdx.x >> 6;
    __syncthreads();
    if (lane == 0) sm[w] = v;
    __syncthreads();
    return sm[0] + sm[1] + sm[2] + sm[3];
}

__global__ void ln1_kernel(const float* __restrict__ Yt, const float* __restrict__ bvp,
                           const float* __restrict__ X, const float* __restrict__ gp,
                           const float* __restrict__ bp, float* __restrict__ X1f,
                           u16* __restrict__ X1b) {
    __shared__ float sm[4];
    int r = blockIdx.x, d = threadIdx.x;
    float x = Yt[(size_t)r * DD + d] + bvp[d];
    float mu = blk_sum(x, sm) * (1.f / DD);
    float dx = x - mu;
    float var = blk_sum(dx * dx, sm) * (1.f / DD);
    float y = dx * rsqrtf(var + 1e-5f) * gp[d] + bp[d];
    float x1 = X[(size_t)r * DD + d] + y;
    X1f[(size_t)r * DD + d] = x1;
    X1b[(size_t)r * DD + d] = f2b(x1);
}

__global__ void ln2_kernel(const float* __restrict__ Y2, const float* __restrict__ b2p,
                           const float* __restrict__ X1f, const float* __restrict__ gp,
                           const float* __restrict__ bp, float* __restrict__ Out) {
    __shared__ float sm[4];
    int r = blockIdx.x, d = threadIdx.x;
    float x = Y2[(size_t)r * DD + d] + b2p[d];
    float mu = blk_sum(x, sm) * (1.f / DD);
    float dx = x - mu;
    float var = blk_sum(dx * dx, sm) * (1.f / DD);
    float y = dx * rsqrtf(var + 1e-5f) * gp[d] + bp[d];
    Out[(size_t)r * DD + d] = X1f[(size_t)r * DD + d] + y;
}

// ============================================================================
extern "C" void kernel_launch(void* const* d_in, const int* in_sizes, int n_in,
                              void* d_out, int out_size, void* d_ws, size_t ws_size,
                              hipStream_t stream) {
    const float* X      = (const float*)d_in[0];
    const int* maskp    = (const int*)d_in[1];
    const float* Adj    = (const float*)d_in[2];
    const int* si[3]    = { (const int*)d_in[3], (const int*)d_in[5], (const int*)d_in[7] };
    const int* ri[3]    = { (const int*)d_in[4], (const int*)d_in[6], (const int*)d_in[8] };
    const float* gm1_Win  = (const float*)d_in[9];
    const float* gm1_alog = (const float*)d_in[10];
    const float* gm1_Wout = (const float*)d_in[11];
    const float* gm2_We   = (const float*)d_in[12];
    const float* gm_Win   = (const float*)d_in[13];
    const float* gm_alog  = (const float*)d_in[14];
    const float* gm_Wout  = (const float*)d_in[15];
    const float* gm_We    = (const float*)d_in[16];
    const float* ln1_g    = (const float*)d_in[17];
    const float* ln1_b    = (const float*)d_in[18];
    const float* ln2_g    = (const float*)d_in[19];
    const float* ln2_b    = (const float*)d_in[20];
    const float* ffn_W1   = (const float*)d_in[21];
    const float* ffn_b1   = (const float*)d_in[22];
    const float* ffn_W2   = (const float*)d_in[23];
    const float* ffn_b2   = (const float*)d_in[24];
    const float* Wv       = (const float*)d_in[25];
    const float* bv       = (const float*)d_in[26];
    float* Out = (float*)d_out;

    char* ws = (char*)d_ws;
    size_t off = 0;
    auto alloc = [&](size_t bytes) { size_t o = off; off += (bytes + 255) & ~(size_t)255; return o; };

    u16* WinT1 = (u16*)(ws + alloc((size_t)512 * 256 * 2));
    u16* WoutT1 = (u16*)(ws + alloc((size_t)256 * 256 * 2));
    u16* WeT1 = (u16*)(ws + alloc((size_t)256 * 256 * 2));
    u16* WinT = (u16*)(ws + alloc((size_t)512 * 256 * 2));
    u16* WoutT = (u16*)(ws + alloc((size_t)256 * 256 * 2));
    u16* WeT = (u16*)(ws + alloc((size_t)256 * 256 * 2));
    u16* WvT = (u16*)(ws + alloc((size_t)256 * 1024 * 2));
    u16* W1T = (u16*)(ws + alloc((size_t)1024 * 256 * 2));
    u16* W2T = (u16*)(ws + alloc((size_t)256 * 1024 * 2));
    int* csr = (int*)(ws + alloc((size_t)NB * CAP * 4));
    int* cnt = (int*)(ws + alloc((size_t)NB * 4));
    float* deg = (float*)(ws + alloc((size_t)NB * 4));
    float* carry = (float*)(ws + alloc((size_t)NBR * BB * NCH * DD * 4));
    float* start = (float*)(ws + alloc((size_t)NBR * BB * NCH * DD * 4));
    u16* zbuf = (u16*)(ws + alloc((size_t)NRT * DD * 2));   // 33.6 MB
    u16* gbuf = (u16*)(ws + alloc((size_t)NRT * DD * 2));
    u16* U4   = (u16*)(ws + alloc((size_t)NRT * DD * 2));
    u16* mo4  = (u16*)(ws + alloc((size_t)NRT * DD * 2));
    u16* P4   = (u16*)(ws + alloc((size_t)NRT * DD * 2));
    u16* Yin  = (u16*)(ws + alloc((size_t)NB * 1024 * 2));
    float* tmpY  = (float*)(ws + alloc((size_t)NB * DD * 4));
    float* X1f   = (float*)(ws + alloc((size_t)NB * DD * 4));
    u16* X1b     = (u16*)(ws + alloc((size_t)NB * DD * 2));
    u16* H       = (u16*)(ws + alloc((size_t)NB * 1024 * 2));
    float* tmpY2 = (float*)(ws + alloc((size_t)NB * DD * 4));
    (void)ws_size; (void)in_sizes; (void)n_in; (void)out_size;

    // 1. all weight transposes in one launch
    TrArgs ta;
    const float* srcs[9] = { gm1_Win, gm1_Wout, gm2_We, gm_Win, gm_Wout, gm_We, Wv, ffn_W1, ffn_W2 };
    u16* dsts[9] = { WinT1, WoutT1, WeT1, WinT, WoutT, WeT, WvT, W1T, W2T };
    int Ks[9] = { 256, 256, 256, 256, 256, 256, 1024, 256, 1024 };
    int Ns[9] = { 512, 256, 256, 512, 256, 256, 256, 1024, 256 };
    int cum = 0;
    for (int i = 0; i < 9; ++i) {
        ta.s[i] = srcs[i]; ta.d[i] = dsts[i]; ta.K[i] = Ks[i]; ta.N[i] = Ns[i];
        ta.beg[i] = cum; cum += (Ks[i] * Ns[i]) / 256;
    }
    ta.beg[9] = cum;
    transpose_all<<<cum, 256, 0, stream>>>(ta);

    // 2. CSR
    csr_kernel<<<NB / 4, 256, 0, stream>>>(Adj, csr, cnt, deg);

    // 3. Win GEMM with fused gather -> planar z/g bf16
    gemm_win_kernel<<<dim3(NRT / 128, 512 / 128), 256, 0, stream>>>(
        X, si[0], si[1], si[2], maskp, WinT1, WinT, zbuf, gbuf);

    // 4-6. batched scan (2 dims/thread)
    scan_carry_kernel<<<NBR * BB * NCH, 128, 0, stream>>>(zbuf, gm1_alog, gm_alog, carry);
    scan_combine_kernel<<<NBR * BB, 128, 0, stream>>>(carry, gm1_alog, gm_alog, start);
    scan_apply_kernel<<<NBR * BB * NCH, 128, 0, stream>>>(zbuf, gbuf, gm1_alog, gm_alog, start, U4);

    // 7. Wout GEMM: [NRT,256] @ [256,256] -> mo4 bf16
    gemm_kernel<<<dim3(NRT / 128, 256 / 128), 256, 0, stream>>>(
        U4, WoutT1, WoutT, 3 * NB, (void*)mo4, nullptr, nullptr, nullptr, 256, 256, 2);

    // 8. batched aggregation -> P4 bf16 (br3 reads X directly)
    agg4_kernel<<<NRT / 8, 256, 0, stream>>>(mo4, X, ri[0], ri[1], ri[2], csr, cnt, deg, P4);

    // 9. We GEMM + fused epilogue (relu, br3 += mo4, mask, slot-write) -> Yin
    gemm_kernel<<<dim3(NRT / 128, 256 / 128), 256, 0, stream>>>(
        P4, WeT1, WeT, 3 * NB, (void*)Yin, nullptr, maskp, mo4, 256, 256, 3);

    // 10. Wv GEMM: [NB,1024] @ [1024,256] -> tmpY f32
    gemm_kernel<<<dim3(NB / 128, 256 / 128), 256, 0, stream>>>(
        Yin, WvT, WvT, NB, (void*)tmpY, nullptr, nullptr, nullptr, 256, 1024, 0);

    // 11. LN1 (+bv fold, +X residual)
    ln1_kernel<<<NB, 256, 0, stream>>>(tmpY, bv, X, ln1_g, ln1_b, X1f, X1b);

    // 12. FFN1: [NB,256] @ [256,1024] +b1, relu -> H bf16
    gemm_kernel<<<dim3(NB / 128, 1024 / 128), 256, 0, stream>>>(
        X1b, W1T, W1T, NB, (void*)H, ffn_b1, nullptr, nullptr, 1024, 256, 1);

    // 13. FFN2: [NB,1024] @ [1024,256] -> tmpY2 f32
    gemm_kernel<<<dim3(NB / 128, 256 / 128), 256, 0, stream>>>(
        H, W2T, W2T, NB, (void*)tmpY2, nullptr, nullptr, nullptr, 256, 1024, 0);

    // 14. LN2 (+b2 fold, +X1 residual) -> Out f32
    ln2_kernel<<<NB, 256, 0, stream>>>(tmpY2, ffn_b2, X1f, ln2_g, ln2_b, Out);
}

// Round 6
// 296.979 us; speedup vs baseline: 2.6069x; 1.1281x over previous
//
#include <hip/hip_runtime.h>

typedef unsigned short u16;
typedef unsigned int u32;
typedef unsigned long long u64;

#define BB 8
#define LL 2048
#define DD 256
#define NB (BB * LL)      // 16384 rows per branch
#define NBR 4
#define NRT (NBR * NB)    // 65536 batched rows
#define NCH 32
#define CHL (LL / NCH)    // 64
#define CAP 64

typedef __attribute__((ext_vector_type(8))) __bf16 bf16x8;
typedef __attribute__((ext_vector_type(4))) float f32x4;

__device__ __forceinline__ float b2f(u16 u) {
    union { u32 u; float f; } x; x.u = ((u32)u) << 16; return x.f;
}
__device__ __forceinline__ u16 f2b(float f) {
    union { float f; u32 u; } x; x.f = f;
    u32 r = (x.u >> 16) & 1u;
    x.u += 0x7FFFu + r;
    return (u16)(x.u >> 16);
}
__device__ __forceinline__ float sigm(float x) { return 1.f / (1.f + __expf(-x)); }

// ---- batched weight transpose/copy + cast: f32 -> bf16 ---------------------
struct TrArgs {
    const float* s[9];
    u16* d[9];
    int K[9], N[9], tr[9];
    int beg[10];
};
__global__ void transpose_all(TrArgs a) {
    int blk = blockIdx.x;
    int i = 0;
    while (blk >= a.beg[i + 1]) ++i;
    int idx = (blk - a.beg[i]) * 256 + threadIdx.x;
    int K = a.K[i], N = a.N[i];
    if (idx >= K * N) return;
    if (a.tr[i]) {
        int k = idx / N, n = idx - k * N;
        a.d[i][(size_t)n * K + k] = f2b(a.s[i][idx]);
    } else {
        a.d[i][idx] = f2b(a.s[i][idx]);
    }
}

// ---------------- CSR build from binary adjacency (f32, float4-vectorized) --
__global__ void csr_kernel(const float* __restrict__ Adj, int* __restrict__ csr,
                           int* __restrict__ cnt, float* __restrict__ deg) {
    int w = threadIdx.x >> 6, lane = threadIdx.x & 63;
    int row = blockIdx.x * 4 + w;                 // 0..NB-1
    const float* arow = Adj + (size_t)row * LL;
    int base = 0;
    for (int c = 0; c < LL / 256; ++c) {          // 8 iterations
        float4 v = *(const float4*)(arow + c * 256 + lane * 4);
#pragma unroll
        for (int e = 0; e < 4; ++e) {
            float f = (e == 0) ? v.x : (e == 1) ? v.y : (e == 2) ? v.z : v.w;
            bool nz = (f != 0.f);
            u64 m = __ballot(nz);
            if (nz) {
                int pos = base + __popcll(m & ((1ull << lane) - 1ull));
                if (pos < CAP) csr[(size_t)row * CAP + pos] = c * 256 + lane * 4 + e;
            }
            base += __popcll(m);
        }
    }
    if (lane == 0) {
        cnt[row] = base < CAP ? base : CAP;
        deg[row] = (float)(base < 1 ? 1 : base);
    }
}

// ------- Win GEMM with fused gather; also taps out masked-X (bf16) ----------
// C[NRT,512] = gathered/masked X @ Win^T, planar: cols 0-255 -> zbuf, rest -> gbuf
__global__ __launch_bounds__(256)
void gemm_win_kernel(const float* __restrict__ X,
                     const int* __restrict__ si0, const int* __restrict__ si1,
                     const int* __restrict__ si2, const int* __restrict__ maskp,
                     const u16* __restrict__ Bt1, const u16* __restrict__ Bt2,
                     u16* __restrict__ zbuf, u16* __restrict__ gbuf,
                     u16* __restrict__ Xm)
{
    __shared__ __align__(16) u16 As[128 * 32];
    __shared__ __align__(16) u16 Bs[128 * 32];
    int tid = threadIdx.x, lane = tid & 63;
    int w = tid >> 6, wm = w >> 1, wn = w & 1;
    int rowBase = blockIdx.x * 128, colBase = blockIdx.y * 128;
    const u16* Bt = (rowBase < 3 * NB) ? Bt1 : Bt2;
    int kk = (tid & 3) << 3;
    bool tap = (rowBase >= 3 * NB) && (colBase == 0);

    const float* pr[2];
#pragma unroll
    for (int rep = 0; rep < 2; ++rep) {
        int rg = rowBase + rep * 64 + (tid >> 2);
        int br = rg >> 14, r = rg & (NB - 1), b = r >> 11, l = r & (LL - 1);
        const float* p = nullptr;
        if (maskp[r]) {
            int src = (br == 0) ? si0[r] : (br == 1) ? si1[r] : (br == 2) ? si2[r] : l;
            p = X + ((size_t)(b << 11) + src) * DD + kk;
        }
        pr[rep] = p;
    }

    f32x4 acc[4][4];
#pragma unroll
    for (int m = 0; m < 4; ++m)
#pragma unroll
        for (int n = 0; n < 4; ++n) acc[m][n] = (f32x4){0.f, 0.f, 0.f, 0.f};

    for (int k0 = 0; k0 < 256; k0 += 32) {
        float4 a0[2], a1[2];
#pragma unroll
        for (int rep = 0; rep < 2; ++rep) {
            if (pr[rep]) {
                a0[rep] = *(const float4*)(pr[rep] + k0);
                a1[rep] = *(const float4*)(pr[rep] + k0 + 4);
            } else {
                a0[rep] = (float4){0.f, 0.f, 0.f, 0.f};
                a1[rep] = (float4){0.f, 0.f, 0.f, 0.f};
            }
        }
#pragma unroll
        for (int rep = 0; rep < 2; ++rep) {
            int s = rep * 256 + tid;
            const u16* gb = Bt + (size_t)(colBase + (s >> 2)) * 256 + (k0 + ((s & 3) << 3));
            __builtin_amdgcn_global_load_lds((const __attribute__((address_space(1))) void*)gb,
                                             (__attribute__((address_space(3))) void*)(Bs + s * 8), 16, 0, 0);
        }
#pragma unroll
        for (int rep = 0; rep < 2; ++rep) {
            union { uint4 q; u16 h[8]; } pk;
            pk.h[0] = f2b(a0[rep].x); pk.h[1] = f2b(a0[rep].y);
            pk.h[2] = f2b(a0[rep].z); pk.h[3] = f2b(a0[rep].w);
            pk.h[4] = f2b(a1[rep].x); pk.h[5] = f2b(a1[rep].y);
            pk.h[6] = f2b(a1[rep].z); pk.h[7] = f2b(a1[rep].w);
            *(uint4*)(As + (rep * 256 + tid) * 8) = pk.q;
            if (tap) {
                int rL = rowBase - 3 * NB + ((rep * 256 + tid) >> 2);
                *(uint4*)(Xm + (size_t)rL * DD + k0 + kk) = pk.q;
            }
        }
        __syncthreads();                           // drains B DMA + A ds_write
        int kq = (lane >> 4) << 3;
        bf16x8 av[4], bw[4];
#pragma unroll
        for (int m = 0; m < 4; ++m)
            av[m] = *(const bf16x8*)(As + (wm * 64 + m * 16 + (lane & 15)) * 32 + kq);
#pragma unroll
        for (int n = 0; n < 4; ++n)
            bw[n] = *(const bf16x8*)(Bs + (wn * 64 + n * 16 + (lane & 15)) * 32 + kq);
#pragma unroll
        for (int m = 0; m < 4; ++m)
#pragma unroll
            for (int n = 0; n < 4; ++n)
                acc[m][n] = __builtin_amdgcn_mfma_f32_16x16x32_bf16(av[m], bw[n], acc[m][n], 0, 0, 0);
        __syncthreads();
    }

    u16* Cz;
    int cb;
    if (colBase < 256) { Cz = zbuf; cb = colBase; }
    else               { Cz = gbuf; cb = colBase - 256; }
    int cBase = cb + wn * 64 + (lane & 15);
    int rBase = rowBase + wm * 64 + ((lane >> 4) << 2);
#pragma unroll
    for (int m = 0; m < 4; ++m)
#pragma unroll
        for (int n = 0; n < 4; ++n)
#pragma unroll
            for (int r = 0; r < 4; ++r)
                Cz[(size_t)(rBase + m * 16 + r) * 256 + (cBase + n * 16)] = f2b(acc[m][n][r]);
}

// --------- generic GEMM: C[M,N] = A[M,K] @ Bt^T, 3-way row-group weights ----
// mode 0: f32 store; mode 1: bias(f32)+relu+bf16; mode 2: plain bf16
__global__ __launch_bounds__(256)
void gemm_kernel(const u16* __restrict__ A, const u16* __restrict__ Bt1,
                 const u16* __restrict__ Bt2, const u16* __restrict__ Bt3,
                 int split1, int split2,
                 void* __restrict__ Cout, const float* __restrict__ bias,
                 int N, int K, int mode)
{
    __shared__ __align__(16) u16 As[128 * 32];
    __shared__ __align__(16) u16 Bs[128 * 32];
    int tid = threadIdx.x;
    int lane = tid & 63;
    int w = tid >> 6, wm = w >> 1, wn = w & 1;
    int rowBase = blockIdx.x * 128, colBase = blockIdx.y * 128;
    const u16* Bt = (rowBase < split1) ? Bt1 : (rowBase < split2) ? Bt2 : Bt3;

    f32x4 acc[4][4];
#pragma unroll
    for (int m = 0; m < 4; ++m)
#pragma unroll
        for (int n = 0; n < 4; ++n) acc[m][n] = (f32x4){0.f, 0.f, 0.f, 0.f};

    for (int k0 = 0; k0 < K; k0 += 32) {
#pragma unroll
        for (int rep = 0; rep < 2; ++rep) {
            int s = rep * 256 + tid;
            int row = s >> 2, kk = (s & 3) << 3;
            const u16* ga = A + (size_t)(rowBase + row) * K + (k0 + kk);
            const u16* gb = Bt + (size_t)(colBase + row) * K + (k0 + kk);
            __builtin_amdgcn_global_load_lds((const __attribute__((address_space(1))) void*)ga,
                                             (__attribute__((address_space(3))) void*)(As + s * 8), 16, 0, 0);
            __builtin_amdgcn_global_load_lds((const __attribute__((address_space(1))) void*)gb,
                                             (__attribute__((address_space(3))) void*)(Bs + s * 8), 16, 0, 0);
        }
        __syncthreads();
        int kq = (lane >> 4) << 3;
        bf16x8 av[4], bw[4];
#pragma unroll
        for (int m = 0; m < 4; ++m)
            av[m] = *(const bf16x8*)(As + (wm * 64 + m * 16 + (lane & 15)) * 32 + kq);
#pragma unroll
        for (int n = 0; n < 4; ++n)
            bw[n] = *(const bf16x8*)(Bs + (wn * 64 + n * 16 + (lane & 15)) * 32 + kq);
#pragma unroll
        for (int m = 0; m < 4; ++m)
#pragma unroll
            for (int n = 0; n < 4; ++n)
                acc[m][n] = __builtin_amdgcn_mfma_f32_16x16x32_bf16(av[m], bw[n], acc[m][n], 0, 0, 0);
        __syncthreads();
    }

    int cBase = colBase + wn * 64 + (lane & 15);
    int rBase = rowBase + wm * 64 + ((lane >> 4) << 2);
    if (mode == 0) {
        float* C = (float*)Cout;
#pragma unroll
        for (int m = 0; m < 4; ++m)
#pragma unroll
            for (int n = 0; n < 4; ++n)
#pragma unroll
                for (int r = 0; r < 4; ++r)
                    C[(size_t)(rBase + m * 16 + r) * N + (cBase + n * 16)] = acc[m][n][r];
    } else {
        u16* C = (u16*)Cout;
        float bz[4];
#pragma unroll
        for (int n = 0; n < 4; ++n) bz[n] = bias ? bias[cBase + n * 16] : 0.f;
#pragma unroll
        for (int m = 0; m < 4; ++m)
#pragma unroll
            for (int n = 0; n < 4; ++n)
#pragma unroll
                for (int r = 0; r < 4; ++r) {
                    float v = acc[m][n][r] + bz[n];
                    if (mode == 1) v = v > 0.f ? v : 0.f;
                    C[(size_t)(rBase + m * 16 + r) * N + (cBase + n * 16)] = f2b(v);
                }
    }
}

// ---------------- batched chunked EMA scan (planar z/g, 2 dims/thread) ------
__global__ void scan_carry_kernel(const u16* __restrict__ z4, const float* __restrict__ alog1,
                                  const float* __restrict__ alog2, float* __restrict__ carry) {
    int bid = blockIdx.x;                          // (br,b,c)
    int br = bid >> 8, b = (bid >> 5) & 7, c = bid & 31;
    int d0 = threadIdx.x * 2;                      // 128 threads
    const float* al = (br < 3) ? alog1 : alog2;
    float aA = sigm(al[d0]), aB = sigm(al[d0 + 1]);
    float hA = 0.f, hB = 0.f;
    const u16* zp = z4 + ((size_t)(br * NB + b * LL + c * CHL) * DD) + d0;
    for (int t = 0; t < CHL; ++t) {
        u32 v = *(const u32*)(zp + (size_t)t * DD);
        hA = aA * hA + (1.f - aA) * b2f((u16)v);
        hB = aB * hB + (1.f - aB) * b2f((u16)(v >> 16));
    }
    carry[(size_t)bid * DD + d0] = hA;
    carry[(size_t)bid * DD + d0 + 1] = hB;
}

__global__ void scan_combine_kernel(const float* __restrict__ carry, const float* __restrict__ alog1,
                                    const float* __restrict__ alog2, float* __restrict__ start) {
    int br = blockIdx.x >> 3, b = blockIdx.x & 7;  // grid 32
    int d0 = threadIdx.x * 2;
    const float* al = (br < 3) ? alog1 : alog2;
    float aA = sigm(al[d0]), aB = sigm(al[d0 + 1]);
    float aPA = aA, aPB = aB;
#pragma unroll
    for (int i = 0; i < 6; ++i) { aPA *= aPA; aPB *= aPB; }   // a^64
    float hA = 0.f, hB = 0.f;
    for (int c = 0; c < NCH; ++c) {
        size_t idx = ((size_t)(br * 256 + b * 32 + c)) * DD + d0;
        start[idx] = hA; start[idx + 1] = hB;
        hA = carry[idx] + aPA * hA;
        hB = carry[idx + 1] + aPB * hB;
    }
}

__global__ void scan_apply_kernel(const u16* __restrict__ z4, const u16* __restrict__ g4,
                                  const float* __restrict__ alog1, const float* __restrict__ alog2,
                                  const float* __restrict__ start, u16* __restrict__ U4) {
    int bid = blockIdx.x;
    int br = bid >> 8, b = (bid >> 5) & 7, c = bid & 31;
    int d0 = threadIdx.x * 2;
    const float* al = (br < 3) ? alog1 : alog2;
    float aA = sigm(al[d0]), aB = sigm(al[d0 + 1]);
    float hA = start[(size_t)bid * DD + d0];
    float hB = start[(size_t)bid * DD + d0 + 1];
    size_t rowOff = ((size_t)(br * NB + b * LL + c * CHL)) * DD + d0;
    const u16* zp = z4 + rowOff;
    const u16* gp = g4 + rowOff;
    u16* up = U4 + rowOff;
    for (int t = 0; t < CHL; ++t) {
        u32 zv = *(const u32*)(zp + (size_t)t * DD);
        u32 gv = *(const u32*)(gp + (size_t)t * DD);
        float gA = b2f((u16)gv), gB = b2f((u16)(gv >> 16));
        hA = aA * hA + (1.f - aA) * b2f((u16)zv);
        hB = aB * hB + (1.f - aB) * b2f((u16)(zv >> 16));
        u32 o = (u32)f2b(hA * gA * sigm(gA)) | ((u32)f2b(hB * gB * sigm(gB)) << 16);
        *(u32*)(up + (size_t)t * DD) = o;
    }
}

// --- batched agg (fused relu+mask+br3-mamba-add), writes Yin slots directly -
// V5 layout: rows [0,3NB)=U@Wc1 (br<3); [3NB,4NB)=U3@Wout (br3 mamba);
//            [4NB,5NB)=Xm@We2 (br3 agg input)
__global__ void agg4_kernel(const u16* __restrict__ V5,
                            const int* __restrict__ ri0, const int* __restrict__ ri1,
                            const int* __restrict__ ri2, const int* __restrict__ csr,
                            const int* __restrict__ cnt, const float* __restrict__ deg,
                            const int* __restrict__ maskp, u16* __restrict__ Yin) {
    int tr = threadIdx.x & 31;        // dims 8*tr..8*tr+7
    int rsub = threadIdx.x >> 5;      // 0..7
    int rg = blockIdx.x * 8 + rsub;   // 0..NRT-1
    int br = rg >> 14, r = rg & (NB - 1), b = r >> 11;
    int n = cnt[r];
    float acc[8] = {0.f, 0.f, 0.f, 0.f, 0.f, 0.f, 0.f, 0.f};
    if (br < 3) {
        const int* ri = (br == 0) ? ri0 : (br == 1) ? ri1 : ri2;
        for (int i = 0; i < n; ++i) {
            int j = csr[(size_t)r * CAP + i];
            int srow = ri[(b << 11) + j];
            union { uint4 q; u16 h[8]; } v;
            v.q = *(const uint4*)(V5 + ((size_t)(br * NB + (b << 11) + srow)) * DD + tr * 8);
#pragma unroll
            for (int k = 0; k < 8; ++k) acc[k] += b2f(v.h[k]);
        }
    } else {
        for (int i = 0; i < n; ++i) {
            int j = csr[(size_t)r * CAP + i];
            union { uint4 q; u16 h[8]; } v;
            v.q = *(const uint4*)(V5 + ((size_t)(4 * NB + (b << 11) + j)) * DD + tr * 8);
#pragma unroll
            for (int k = 0; k < 8; ++k) acc[k] += b2f(v.h[k]);
        }
    }
    float inv = 1.f / deg[r];
    int msk = maskp[r];
    union { uint4 q; u16 h[8]; } mo;
    if (br == 3) mo.q = *(const uint4*)(V5 + ((size_t)(3 * NB + r)) * DD + tr * 8);
    union { uint4 q; u16 h[8]; } o;
#pragma unroll
    for (int k = 0; k < 8; ++k) {
        float v = acc[k] * inv;
        v = v > 0.f ? v : 0.f;
        if (br == 3) v += b2f(mo.h[k]);
        v = msk ? v : 0.f;
        o.h[k] = f2b(v);
    }
    *(uint4*)(Yin + (size_t)r * 1024 + (br << 8) + tr * 8) = o.q;
}

// ---------------- layernorm, wave-per-row (float4, shfl_xor butterfly) ------
__global__ void ln1_kernel(const float* __restrict__ Yt, const float* __restrict__ bvp,
                           const float* __restrict__ X, const float* __restrict__ gp,
                           const float* __restrict__ bp, float* __restrict__ X1f,
                           u16* __restrict__ X1b) {
    int wv = threadIdx.x >> 6, lane = threadIdx.x & 63;
    int r = blockIdx.x * 4 + wv;
    int d0 = lane << 2;
    float4 yv = *(const float4*)(Yt + (size_t)r * DD + d0);
    float4 bb = *(const float4*)(bvp + d0);
    float x[4] = { yv.x + bb.x, yv.y + bb.y, yv.z + bb.z, yv.w + bb.w };
    float s = x[0] + x[1] + x[2] + x[3];
#pragma unroll
    for (int o = 32; o > 0; o >>= 1) s += __shfl_xor(s, o, 64);
    float mu = s * (1.f / DD);
    float dx[4], ss = 0.f;
#pragma unroll
    for (int k = 0; k < 4; ++k) { dx[k] = x[k] - mu; ss += dx[k] * dx[k]; }
#pragma unroll
    for (int o = 32; o > 0; o >>= 1) ss += __shfl_xor(ss, o, 64);
    float rstd = rsqrtf(ss * (1.f / DD) + 1e-5f);
    float4 g4 = *(const float4*)(gp + d0);
    float4 b4 = *(const float4*)(bp + d0);
    float4 xv = *(const float4*)(X + (size_t)r * DD + d0);
    float gg[4] = { g4.x, g4.y, g4.z, g4.w };
    float bz[4] = { b4.x, b4.y, b4.z, b4.w };
    float xx[4] = { xv.x, xv.y, xv.z, xv.w };
    float o4[4];
    union { u64 q; u16 h[4]; } pk;
#pragma unroll
    for (int k = 0; k < 4; ++k) {
        float y = dx[k] * rstd * gg[k] + bz[k];
        o4[k] = xx[k] + y;
        pk.h[k] = f2b(o4[k]);
    }
    *(float4*)(X1f + (size_t)r * DD + d0) = (float4){o4[0], o4[1], o4[2], o4[3]};
    *(u64*)(X1b + (size_t)r * DD + d0) = pk.q;
}

__global__ void ln2_kernel(const float* __restrict__ Y2, const float* __restrict__ b2p,
                           const float* __restrict__ X1f, const float* __restrict__ gp,
                           const float* __restrict__ bp, float* __restrict__ Out) {
    int wv = threadIdx.x >> 6, lane = threadIdx.x & 63;
    int r = blockIdx.x * 4 + wv;
    int d0 = lane << 2;
    float4 yv = *(const float4*)(Y2 + (size_t)r * DD + d0);
    float4 bb = *(const float4*)(b2p + d0);
    float x[4] = { yv.x + bb.x, yv.y + bb.y, yv.z + bb.z, yv.w + bb.w };
    float s = x[0] + x[1] + x[2] + x[3];
#pragma unroll
    for (int o = 32; o > 0; o >>= 1) s += __shfl_xor(s, o, 64);
    float mu = s * (1.f / DD);
    float dx[4], ss = 0.f;
#pragma unroll
    for (int k = 0; k < 4; ++k) { dx[k] = x[k] - mu; ss += dx[k] * dx[k]; }
#pragma unroll
    for (int o = 32; o > 0; o >>= 1) ss += __shfl_xor(ss, o, 64);
    float rstd = rsqrtf(ss * (1.f / DD) + 1e-5f);
    float4 g4 = *(const float4*)(gp + d0);
    float4 b4 = *(const float4*)(bp + d0);
    float4 xv = *(const float4*)(X1f + (size_t)r * DD + d0);
    float o4[4];
    o4[0] = xv.x + dx[0] * rstd * g4.x + b4.x;
    o4[1] = xv.y + dx[1] * rstd * g4.y + b4.y;
    o4[2] = xv.z + dx[2] * rstd * g4.z + b4.z;
    o4[3] = xv.w + dx[3] * rstd * g4.w + b4.w;
    *(float4*)(Out + (size_t)r * DD + d0) = (float4){o4[0], o4[1], o4[2], o4[3]};
}

// ============================================================================
extern "C" void kernel_launch(void* const* d_in, const int* in_sizes, int n_in,
                              void* d_out, int out_size, void* d_ws, size_t ws_size,
                              hipStream_t stream) {
    const float* X      = (const float*)d_in[0];
    const int* maskp    = (const int*)d_in[1];
    const float* Adj    = (const float*)d_in[2];
    const int* si[3]    = { (const int*)d_in[3], (const int*)d_in[5], (const int*)d_in[7] };
    const int* ri[3]    = { (const int*)d_in[4], (const int*)d_in[6], (const int*)d_in[8] };
    const float* gm1_Win  = (const float*)d_in[9];
    const float* gm1_alog = (const float*)d_in[10];
    const float* gm1_Wout = (const float*)d_in[11];
    const float* gm2_We   = (const float*)d_in[12];
    const float* gm_Win   = (const float*)d_in[13];
    const float* gm_alog  = (const float*)d_in[14];
    const float* gm_Wout  = (const float*)d_in[15];
    const float* gm_We    = (const float*)d_in[16];
    const float* ln1_g    = (const float*)d_in[17];
    const float* ln1_b    = (const float*)d_in[18];
    const float* ln2_g    = (const float*)d_in[19];
    const float* ln2_b    = (const float*)d_in[20];
    const float* ffn_W1   = (const float*)d_in[21];
    const float* ffn_b1   = (const float*)d_in[22];
    const float* ffn_W2   = (const float*)d_in[23];
    const float* ffn_b2   = (const float*)d_in[24];
    const float* Wv       = (const float*)d_in[25];
    const float* bv       = (const float*)d_in[26];
    float* Out = (float*)d_out;

    char* ws = (char*)d_ws;
    size_t off = 0;
    auto alloc = [&](size_t bytes) { size_t o = off; off += (bytes + 255) & ~(size_t)255; return o; };

    u16* WinT1  = (u16*)(ws + alloc((size_t)512 * 256 * 2));
    u16* WinT   = (u16*)(ws + alloc((size_t)512 * 256 * 2));
    u16* WoutT  = (u16*)(ws + alloc((size_t)256 * 256 * 2));
    u16* WeT1   = (u16*)(ws + alloc((size_t)256 * 256 * 2));
    u16* WeT    = (u16*)(ws + alloc((size_t)256 * 256 * 2));
    u16* WvT    = (u16*)(ws + alloc((size_t)256 * 1024 * 2));
    u16* W1T    = (u16*)(ws + alloc((size_t)1024 * 256 * 2));
    u16* W2T    = (u16*)(ws + alloc((size_t)256 * 1024 * 2));
    u16* WoutL  = (u16*)(ws + alloc((size_t)256 * 256 * 2));   // gm1_Wout linear bf16
    u16* Wc1T   = (u16*)(ws + alloc((size_t)256 * 256 * 2));   // (Wout1@We1)^T
    int* csr = (int*)(ws + alloc((size_t)NB * CAP * 4));
    int* cnt = (int*)(ws + alloc((size_t)NB * 4));
    float* deg = (float*)(ws + alloc((size_t)NB * 4));
    float* carry = (float*)(ws + alloc((size_t)NBR * BB * NCH * DD * 4));
    float* start = (float*)(ws + alloc((size_t)NBR * BB * NCH * DD * 4));
    u16* zbuf = (u16*)(ws + alloc((size_t)NRT * DD * 2));      // 33.6 MB
    u16* gbuf = (u16*)(ws + alloc((size_t)NRT * DD * 2));
    u16* U5   = (u16*)(ws + alloc((size_t)5 * NB * DD * 2));   // U4 (4NB) + Xm (NB)
    u16* V5   = (u16*)(ws + alloc((size_t)5 * NB * DD * 2));
    u16* Yin  = (u16*)(ws + alloc((size_t)NB * 1024 * 2));
    float* tmpY  = (float*)(ws + alloc((size_t)NB * DD * 4));
    float* X1f   = (float*)(ws + alloc((size_t)NB * DD * 4));
    u16* X1b     = (u16*)(ws + alloc((size_t)NB * DD * 2));
    u16* H       = (u16*)(ws + alloc((size_t)NB * 1024 * 2));
    float* tmpY2 = (float*)(ws + alloc((size_t)NB * DD * 4));
    u16* Xm = U5 + (size_t)4 * NB * DD;
    (void)ws_size; (void)in_sizes; (void)n_in; (void)out_size;

    // 1. all weight transposes/copies in one launch
    TrArgs ta;
    const float* srcs[9] = { gm1_Win, gm_Win, gm_Wout, gm2_We, gm_We, Wv, ffn_W1, ffn_W2, gm1_Wout };
    u16* dsts[9]         = { WinT1,   WinT,   WoutT,   WeT1,   WeT,   WvT, W1T,   W2T,    WoutL };
    int Ks[9] = { 256, 256, 256, 256, 256, 1024, 256, 1024, 256 };
    int Ns[9] = { 512, 512, 256, 256, 256, 256, 1024, 256, 256 };
    int trs[9] = { 1, 1, 1, 1, 1, 1, 1, 1, 0 };
    int cum = 0;
    for (int i = 0; i < 9; ++i) {
        ta.s[i] = srcs[i]; ta.d[i] = dsts[i]; ta.K[i] = Ks[i]; ta.N[i] = Ns[i]; ta.tr[i] = trs[i];
        ta.beg[i] = cum; cum += (Ks[i] * Ns[i]) / 256;
    }
    ta.beg[9] = cum;
    transpose_all<<<cum, 256, 0, stream>>>(ta);

    // 2. Wc1T = WeT1 @ WoutL  (==(Wout1@We1)^T), tiny 256^3 GEMM
    gemm_kernel<<<dim3(2, 2), 256, 0, stream>>>(
        WeT1, WoutL, WoutL, WoutL, 1 << 30, 1 << 30, (void*)Wc1T, nullptr, 256, 256, 2);

    // 3. CSR
    csr_kernel<<<NB / 4, 256, 0, stream>>>(Adj, csr, cnt, deg);

    // 4. Win GEMM with fused gather -> planar z/g bf16 (+ Xm tap-out)
    gemm_win_kernel<<<dim3(NRT / 128, 512 / 128), 256, 0, stream>>>(
        X, si[0], si[1], si[2], maskp, WinT1, WinT, zbuf, gbuf, Xm);

    // 5-7. batched scan (2 dims/thread) -> U5[0..4NB)
    scan_carry_kernel<<<NBR * BB * NCH, 128, 0, stream>>>(zbuf, gm1_alog, gm_alog, carry);
    scan_combine_kernel<<<NBR * BB, 128, 0, stream>>>(carry, gm1_alog, gm_alog, start);
    scan_apply_kernel<<<NBR * BB * NCH, 128, 0, stream>>>(zbuf, gbuf, gm1_alog, gm_alog, start, U5);

    // 8. combined GEMM: [5NB,256] rows; br<3 @Wc1T, br3 @WoutT, Xm @WeT -> V5
    gemm_kernel<<<dim3(5 * NB / 128, 2), 256, 0, stream>>>(
        U5, Wc1T, WoutT, WeT, 3 * NB, 4 * NB, (void*)V5, nullptr, 256, 256, 2);

    // 9. fused aggregation (relu + mask + br3 mamba add) -> Yin slots
    agg4_kernel<<<NRT / 8, 256, 0, stream>>>(V5, ri[0], ri[1], ri[2], csr, cnt, deg, maskp, Yin);

    // 10. Wv GEMM: [NB,1024] @ [1024,256] -> tmpY f32
    gemm_kernel<<<dim3(NB / 128, 2), 256, 0, stream>>>(
        Yin, WvT, WvT, WvT, 1 << 30, 1 << 30, (void*)tmpY, nullptr, 256, 1024, 0);

    // 11. LN1 (+bv fold, +X residual), wave-per-row
    ln1_kernel<<<NB / 4, 256, 0, stream>>>(tmpY, bv, X, ln1_g, ln1_b, X1f, X1b);

    // 12. FFN1: [NB,256] @ [256,1024] +b1, relu -> H bf16
    gemm_kernel<<<dim3(NB / 128, 8), 256, 0, stream>>>(
        X1b, W1T, W1T, W1T, 1 << 30, 1 << 30, (void*)H, ffn_b1, 1024, 256, 1);

    // 13. FFN2: [NB,1024] @ [1024,256] -> tmpY2 f32
    gemm_kernel<<<dim3(NB / 128, 2), 256, 0, stream>>>(
        H, W2T, W2T, W2T, 1 << 30, 1 << 30, (void*)tmpY2, nullptr, 256, 1024, 0);

    // 14. LN2 (+b2 fold, +X1 residual) -> Out f32
    ln2_kernel<<<NB / 4, 256, 0, stream>>>(tmpY2, ffn_b2, X1f, ln2_g, ln2_b, Out);
}

// Round 7
// 292.275 us; speedup vs baseline: 2.6489x; 1.0161x over previous
//
#include <hip/hip_runtime.h>

typedef unsigned short u16;
typedef unsigned int u32;
typedef unsigned long long u64;

#define BB 8
#define LL 2048
#define DD 256
#define NB (BB * LL)      // 16384 rows per branch
#define NBR 4
#define NRT (NBR * NB)    // 65536 batched rows
#define NCH 32
#define CHL (LL / NCH)    // 64
#define CAP 64

typedef __attribute__((ext_vector_type(8))) __bf16 bf16x8;
typedef __attribute__((ext_vector_type(4))) float f32x4;

__device__ __forceinline__ float b2f(u16 u) {
    union { u32 u; float f; } x; x.u = ((u32)u) << 16; return x.f;
}
__device__ __forceinline__ u16 f2b(float f) {
    union { float f; u32 u; } x; x.f = f;
    u32 r = (x.u >> 16) & 1u;
    x.u += 0x7FFFu + r;
    return (u16)(x.u >> 16);
}
__device__ __forceinline__ float sigm(float x) { return 1.f / (1.f + __expf(-x)); }

// ---- Xb = mask(X) cast to bf16 (masked rows -> 0) --------------------------
__global__ void xb_kernel(const float* __restrict__ X, const int* __restrict__ maskp,
                          u16* __restrict__ Xb) {
    int g = blockIdx.x * 256 + threadIdx.x;       // NB*DD/4 threads
    int r = g >> 6;                               // 64 quads per row
    float4 v = maskp[r] ? *(const float4*)(X + (size_t)g * 4)
                        : (float4){0.f, 0.f, 0.f, 0.f};
    union { u64 q; u16 h[4]; } pk;
    pk.h[0] = f2b(v.x); pk.h[1] = f2b(v.y); pk.h[2] = f2b(v.z); pk.h[3] = f2b(v.w);
    *(u64*)(Xb + (size_t)g * 4) = pk.q;
}

// ---- batched weight transpose/copy + cast: f32 -> bf16 ---------------------
struct TrArgs {
    const float* s[9];
    u16* d[9];
    int K[9], N[9], tr[9];
    int beg[10];
};
__global__ void transpose_all(TrArgs a) {
    int blk = blockIdx.x;
    int i = 0;
    while (blk >= a.beg[i + 1]) ++i;
    int idx = (blk - a.beg[i]) * 256 + threadIdx.x;
    int K = a.K[i], N = a.N[i];
    if (idx >= K * N) return;
    if (a.tr[i]) {
        int k = idx / N, n = idx - k * N;
        a.d[i][(size_t)n * K + k] = f2b(a.s[i][idx]);
    } else {
        a.d[i][idx] = f2b(a.s[i][idx]);
    }
}

// ---- CSR build; writes ri-composed index lists for br<3, raw for br3 -------
// csr4 layout: [br][NB][CAP]; br<3 holds ri_br[csr], br3 holds raw j.
__global__ void csr_kernel(const float* __restrict__ Adj,
                           const int* __restrict__ ri0, const int* __restrict__ ri1,
                           const int* __restrict__ ri2,
                           int* __restrict__ csr4, int* __restrict__ cnt,
                           float* __restrict__ deg) {
    int w = threadIdx.x >> 6, lane = threadIdx.x & 63;
    int row = blockIdx.x * 4 + w;                 // 0..NB-1
    int rowb = row & ~(LL - 1);                   // (b<<11)
    const float* arow = Adj + (size_t)row * LL;
    int base = 0;
    for (int c = 0; c < LL / 256; ++c) {          // 8 iterations
        float4 v = *(const float4*)(arow + c * 256 + lane * 4);
#pragma unroll
        for (int e = 0; e < 4; ++e) {
            float f = (e == 0) ? v.x : (e == 1) ? v.y : (e == 2) ? v.z : v.w;
            bool nz = (f != 0.f);
            u64 m = __ballot(nz);
            if (nz) {
                int pos = base + __popcll(m & ((1ull << lane) - 1ull));
                if (pos < CAP) {
                    int j = c * 256 + lane * 4 + e;
                    csr4[((size_t)(3 * NB + row)) * CAP + pos] = j;
                    csr4[((size_t)(0 * NB + row)) * CAP + pos] = ri0[rowb + j];
                    csr4[((size_t)(1 * NB + row)) * CAP + pos] = ri1[rowb + j];
                    csr4[((size_t)(2 * NB + row)) * CAP + pos] = ri2[rowb + j];
                }
            }
            base += __popcll(m);
        }
    }
    if (lane == 0) {
        cnt[row] = base < CAP ? base : CAP;
        deg[row] = (float)(base < 1 ? 1 : base);
    }
}

// ------- Win GEMM, A = row-gathered Xb via per-lane global_load_lds ---------
// C[NRT,512] = Xb[gather] @ Win^T, planar: cols 0-255 -> zbuf, rest -> gbuf
__global__ __launch_bounds__(256)
void gemm_win_kernel(const u16* __restrict__ Xb,
                     const int* __restrict__ si0, const int* __restrict__ si1,
                     const int* __restrict__ si2,
                     const u16* __restrict__ Bt1, const u16* __restrict__ Bt2,
                     u16* __restrict__ zbuf, u16* __restrict__ gbuf)
{
    __shared__ __align__(16) u16 As[128 * 32];
    __shared__ __align__(16) u16 Bs[128 * 32];
    int tid = threadIdx.x, lane = tid & 63;
    int w = tid >> 6, wm = w >> 1, wn = w & 1;
    int rowBase = blockIdx.x * 128, colBase = blockIdx.y * 128;
    const u16* Bt = (rowBase < 3 * NB) ? Bt1 : Bt2;

    const u16* pa[2];
#pragma unroll
    for (int rep = 0; rep < 2; ++rep) {
        int s = rep * 256 + tid;
        int row = s >> 2, kk = (s & 3) << 3;
        int rg = rowBase + row;
        int br = rg >> 14, r = rg & (NB - 1), b = r >> 11, l = r & (LL - 1);
        int src = (br == 0) ? si0[r] : (br == 1) ? si1[r] : (br == 2) ? si2[r] : l;
        pa[rep] = Xb + ((size_t)(b << 11) + src) * DD + kk;
    }

    f32x4 acc[4][4];
#pragma unroll
    for (int m = 0; m < 4; ++m)
#pragma unroll
        for (int n = 0; n < 4; ++n) acc[m][n] = (f32x4){0.f, 0.f, 0.f, 0.f};

    for (int k0 = 0; k0 < 256; k0 += 32) {
#pragma unroll
        for (int rep = 0; rep < 2; ++rep) {
            int s = rep * 256 + tid;
            const u16* gb = Bt + (size_t)(colBase + (s >> 2)) * 256 + (k0 + ((s & 3) << 3));
            __builtin_amdgcn_global_load_lds((const __attribute__((address_space(1))) void*)(pa[rep] + k0),
                                             (__attribute__((address_space(3))) void*)(As + s * 8), 16, 0, 0);
            __builtin_amdgcn_global_load_lds((const __attribute__((address_space(1))) void*)gb,
                                             (__attribute__((address_space(3))) void*)(Bs + s * 8), 16, 0, 0);
        }
        __syncthreads();
        int kq = (lane >> 4) << 3;
        bf16x8 av[4], bw[4];
#pragma unroll
        for (int m = 0; m < 4; ++m)
            av[m] = *(const bf16x8*)(As + (wm * 64 + m * 16 + (lane & 15)) * 32 + kq);
#pragma unroll
        for (int n = 0; n < 4; ++n)
            bw[n] = *(const bf16x8*)(Bs + (wn * 64 + n * 16 + (lane & 15)) * 32 + kq);
#pragma unroll
        for (int m = 0; m < 4; ++m)
#pragma unroll
            for (int n = 0; n < 4; ++n)
                acc[m][n] = __builtin_amdgcn_mfma_f32_16x16x32_bf16(av[m], bw[n], acc[m][n], 0, 0, 0);
        __syncthreads();
    }

    u16* Cz;
    int cb;
    if (colBase < 256) { Cz = zbuf; cb = colBase; }
    else               { Cz = gbuf; cb = colBase - 256; }
    int cBase = cb + wn * 64 + (lane & 15);
    int rBase = rowBase + wm * 64 + ((lane >> 4) << 2);
#pragma unroll
    for (int m = 0; m < 4; ++m)
#pragma unroll
        for (int n = 0; n < 4; ++n)
#pragma unroll
            for (int r = 0; r < 4; ++r)
                Cz[(size_t)(rBase + m * 16 + r) * 256 + (cBase + n * 16)] = f2b(acc[m][n][r]);
}

// --------- generic GEMM: 2-way A row-split, 3-way B row-group weights -------
// mode 0: f32 store; mode 1: bias(f32)+relu+bf16; mode 2: plain bf16
__global__ __launch_bounds__(256)
void gemm_kernel(const u16* __restrict__ A1, const u16* __restrict__ A2, int asplit,
                 const u16* __restrict__ Bt1, const u16* __restrict__ Bt2,
                 const u16* __restrict__ Bt3, int split1, int split2,
                 void* __restrict__ Cout, const float* __restrict__ bias,
                 int N, int K, int mode)
{
    __shared__ __align__(16) u16 As[128 * 32];
    __shared__ __align__(16) u16 Bs[128 * 32];
    int tid = threadIdx.x;
    int lane = tid & 63;
    int w = tid >> 6, wm = w >> 1, wn = w & 1;
    int rowBase = blockIdx.x * 128, colBase = blockIdx.y * 128;
    const u16* Bt = (rowBase < split1) ? Bt1 : (rowBase < split2) ? Bt2 : Bt3;
    const u16* Arow = (rowBase < asplit) ? A1 + (size_t)rowBase * K
                                         : A2 + (size_t)(rowBase - asplit) * K;

    f32x4 acc[4][4];
#pragma unroll
    for (int m = 0; m < 4; ++m)
#pragma unroll
        for (int n = 0; n < 4; ++n) acc[m][n] = (f32x4){0.f, 0.f, 0.f, 0.f};

    for (int k0 = 0; k0 < K; k0 += 32) {
#pragma unroll
        for (int rep = 0; rep < 2; ++rep) {
            int s = rep * 256 + tid;
            int row = s >> 2, kk = (s & 3) << 3;
            const u16* ga = Arow + (size_t)row * K + (k0 + kk);
            const u16* gb = Bt + (size_t)(colBase + row) * K + (k0 + kk);
            __builtin_amdgcn_global_load_lds((const __attribute__((address_space(1))) void*)ga,
                                             (__attribute__((address_space(3))) void*)(As + s * 8), 16, 0, 0);
            __builtin_amdgcn_global_load_lds((const __attribute__((address_space(1))) void*)gb,
                                             (__attribute__((address_space(3))) void*)(Bs + s * 8), 16, 0, 0);
        }
        __syncthreads();
        int kq = (lane >> 4) << 3;
        bf16x8 av[4], bw[4];
#pragma unroll
        for (int m = 0; m < 4; ++m)
            av[m] = *(const bf16x8*)(As + (wm * 64 + m * 16 + (lane & 15)) * 32 + kq);
#pragma unroll
        for (int n = 0; n < 4; ++n)
            bw[n] = *(const bf16x8*)(Bs + (wn * 64 + n * 16 + (lane & 15)) * 32 + kq);
#pragma unroll
        for (int m = 0; m < 4; ++m)
#pragma unroll
            for (int n = 0; n < 4; ++n)
                acc[m][n] = __builtin_amdgcn_mfma_f32_16x16x32_bf16(av[m], bw[n], acc[m][n], 0, 0, 0);
        __syncthreads();
    }

    int cBase = colBase + wn * 64 + (lane & 15);
    int rBase = rowBase + wm * 64 + ((lane >> 4) << 2);
    if (mode == 0) {
        float* C = (float*)Cout;
#pragma unroll
        for (int m = 0; m < 4; ++m)
#pragma unroll
            for (int n = 0; n < 4; ++n)
#pragma unroll
                for (int r = 0; r < 4; ++r)
                    C[(size_t)(rBase + m * 16 + r) * N + (cBase + n * 16)] = acc[m][n][r];
    } else {
        u16* C = (u16*)Cout;
        float bz[4];
#pragma unroll
        for (int n = 0; n < 4; ++n) bz[n] = bias ? bias[cBase + n * 16] : 0.f;
#pragma unroll
        for (int m = 0; m < 4; ++m)
#pragma unroll
            for (int n = 0; n < 4; ++n)
#pragma unroll
                for (int r = 0; r < 4; ++r) {
                    float v = acc[m][n][r] + bz[n];
                    if (mode == 1) v = v > 0.f ? v : 0.f;
                    C[(size_t)(rBase + m * 16 + r) * N + (cBase + n * 16)] = f2b(v);
                }
    }
}

// ---------------- batched chunked EMA scan (planar z/g, 2 dims/thread) ------
__global__ void scan_carry_kernel(const u16* __restrict__ z4, const float* __restrict__ alog1,
                                  const float* __restrict__ alog2, float* __restrict__ carry) {
    int bid = blockIdx.x;                          // (br,b,c)
    int br = bid >> 8, b = (bid >> 5) & 7, c = bid & 31;
    int d0 = threadIdx.x * 2;                      // 128 threads
    const float* al = (br < 3) ? alog1 : alog2;
    float aA = sigm(al[d0]), aB = sigm(al[d0 + 1]);
    float hA = 0.f, hB = 0.f;
    const u16* zp = z4 + ((size_t)(br * NB + b * LL + c * CHL) * DD) + d0;
    for (int t = 0; t < CHL; ++t) {
        u32 v = *(const u32*)(zp + (size_t)t * DD);
        hA = aA * hA + (1.f - aA) * b2f((u16)v);
        hB = aB * hB + (1.f - aB) * b2f((u16)(v >> 16));
    }
    carry[(size_t)bid * DD + d0] = hA;
    carry[(size_t)bid * DD + d0 + 1] = hB;
}

__global__ void scan_combine_kernel(const float* __restrict__ carry, const float* __restrict__ alog1,
                                    const float* __restrict__ alog2, float* __restrict__ start) {
    int br = blockIdx.x >> 3, b = blockIdx.x & 7;  // grid 32
    int d0 = threadIdx.x * 2;
    const float* al = (br < 3) ? alog1 : alog2;
    float aA = sigm(al[d0]), aB = sigm(al[d0 + 1]);
    float aPA = aA, aPB = aB;
#pragma unroll
    for (int i = 0; i < 6; ++i) { aPA *= aPA; aPB *= aPB; }   // a^64
    float hA = 0.f, hB = 0.f;
    for (int c = 0; c < NCH; ++c) {
        size_t idx = ((size_t)(br * 256 + b * 32 + c)) * DD + d0;
        start[idx] = hA; start[idx + 1] = hB;
        hA = carry[idx] + aPA * hA;
        hB = carry[idx + 1] + aPB * hB;
    }
}

__global__ void scan_apply_kernel(const u16* __restrict__ z4, const u16* __restrict__ g4,
                                  const float* __restrict__ alog1, const float* __restrict__ alog2,
                                  const float* __restrict__ start, u16* __restrict__ U4) {
    int bid = blockIdx.x;
    int br = bid >> 8, b = (bid >> 5) & 7, c = bid & 31;
    int d0 = threadIdx.x * 2;
    const float* al = (br < 3) ? alog1 : alog2;
    float aA = sigm(al[d0]), aB = sigm(al[d0 + 1]);
    float hA = start[(size_t)bid * DD + d0];
    float hB = start[(size_t)bid * DD + d0 + 1];
    size_t rowOff = ((size_t)(br * NB + b * LL + c * CHL)) * DD + d0;
    const u16* zp = z4 + rowOff;
    const u16* gp = g4 + rowOff;
    u16* up = U4 + rowOff;
    for (int t = 0; t < CHL; ++t) {
        u32 zv = *(const u32*)(zp + (size_t)t * DD);
        u32 gv = *(const u32*)(gp + (size_t)t * DD);
        float gA = b2f((u16)gv), gB = b2f((u16)(gv >> 16));
        hA = aA * hA + (1.f - aA) * b2f((u16)zv);
        hB = aB * hB + (1.f - aB) * b2f((u16)(zv >> 16));
        u32 o = (u32)f2b(hA * gA * sigm(gA)) | ((u32)f2b(hB * gB * sigm(gB)) << 16);
        *(u32*)(up + (size_t)t * DD) = o;
    }
}

// --- batched agg (fused relu+mask+br3-mamba-add), writes Yin slots directly -
// V5 rows: [0,3NB)=U@Wc1 (sorted order, br<3); [3NB,4NB)=U3@Wout; [4NB,5NB)=Xb@We2
__global__ void agg4_kernel(const u16* __restrict__ V5, const int* __restrict__ csr4,
                            const int* __restrict__ cnt, const float* __restrict__ deg,
                            const int* __restrict__ maskp, u16* __restrict__ Yin) {
    int tr = threadIdx.x & 31;        // dims 8*tr..8*tr+7
    int rsub = threadIdx.x >> 5;      // 0..7
    int rg = blockIdx.x * 8 + rsub;   // 0..NRT-1
    int br = rg >> 14, r = rg & (NB - 1), b = r >> 11;
    int n = cnt[r];
    const int* lst = csr4 + ((size_t)(br * NB + r)) * CAP;
    const u16* srcB = V5 + ((size_t)((br < 3 ? br : 4) * NB + (b << 11))) * DD + tr * 8;
    float acc[8] = {0.f, 0.f, 0.f, 0.f, 0.f, 0.f, 0.f, 0.f};
    for (int i = 0; i < n; ++i) {
        int idx = lst[i];
        union { uint4 q; u16 h[8]; } v;
        v.q = *(const uint4*)(srcB + (size_t)idx * DD);
#pragma unroll
        for (int k = 0; k < 8; ++k) acc[k] += b2f(v.h[k]);
    }
    float inv = 1.f / deg[r];
    int msk = maskp[r];
    union { uint4 q; u16 h[8]; } mo;
    if (br == 3) mo.q = *(const uint4*)(V5 + ((size_t)(3 * NB + r)) * DD + tr * 8);
    union { uint4 q; u16 h[8]; } o;
#pragma unroll
    for (int k = 0; k < 8; ++k) {
        float v = acc[k] * inv;
        v = v > 0.f ? v : 0.f;
        if (br == 3) v += b2f(mo.h[k]);
        v = msk ? v : 0.f;
        o.h[k] = f2b(v);
    }
    *(uint4*)(Yin + (size_t)r * 1024 + (br << 8) + tr * 8) = o.q;
}

// ---------------- layernorm, wave-per-row (float4, shfl_xor butterfly) ------
__global__ void ln1_kernel(const float* __restrict__ Yt, const float* __restrict__ bvp,
                           const float* __restrict__ X, const float* __restrict__ gp,
                           const float* __restrict__ bp, float* __restrict__ X1f,
                           u16* __restrict__ X1b) {
    int wv = threadIdx.x >> 6, lane = threadIdx.x & 63;
    int r = blockIdx.x * 4 + wv;
    int d0 = lane << 2;
    float4 yv = *(const float4*)(Yt + (size_t)r * DD + d0);
    float4 bb = *(const float4*)(bvp + d0);
    float x[4] = { yv.x + bb.x, yv.y + bb.y, yv.z + bb.z, yv.w + bb.w };
    float s = x[0] + x[1] + x[2] + x[3];
#pragma unroll
    for (int o = 32; o > 0; o >>= 1) s += __shfl_xor(s, o, 64);
    float mu = s * (1.f / DD);
    float dx[4], ss = 0.f;
#pragma unroll
    for (int k = 0; k < 4; ++k) { dx[k] = x[k] - mu; ss += dx[k] * dx[k]; }
#pragma unroll
    for (int o = 32; o > 0; o >>= 1) ss += __shfl_xor(ss, o, 64);
    float rstd = rsqrtf(ss * (1.f / DD) + 1e-5f);
    float4 g4 = *(const float4*)(gp + d0);
    float4 b4 = *(const float4*)(bp + d0);
    float4 xv = *(const float4*)(X + (size_t)r * DD + d0);
    float gg[4] = { g4.x, g4.y, g4.z, g4.w };
    float bz[4] = { b4.x, b4.y, b4.z, b4.w };
    float xx[4] = { xv.x, xv.y, xv.z, xv.w };
    float o4[4];
    union { u64 q; u16 h[4]; } pk;
#pragma unroll
    for (int k = 0; k < 4; ++k) {
        float y = dx[k] * rstd * gg[k] + bz[k];
        o4[k] = xx[k] + y;
        pk.h[k] = f2b(o4[k]);
    }
    *(float4*)(X1f + (size_t)r * DD + d0) = (float4){o4[0], o4[1], o4[2], o4[3]};
    *(u64*)(X1b + (size_t)r * DD + d0) = pk.q;
}

__global__ void ln2_kernel(const float* __restrict__ Y2, const float* __restrict__ b2p,
                           const float* __restrict__ X1f, const float* __restrict__ gp,
                           const float* __restrict__ bp, float* __restrict__ Out) {
    int wv = threadIdx.x >> 6, lane = threadIdx.x & 63;
    int r = blockIdx.x * 4 + wv;
    int d0 = lane << 2;
    float4 yv = *(const float4*)(Y2 + (size_t)r * DD + d0);
    float4 bb = *(const float4*)(b2p + d0);
    float x[4] = { yv.x + bb.x, yv.y + bb.y, yv.z + bb.z, yv.w + bb.w };
    float s = x[0] + x[1] + x[2] + x[3];
#pragma unroll
    for (int o = 32; o > 0; o >>= 1) s += __shfl_xor(s, o, 64);
    float mu = s * (1.f / DD);
    float dx[4], ss = 0.f;
#pragma unroll
    for (int k = 0; k < 4; ++k) { dx[k] = x[k] - mu; ss += dx[k] * dx[k]; }
#pragma unroll
    for (int o = 32; o > 0; o >>= 1) ss += __shfl_xor(ss, o, 64);
    float rstd = rsqrtf(ss * (1.f / DD) + 1e-5f);
    float4 g4 = *(const float4*)(gp + d0);
    float4 b4 = *(const float4*)(bp + d0);
    float4 xv = *(const float4*)(X1f + (size_t)r * DD + d0);
    float o4[4];
    o4[0] = xv.x + dx[0] * rstd * g4.x + b4.x;
    o4[1] = xv.y + dx[1] * rstd * g4.y + b4.y;
    o4[2] = xv.z + dx[2] * rstd * g4.z + b4.z;
    o4[3] = xv.w + dx[3] * rstd * g4.w + b4.w;
    *(float4*)(Out + (size_t)r * DD + d0) = (float4){o4[0], o4[1], o4[2], o4[3]};
}

// ============================================================================
extern "C" void kernel_launch(void* const* d_in, const int* in_sizes, int n_in,
                              void* d_out, int out_size, void* d_ws, size_t ws_size,
                              hipStream_t stream) {
    const float* X      = (const float*)d_in[0];
    const int* maskp    = (const int*)d_in[1];
    const float* Adj    = (const float*)d_in[2];
    const int* si[3]    = { (const int*)d_in[3], (const int*)d_in[5], (const int*)d_in[7] };
    const int* ri[3]    = { (const int*)d_in[4], (const int*)d_in[6], (const int*)d_in[8] };
    const float* gm1_Win  = (const float*)d_in[9];
    const float* gm1_alog = (const float*)d_in[10];
    const float* gm1_Wout = (const float*)d_in[11];
    const float* gm2_We   = (const float*)d_in[12];
    const float* gm_Win   = (const float*)d_in[13];
    const float* gm_alog  = (const float*)d_in[14];
    const float* gm_Wout  = (const float*)d_in[15];
    const float* gm_We    = (const float*)d_in[16];
    const float* ln1_g    = (const float*)d_in[17];
    const float* ln1_b    = (const float*)d_in[18];
    const float* ln2_g    = (const float*)d_in[19];
    const float* ln2_b    = (const float*)d_in[20];
    const float* ffn_W1   = (const float*)d_in[21];
    const float* ffn_b1   = (const float*)d_in[22];
    const float* ffn_W2   = (const float*)d_in[23];
    const float* ffn_b2   = (const float*)d_in[24];
    const float* Wv       = (const float*)d_in[25];
    const float* bv       = (const float*)d_in[26];
    float* Out = (float*)d_out;

    char* ws = (char*)d_ws;
    size_t off = 0;
    auto alloc = [&](size_t bytes) { size_t o = off; off += (bytes + 255) & ~(size_t)255; return o; };

    u16* WinT1  = (u16*)(ws + alloc((size_t)512 * 256 * 2));
    u16* WinT   = (u16*)(ws + alloc((size_t)512 * 256 * 2));
    u16* WoutT  = (u16*)(ws + alloc((size_t)256 * 256 * 2));
    u16* WeT1   = (u16*)(ws + alloc((size_t)256 * 256 * 2));
    u16* WeT    = (u16*)(ws + alloc((size_t)256 * 256 * 2));
    u16* WvT    = (u16*)(ws + alloc((size_t)256 * 1024 * 2));
    u16* W1T    = (u16*)(ws + alloc((size_t)1024 * 256 * 2));
    u16* W2T    = (u16*)(ws + alloc((size_t)256 * 1024 * 2));
    u16* WoutL  = (u16*)(ws + alloc((size_t)256 * 256 * 2));   // gm1_Wout linear bf16
    u16* Wc1T   = (u16*)(ws + alloc((size_t)256 * 256 * 2));   // (Wout1@We1)^T
    u16* Xb     = (u16*)(ws + alloc((size_t)NB * DD * 2));     // masked X bf16
    int* csr4 = (int*)(ws + alloc((size_t)4 * NB * CAP * 4));  // 16.8 MB
    int* cnt = (int*)(ws + alloc((size_t)NB * 4));
    float* deg = (float*)(ws + alloc((size_t)NB * 4));
    float* carry = (float*)(ws + alloc((size_t)NBR * BB * NCH * DD * 4));
    float* start = (float*)(ws + alloc((size_t)NBR * BB * NCH * DD * 4));
    u16* zbuf = (u16*)(ws + alloc((size_t)NRT * DD * 2));      // 33.6 MB
    u16* gbuf = (u16*)(ws + alloc((size_t)NRT * DD * 2));
    u16* U4   = (u16*)(ws + alloc((size_t)4 * NB * DD * 2));
    u16* V5   = (u16*)(ws + alloc((size_t)5 * NB * DD * 2));
    u16* Yin  = (u16*)(ws + alloc((size_t)NB * 1024 * 2));
    float* tmpY  = (float*)(ws + alloc((size_t)NB * DD * 4));
    float* X1f   = (float*)(ws + alloc((size_t)NB * DD * 4));
    u16* X1b     = (u16*)(ws + alloc((size_t)NB * DD * 2));
    u16* H       = (u16*)(ws + alloc((size_t)NB * 1024 * 2));
    float* tmpY2 = (float*)(ws + alloc((size_t)NB * DD * 4));
    (void)ws_size; (void)in_sizes; (void)n_in; (void)out_size;

    // 1. Xb = mask(X) -> bf16
    xb_kernel<<<NB * DD / 4 / 256, 256, 0, stream>>>(X, maskp, Xb);

    // 2. all weight transposes/copies in one launch
    TrArgs ta;
    const float* srcs[9] = { gm1_Win, gm_Win, gm_Wout, gm2_We, gm_We, Wv, ffn_W1, ffn_W2, gm1_Wout };
    u16* dsts[9]         = { WinT1,   WinT,   WoutT,   WeT1,   WeT,   WvT, W1T,   W2T,    WoutL };
    int Ks[9] = { 256, 256, 256, 256, 256, 1024, 256, 1024, 256 };
    int Ns[9] = { 512, 512, 256, 256, 256, 256, 1024, 256, 256 };
    int trs[9] = { 1, 1, 1, 1, 1, 1, 1, 1, 0 };
    int cum = 0;
    for (int i = 0; i < 9; ++i) {
        ta.s[i] = srcs[i]; ta.d[i] = dsts[i]; ta.K[i] = Ks[i]; ta.N[i] = Ns[i]; ta.tr[i] = trs[i];
        ta.beg[i] = cum; cum += (Ks[i] * Ns[i]) / 256;
    }
    ta.beg[9] = cum;
    transpose_all<<<cum, 256, 0, stream>>>(ta);

    // 3. Wc1T = WeT1 @ WoutL  (==(Wout1@We1)^T)
    gemm_kernel<<<dim3(2, 2), 256, 0, stream>>>(
        WeT1, WeT1, 1 << 30, WoutL, WoutL, WoutL, 1 << 30, 1 << 30,
        (void*)Wc1T, nullptr, 256, 256, 2);

    // 4. CSR (+ri-composed lists)
    csr_kernel<<<NB / 4, 256, 0, stream>>>(Adj, ri[0], ri[1], ri[2], csr4, cnt, deg);

    // 5. Win GEMM, gathered Xb A-staging -> planar z/g bf16
    gemm_win_kernel<<<dim3(NRT / 128, 512 / 128), 256, 0, stream>>>(
        Xb, si[0], si[1], si[2], WinT1, WinT, zbuf, gbuf);

    // 6-8. batched scan (2 dims/thread) -> U4
    scan_carry_kernel<<<NBR * BB * NCH, 128, 0, stream>>>(zbuf, gm1_alog, gm_alog, carry);
    scan_combine_kernel<<<NBR * BB, 128, 0, stream>>>(carry, gm1_alog, gm_alog, start);
    scan_apply_kernel<<<NBR * BB * NCH, 128, 0, stream>>>(zbuf, gbuf, gm1_alog, gm_alog, start, U4);

    // 9. combined GEMM: rows [0,4NB) from U4, [4NB,5NB) from Xb;
    //    B: br<3 @Wc1T, br3 @WoutT, Xb-seg @WeT -> V5
    gemm_kernel<<<dim3(5 * NB / 128, 2), 256, 0, stream>>>(
        U4, Xb, 4 * NB, Wc1T, WoutT, WeT, 3 * NB, 4 * NB,
        (void*)V5, nullptr, 256, 256, 2);

    // 10. fused aggregation (relu + mask + br3 mamba add) -> Yin slots
    agg4_kernel<<<NRT / 8, 256, 0, stream>>>(V5, csr4, cnt, deg, maskp, Yin);

    // 11. Wv GEMM: [NB,1024] @ [1024,256] -> tmpY f32
    gemm_kernel<<<dim3(NB / 128, 2), 256, 0, stream>>>(
        Yin, Yin, 1 << 30, WvT, WvT, WvT, 1 << 30, 1 << 30,
        (void*)tmpY, nullptr, 256, 1024, 0);

    // 12. LN1 (+bv fold, +X residual), wave-per-row
    ln1_kernel<<<NB / 4, 256, 0, stream>>>(tmpY, bv, X, ln1_g, ln1_b, X1f, X1b);

    // 13. FFN1: [NB,256] @ [256,1024] +b1, relu -> H bf16
    gemm_kernel<<<dim3(NB / 128, 8), 256, 0, stream>>>(
        X1b, X1b, 1 << 30, W1T, W1T, W1T, 1 << 30, 1 << 30,
        (void*)H, ffn_b1, 1024, 256, 1);

    // 14. FFN2: [NB,1024] @ [1024,256] -> tmpY2 f32
    gemm_kernel<<<dim3(NB / 128, 2), 256, 0, stream>>>(
        H, H, 1 << 30, W2T, W2T, W2T, 1 << 30, 1 << 30,
        (void*)tmpY2, nullptr, 256, 1024, 0);

    // 15. LN2 (+b2 fold, +X1 residual) -> Out f32
    ln2_kernel<<<NB / 4, 256, 0, stream>>>(tmpY2, ffn_b2, X1f, ln2_g, ln2_b, Out);
}

// Round 8
// 275.711 us; speedup vs baseline: 2.8080x; 1.0601x over previous
//
#include <hip/hip_runtime.h>

typedef unsigned short u16;
typedef unsigned int u32;
typedef unsigned long long u64;

#define BB 8
#define LL 2048
#define DD 256
#define NB (BB * LL)      // 16384 rows per branch
#define NBR 4
#define NRT (NBR * NB)    // 65536 batched rows
#define NCH 32
#define CHL (LL / NCH)    // 64
#define CAP 64

typedef __attribute__((ext_vector_type(8))) __bf16 bf16x8;
typedef __attribute__((ext_vector_type(4))) float f32x4;

__device__ __forceinline__ float b2f(u16 u) {
    union { u32 u; float f; } x; x.u = ((u32)u) << 16; return x.f;
}
__device__ __forceinline__ u16 f2b(float f) {
    union { float f; u32 u; } x; x.f = f;
    u32 r = (x.u >> 16) & 1u;
    x.u += 0x7FFFu + r;
    return (u16)(x.u >> 16);
}
__device__ __forceinline__ float sigm(float x) { return 1.f / (1.f + __expf(-x)); }

#define GLD(gp, lp) __builtin_amdgcn_global_load_lds( \
    (const __attribute__((address_space(1))) void*)(gp), \
    (__attribute__((address_space(3))) void*)(lp), 16, 0, 0)

// ---- Xb = mask(X) cast to bf16 (masked rows -> 0) --------------------------
__global__ void xb_kernel(const float* __restrict__ X, const int* __restrict__ maskp,
                          u16* __restrict__ Xb) {
    int g = blockIdx.x * 256 + threadIdx.x;       // NB*DD/4 threads
    int r = g >> 6;                               // 64 quads per row
    float4 v = maskp[r] ? *(const float4*)(X + (size_t)g * 4)
                        : (float4){0.f, 0.f, 0.f, 0.f};
    union { u64 q; u16 h[4]; } pk;
    pk.h[0] = f2b(v.x); pk.h[1] = f2b(v.y); pk.h[2] = f2b(v.z); pk.h[3] = f2b(v.w);
    *(u64*)(Xb + (size_t)g * 4) = pk.q;
}

// ---- batched weight transpose/copy + cast: f32 -> bf16 ---------------------
struct TrArgs {
    const float* s[9];
    u16* d[9];
    int K[9], N[9], tr[9];
    int beg[10];
};
__global__ void transpose_all(TrArgs a) {
    int blk = blockIdx.x;
    int i = 0;
    while (blk >= a.beg[i + 1]) ++i;
    int idx = (blk - a.beg[i]) * 256 + threadIdx.x;
    int K = a.K[i], N = a.N[i];
    if (idx >= K * N) return;
    if (a.tr[i]) {
        int k = idx / N, n = idx - k * N;
        a.d[i][(size_t)n * K + k] = f2b(a.s[i][idx]);
    } else {
        a.d[i][idx] = f2b(a.s[i][idx]);
    }
}

// ---- CSR build; writes ri-composed index lists for br<3, raw for br3 -------
__global__ void csr_kernel(const float* __restrict__ Adj,
                           const int* __restrict__ ri0, const int* __restrict__ ri1,
                           const int* __restrict__ ri2,
                           int* __restrict__ csr4, int* __restrict__ cnt,
                           float* __restrict__ deg) {
    int w = threadIdx.x >> 6, lane = threadIdx.x & 63;
    int row = blockIdx.x * 4 + w;                 // 0..NB-1
    int rowb = row & ~(LL - 1);                   // (b<<11)
    const float* arow = Adj + (size_t)row * LL;
    int base = 0;
    for (int c = 0; c < LL / 256; ++c) {          // 8 iterations
        float4 v = *(const float4*)(arow + c * 256 + lane * 4);
#pragma unroll
        for (int e = 0; e < 4; ++e) {
            float f = (e == 0) ? v.x : (e == 1) ? v.y : (e == 2) ? v.z : v.w;
            bool nz = (f != 0.f);
            u64 m = __ballot(nz);
            if (nz) {
                int pos = base + __popcll(m & ((1ull << lane) - 1ull));
                if (pos < CAP) {
                    int j = c * 256 + lane * 4 + e;
                    csr4[((size_t)(3 * NB + row)) * CAP + pos] = j;
                    csr4[((size_t)(0 * NB + row)) * CAP + pos] = ri0[rowb + j];
                    csr4[((size_t)(1 * NB + row)) * CAP + pos] = ri1[rowb + j];
                    csr4[((size_t)(2 * NB + row)) * CAP + pos] = ri2[rowb + j];
                }
            }
            base += __popcll(m);
        }
    }
    if (lane == 0) {
        cnt[row] = base < CAP ? base : CAP;
        deg[row] = (float)(base < 1 ? 1 : base);
    }
}

// ------- Win GEMM, A = row-gathered Xb; 2-phase dbuf pipeline ---------------
__global__ __launch_bounds__(256)
void gemm_win_kernel(const u16* __restrict__ Xb,
                     const int* __restrict__ si0, const int* __restrict__ si1,
                     const int* __restrict__ si2,
                     const u16* __restrict__ Bt1, const u16* __restrict__ Bt2,
                     u16* __restrict__ zbuf, u16* __restrict__ gbuf)
{
    __shared__ __align__(16) u16 As[2][128 * 32];
    __shared__ __align__(16) u16 Bs[2][128 * 32];
    int tid = threadIdx.x, lane = tid & 63;
    int w = tid >> 6, wm = w >> 1, wn = w & 1;
    int rowBase = blockIdx.x * 128, colBase = blockIdx.y * 128;
    const u16* Bt = (rowBase < 3 * NB) ? Bt1 : Bt2;

    const u16* pa[2];
    const u16* pb[2];
#pragma unroll
    for (int rep = 0; rep < 2; ++rep) {
        int s = rep * 256 + tid;
        int row = s >> 2, kk = (s & 3) << 3;
        int rg = rowBase + row;
        int br = rg >> 14, r = rg & (NB - 1), b = r >> 11, l = r & (LL - 1);
        int src = (br == 0) ? si0[r] : (br == 1) ? si1[r] : (br == 2) ? si2[r] : l;
        pa[rep] = Xb + ((size_t)(b << 11) + src) * DD + kk;
        pb[rep] = Bt + (size_t)(colBase + row) * 256 + kk;
    }

    f32x4 acc[4][4];
#pragma unroll
    for (int m = 0; m < 4; ++m)
#pragma unroll
        for (int n = 0; n < 4; ++n) acc[m][n] = (f32x4){0.f, 0.f, 0.f, 0.f};

    // prologue: stage tile 0 into buffer 0
#pragma unroll
    for (int rep = 0; rep < 2; ++rep) {
        int s = rep * 256 + tid;
        GLD(pa[rep], As[0] + s * 8);
        GLD(pb[rep], Bs[0] + s * 8);
    }
    int p = 0;
    for (int t = 0; t < 8; ++t) {
        if (t + 1 < 8) {
            int k0 = (t + 1) * 32;
#pragma unroll
            for (int rep = 0; rep < 2; ++rep) {
                int s = rep * 256 + tid;
                GLD(pa[rep] + k0, As[p ^ 1] + s * 8);
                GLD(pb[rep] + k0, Bs[p ^ 1] + s * 8);
            }
            asm volatile("s_waitcnt vmcnt(4)" ::: "memory");
        } else {
            asm volatile("s_waitcnt vmcnt(0)" ::: "memory");
        }
        __builtin_amdgcn_s_barrier();
        int kq = (lane >> 4) << 3;
        bf16x8 av[4], bw[4];
#pragma unroll
        for (int m = 0; m < 4; ++m)
            av[m] = *(const bf16x8*)(As[p] + (wm * 64 + m * 16 + (lane & 15)) * 32 + kq);
#pragma unroll
        for (int n = 0; n < 4; ++n)
            bw[n] = *(const bf16x8*)(Bs[p] + (wn * 64 + n * 16 + (lane & 15)) * 32 + kq);
#pragma unroll
        for (int m = 0; m < 4; ++m)
#pragma unroll
            for (int n = 0; n < 4; ++n)
                acc[m][n] = __builtin_amdgcn_mfma_f32_16x16x32_bf16(av[m], bw[n], acc[m][n], 0, 0, 0);
        __builtin_amdgcn_s_barrier();
        p ^= 1;
    }

    u16* Cz;
    int cb;
    if (colBase < 256) { Cz = zbuf; cb = colBase; }
    else               { Cz = gbuf; cb = colBase - 256; }
    int cBase = cb + wn * 64 + (lane & 15);
    int rBase = rowBase + wm * 64 + ((lane >> 4) << 2);
#pragma unroll
    for (int m = 0; m < 4; ++m)
#pragma unroll
        for (int n = 0; n < 4; ++n)
#pragma unroll
            for (int r = 0; r < 4; ++r)
                Cz[(size_t)(rBase + m * 16 + r) * 256 + (cBase + n * 16)] = f2b(acc[m][n][r]);
}

// --------- generic GEMM: 2-way A row-split, 3-way B weights, dbuf pipeline --
// mode 0: f32 store; mode 1: bias(f32)+relu+bf16; mode 2: plain bf16
__global__ __launch_bounds__(256)
void gemm_kernel(const u16* __restrict__ A1, const u16* __restrict__ A2, int asplit,
                 const u16* __restrict__ Bt1, const u16* __restrict__ Bt2,
                 const u16* __restrict__ Bt3, int split1, int split2,
                 void* __restrict__ Cout, const float* __restrict__ bias,
                 int N, int K, int mode)
{
    __shared__ __align__(16) u16 As[2][128 * 32];
    __shared__ __align__(16) u16 Bs[2][128 * 32];
    int tid = threadIdx.x;
    int lane = tid & 63;
    int w = tid >> 6, wm = w >> 1, wn = w & 1;
    int rowBase = blockIdx.x * 128, colBase = blockIdx.y * 128;
    const u16* Bt = (rowBase < split1) ? Bt1 : (rowBase < split2) ? Bt2 : Bt3;
    const u16* Arow = (rowBase < asplit) ? A1 + (size_t)rowBase * K
                                         : A2 + (size_t)(rowBase - asplit) * K;

    const u16* pa[2];
    const u16* pb[2];
#pragma unroll
    for (int rep = 0; rep < 2; ++rep) {
        int s = rep * 256 + tid;
        int row = s >> 2, kk = (s & 3) << 3;
        pa[rep] = Arow + (size_t)row * K + kk;
        pb[rep] = Bt + (size_t)(colBase + row) * K + kk;
    }

    f32x4 acc[4][4];
#pragma unroll
    for (int m = 0; m < 4; ++m)
#pragma unroll
        for (int n = 0; n < 4; ++n) acc[m][n] = (f32x4){0.f, 0.f, 0.f, 0.f};

    int nt = K >> 5;
#pragma unroll
    for (int rep = 0; rep < 2; ++rep) {
        int s = rep * 256 + tid;
        GLD(pa[rep], As[0] + s * 8);
        GLD(pb[rep], Bs[0] + s * 8);
    }
    int p = 0;
    for (int t = 0; t < nt; ++t) {
        if (t + 1 < nt) {
            int k0 = (t + 1) << 5;
#pragma unroll
            for (int rep = 0; rep < 2; ++rep) {
                int s = rep * 256 + tid;
                GLD(pa[rep] + k0, As[p ^ 1] + s * 8);
                GLD(pb[rep] + k0, Bs[p ^ 1] + s * 8);
            }
            asm volatile("s_waitcnt vmcnt(4)" ::: "memory");
        } else {
            asm volatile("s_waitcnt vmcnt(0)" ::: "memory");
        }
        __builtin_amdgcn_s_barrier();
        int kq = (lane >> 4) << 3;
        bf16x8 av[4], bw[4];
#pragma unroll
        for (int m = 0; m < 4; ++m)
            av[m] = *(const bf16x8*)(As[p] + (wm * 64 + m * 16 + (lane & 15)) * 32 + kq);
#pragma unroll
        for (int n = 0; n < 4; ++n)
            bw[n] = *(const bf16x8*)(Bs[p] + (wn * 64 + n * 16 + (lane & 15)) * 32 + kq);
#pragma unroll
        for (int m = 0; m < 4; ++m)
#pragma unroll
            for (int n = 0; n < 4; ++n)
                acc[m][n] = __builtin_amdgcn_mfma_f32_16x16x32_bf16(av[m], bw[n], acc[m][n], 0, 0, 0);
        __builtin_amdgcn_s_barrier();
        p ^= 1;
    }

    int cBase = colBase + wn * 64 + (lane & 15);
    int rBase = rowBase + wm * 64 + ((lane >> 4) << 2);
    if (mode == 0) {
        float* C = (float*)Cout;
#pragma unroll
        for (int m = 0; m < 4; ++m)
#pragma unroll
            for (int n = 0; n < 4; ++n)
#pragma unroll
                for (int r = 0; r < 4; ++r)
                    C[(size_t)(rBase + m * 16 + r) * N + (cBase + n * 16)] = acc[m][n][r];
    } else {
        u16* C = (u16*)Cout;
        float bz[4];
#pragma unroll
        for (int n = 0; n < 4; ++n) bz[n] = bias ? bias[cBase + n * 16] : 0.f;
#pragma unroll
        for (int m = 0; m < 4; ++m)
#pragma unroll
            for (int n = 0; n < 4; ++n)
#pragma unroll
                for (int r = 0; r < 4; ++r) {
                    float v = acc[m][n][r] + bz[n];
                    if (mode == 1) v = v > 0.f ? v : 0.f;
                    C[(size_t)(rBase + m * 16 + r) * N + (cBase + n * 16)] = f2b(v);
                }
    }
}

// ---------------- batched chunked EMA scan (planar z/g, 2 dims/thread) ------
__global__ void scan_carry_kernel(const u16* __restrict__ z4, const float* __restrict__ alog1,
                                  const float* __restrict__ alog2, float* __restrict__ carry) {
    int bid = blockIdx.x;                          // (br,b,c)
    int br = bid >> 8, b = (bid >> 5) & 7, c = bid & 31;
    int d0 = threadIdx.x * 2;                      // 128 threads
    const float* al = (br < 3) ? alog1 : alog2;
    float aA = sigm(al[d0]), aB = sigm(al[d0 + 1]);
    float hA = 0.f, hB = 0.f;
    const u16* zp = z4 + ((size_t)(br * NB + b * LL + c * CHL) * DD) + d0;
    for (int t = 0; t < CHL; ++t) {
        u32 v = *(const u32*)(zp + (size_t)t * DD);
        hA = aA * hA + (1.f - aA) * b2f((u16)v);
        hB = aB * hB + (1.f - aB) * b2f((u16)(v >> 16));
    }
    carry[(size_t)bid * DD + d0] = hA;
    carry[(size_t)bid * DD + d0 + 1] = hB;
}

// apply with inline chunk-combine (start recomputed from carries)
__global__ void scan_apply_kernel(const u16* __restrict__ z4, const u16* __restrict__ g4,
                                  const float* __restrict__ alog1, const float* __restrict__ alog2,
                                  const float* __restrict__ carry, u16* __restrict__ U4) {
    int bid = blockIdx.x;
    int br = bid >> 8, b = (bid >> 5) & 7, c = bid & 31;
    int d0 = threadIdx.x * 2;
    const float* al = (br < 3) ? alog1 : alog2;
    float aA = sigm(al[d0]), aB = sigm(al[d0 + 1]);
    float aPA = aA, aPB = aB;
#pragma unroll
    for (int i = 0; i < 6; ++i) { aPA *= aPA; aPB *= aPB; }   // a^64
    float hA = 0.f, hB = 0.f;
    const float* cp = carry + ((size_t)((br * 8 + b) * 32)) * DD + d0;
    for (int cc = 0; cc < c; ++cc) {
        float2 cv = *(const float2*)(cp + (size_t)cc * DD);
        hA = cv.x + aPA * hA;
        hB = cv.y + aPB * hB;
    }
    size_t rowOff = ((size_t)(br * NB + b * LL + c * CHL)) * DD + d0;
    const u16* zp = z4 + rowOff;
    const u16* gp = g4 + rowOff;
    u16* up = U4 + rowOff;
    for (int t = 0; t < CHL; ++t) {
        u32 zv = *(const u32*)(zp + (size_t)t * DD);
        u32 gv = *(const u32*)(gp + (size_t)t * DD);
        float gA = b2f((u16)gv), gB = b2f((u16)(gv >> 16));
        hA = aA * hA + (1.f - aA) * b2f((u16)zv);
        hB = aB * hB + (1.f - aB) * b2f((u16)(zv >> 16));
        u32 o = (u32)f2b(hA * gA * sigm(gA)) | ((u32)f2b(hB * gB * sigm(gB)) << 16);
        *(u32*)(up + (size_t)t * DD) = o;
    }
}

// --- batched agg (fused relu+mask+br3-mamba-add), int4 idx batching ---------
__global__ void agg4_kernel(const u16* __restrict__ V5, const int* __restrict__ csr4,
                            const int* __restrict__ cnt, const float* __restrict__ deg,
                            const int* __restrict__ maskp, u16* __restrict__ Yin) {
    int tr = threadIdx.x & 31;        // dims 8*tr..8*tr+7
    int rsub = threadIdx.x >> 5;      // 0..7
    int rg = blockIdx.x * 8 + rsub;   // 0..NRT-1
    int br = rg >> 14, r = rg & (NB - 1), b = r >> 11;
    int n = cnt[r];
    const int* lst = csr4 + ((size_t)(br * NB + r)) * CAP;
    const u16* srcB = V5 + ((size_t)((br < 3 ? br : 4) * NB + (b << 11))) * DD + tr * 8;
    float acc[8] = {0.f, 0.f, 0.f, 0.f, 0.f, 0.f, 0.f, 0.f};
    int i = 0;
    for (; i + 4 <= n; i += 4) {
        int4 il = *(const int4*)(lst + i);
        union { uint4 q; u16 h[8]; } v0, v1, v2, v3;
        v0.q = *(const uint4*)(srcB + (size_t)il.x * DD);
        v1.q = *(const uint4*)(srcB + (size_t)il.y * DD);
        v2.q = *(const uint4*)(srcB + (size_t)il.z * DD);
        v3.q = *(const uint4*)(srcB + (size_t)il.w * DD);
#pragma unroll
        for (int k = 0; k < 8; ++k)
            acc[k] += b2f(v0.h[k]) + b2f(v1.h[k]) + b2f(v2.h[k]) + b2f(v3.h[k]);
    }
    for (; i < n; ++i) {
        int idx = lst[i];
        union { uint4 q; u16 h[8]; } v;
        v.q = *(const uint4*)(srcB + (size_t)idx * DD);
#pragma unroll
        for (int k = 0; k < 8; ++k) acc[k] += b2f(v.h[k]);
    }
    float inv = 1.f / deg[r];
    int msk = maskp[r];
    union { uint4 q; u16 h[8]; } mo;
    if (br == 3) mo.q = *(const uint4*)(V5 + ((size_t)(3 * NB + r)) * DD + tr * 8);
    union { uint4 q; u16 h[8]; } o;
#pragma unroll
    for (int k = 0; k < 8; ++k) {
        float v = acc[k] * inv;
        v = v > 0.f ? v : 0.f;
        if (br == 3) v += b2f(mo.h[k]);
        v = msk ? v : 0.f;
        o.h[k] = f2b(v);
    }
    *(uint4*)(Yin + (size_t)r * 1024 + (br << 8) + tr * 8) = o.q;
}

// ---------------- layernorm, wave-per-row (float4, shfl_xor butterfly) ------
__global__ void ln1_kernel(const float* __restrict__ Yt, const float* __restrict__ bvp,
                           const float* __restrict__ X, const float* __restrict__ gp,
                           const float* __restrict__ bp, float* __restrict__ X1f,
                           u16* __restrict__ X1b) {
    int wv = threadIdx.x >> 6, lane = threadIdx.x & 63;
    int r = blockIdx.x * 4 + wv;
    int d0 = lane << 2;
    float4 yv = *(const float4*)(Yt + (size_t)r * DD + d0);
    float4 bb = *(const float4*)(bvp + d0);
    float x[4] = { yv.x + bb.x, yv.y + bb.y, yv.z + bb.z, yv.w + bb.w };
    float s = x[0] + x[1] + x[2] + x[3];
#pragma unroll
    for (int o = 32; o > 0; o >>= 1) s += __shfl_xor(s, o, 64);
    float mu = s * (1.f / DD);
    float dx[4], ss = 0.f;
#pragma unroll
    for (int k = 0; k < 4; ++k) { dx[k] = x[k] - mu; ss += dx[k] * dx[k]; }
#pragma unroll
    for (int o = 32; o > 0; o >>= 1) ss += __shfl_xor(ss, o, 64);
    float rstd = rsqrtf(ss * (1.f / DD) + 1e-5f);
    float4 g4 = *(const float4*)(gp + d0);
    float4 b4 = *(const float4*)(bp + d0);
    float4 xv = *(const float4*)(X + (size_t)r * DD + d0);
    float gg[4] = { g4.x, g4.y, g4.z, g4.w };
    float bz[4] = { b4.x, b4.y, b4.z, b4.w };
    float xx[4] = { xv.x, xv.y, xv.z, xv.w };
    float o4[4];
    union { u64 q; u16 h[4]; } pk;
#pragma unroll
    for (int k = 0; k < 4; ++k) {
        float y = dx[k] * rstd * gg[k] + bz[k];
        o4[k] = xx[k] + y;
        pk.h[k] = f2b(o4[k]);
    }
    *(float4*)(X1f + (size_t)r * DD + d0) = (float4){o4[0], o4[1], o4[2], o4[3]};
    *(u64*)(X1b + (size_t)r * DD + d0) = pk.q;
}

__global__ void ln2_kernel(const float* __restrict__ Y2, const float* __restrict__ b2p,
                           const float* __restrict__ X1f, const float* __restrict__ gp,
                           const float* __restrict__ bp, float* __restrict__ Out) {
    int wv = threadIdx.x >> 6, lane = threadIdx.x & 63;
    int r = blockIdx.x * 4 + wv;
    int d0 = lane << 2;
    float4 yv = *(const float4*)(Y2 + (size_t)r * DD + d0);
    float4 bb = *(const float4*)(b2p + d0);
    float x[4] = { yv.x + bb.x, yv.y + bb.y, yv.z + bb.z, yv.w + bb.w };
    float s = x[0] + x[1] + x[2] + x[3];
#pragma unroll
    for (int o = 32; o > 0; o >>= 1) s += __shfl_xor(s, o, 64);
    float mu = s * (1.f / DD);
    float dx[4], ss = 0.f;
#pragma unroll
    for (int k = 0; k < 4; ++k) { dx[k] = x[k] - mu; ss += dx[k] * dx[k]; }
#pragma unroll
    for (int o = 32; o > 0; o >>= 1) ss += __shfl_xor(ss, o, 64);
    float rstd = rsqrtf(ss * (1.f / DD) + 1e-5f);
    float4 g4 = *(const float4*)(gp + d0);
    float4 b4 = *(const float4*)(bp + d0);
    float4 xv = *(const float4*)(X1f + (size_t)r * DD + d0);
    float o4[4];
    o4[0] = xv.x + dx[0] * rstd * g4.x + b4.x;
    o4[1] = xv.y + dx[1] * rstd * g4.y + b4.y;
    o4[2] = xv.z + dx[2] * rstd * g4.z + b4.z;
    o4[3] = xv.w + dx[3] * rstd * g4.w + b4.w;
    *(float4*)(Out + (size_t)r * DD + d0) = (float4){o4[0], o4[1], o4[2], o4[3]};
}

// ============================================================================
extern "C" void kernel_launch(void* const* d_in, const int* in_sizes, int n_in,
                              void* d_out, int out_size, void* d_ws, size_t ws_size,
                              hipStream_t stream) {
    const float* X      = (const float*)d_in[0];
    const int* maskp    = (const int*)d_in[1];
    const float* Adj    = (const float*)d_in[2];
    const int* si[3]    = { (const int*)d_in[3], (const int*)d_in[5], (const int*)d_in[7] };
    const int* ri[3]    = { (const int*)d_in[4], (const int*)d_in[6], (const int*)d_in[8] };
    const float* gm1_Win  = (const float*)d_in[9];
    const float* gm1_alog = (const float*)d_in[10];
    const float* gm1_Wout = (const float*)d_in[11];
    const float* gm2_We   = (const float*)d_in[12];
    const float* gm_Win   = (const float*)d_in[13];
    const float* gm_alog  = (const float*)d_in[14];
    const float* gm_Wout  = (const float*)d_in[15];
    const float* gm_We    = (const float*)d_in[16];
    const float* ln1_g    = (const float*)d_in[17];
    const float* ln1_b    = (const float*)d_in[18];
    const float* ln2_g    = (const float*)d_in[19];
    const float* ln2_b    = (const float*)d_in[20];
    const float* ffn_W1   = (const float*)d_in[21];
    const float* ffn_b1   = (const float*)d_in[22];
    const float* ffn_W2   = (const float*)d_in[23];
    const float* ffn_b2   = (const float*)d_in[24];
    const float* Wv       = (const float*)d_in[25];
    const float* bv       = (const float*)d_in[26];
    float* Out = (float*)d_out;

    char* ws = (char*)d_ws;
    size_t off = 0;
    auto alloc = [&](size_t bytes) { size_t o = off; off += (bytes + 255) & ~(size_t)255; return o; };

    u16* WinT1  = (u16*)(ws + alloc((size_t)512 * 256 * 2));
    u16* WinT   = (u16*)(ws + alloc((size_t)512 * 256 * 2));
    u16* WoutT  = (u16*)(ws + alloc((size_t)256 * 256 * 2));
    u16* WeT1   = (u16*)(ws + alloc((size_t)256 * 256 * 2));
    u16* WeT    = (u16*)(ws + alloc((size_t)256 * 256 * 2));
    u16* WvT    = (u16*)(ws + alloc((size_t)256 * 1024 * 2));
    u16* W1T    = (u16*)(ws + alloc((size_t)1024 * 256 * 2));
    u16* W2T    = (u16*)(ws + alloc((size_t)256 * 1024 * 2));
    u16* WoutL  = (u16*)(ws + alloc((size_t)256 * 256 * 2));   // gm1_Wout linear bf16
    u16* Wc1T   = (u16*)(ws + alloc((size_t)256 * 256 * 2));   // (Wout1@We1)^T
    u16* Xb     = (u16*)(ws + alloc((size_t)NB * DD * 2));     // masked X bf16
    int* csr4 = (int*)(ws + alloc((size_t)4 * NB * CAP * 4));  // 16.8 MB
    int* cnt = (int*)(ws + alloc((size_t)NB * 4));
    float* deg = (float*)(ws + alloc((size_t)NB * 4));
    float* carry = (float*)(ws + alloc((size_t)NBR * BB * NCH * DD * 4));
    u16* zbuf = (u16*)(ws + alloc((size_t)NRT * DD * 2));      // 33.6 MB
    u16* gbuf = (u16*)(ws + alloc((size_t)NRT * DD * 2));
    u16* U4   = (u16*)(ws + alloc((size_t)4 * NB * DD * 2));
    u16* V5   = (u16*)(ws + alloc((size_t)5 * NB * DD * 2));
    u16* Yin  = (u16*)(ws + alloc((size_t)NB * 1024 * 2));
    float* tmpY  = (float*)(ws + alloc((size_t)NB * DD * 4));
    float* X1f   = (float*)(ws + alloc((size_t)NB * DD * 4));
    u16* X1b     = (u16*)(ws + alloc((size_t)NB * DD * 2));
    u16* H       = (u16*)(ws + alloc((size_t)NB * 1024 * 2));
    float* tmpY2 = (float*)(ws + alloc((size_t)NB * DD * 4));
    (void)ws_size; (void)in_sizes; (void)n_in; (void)out_size;

    // 1. Xb = mask(X) -> bf16
    xb_kernel<<<NB * DD / 4 / 256, 256, 0, stream>>>(X, maskp, Xb);

    // 2. all weight transposes/copies in one launch
    TrArgs ta;
    const float* srcs[9] = { gm1_Win, gm_Win, gm_Wout, gm2_We, gm_We, Wv, ffn_W1, ffn_W2, gm1_Wout };
    u16* dsts[9]         = { WinT1,   WinT,   WoutT,   WeT1,   WeT,   WvT, W1T,   W2T,    WoutL };
    int Ks[9] = { 256, 256, 256, 256, 256, 1024, 256, 1024, 256 };
    int Ns[9] = { 512, 512, 256, 256, 256, 256, 1024, 256, 256 };
    int trs[9] = { 1, 1, 1, 1, 1, 1, 1, 1, 0 };
    int cum = 0;
    for (int i = 0; i < 9; ++i) {
        ta.s[i] = srcs[i]; ta.d[i] = dsts[i]; ta.K[i] = Ks[i]; ta.N[i] = Ns[i]; ta.tr[i] = trs[i];
        ta.beg[i] = cum; cum += (Ks[i] * Ns[i]) / 256;
    }
    ta.beg[9] = cum;
    transpose_all<<<cum, 256, 0, stream>>>(ta);

    // 3. Wc1T = WeT1 @ WoutL  (==(Wout1@We1)^T)
    gemm_kernel<<<dim3(2, 2), 256, 0, stream>>>(
        WeT1, WeT1, 1 << 30, WoutL, WoutL, WoutL, 1 << 30, 1 << 30,
        (void*)Wc1T, nullptr, 256, 256, 2);

    // 4. CSR (+ri-composed lists)
    csr_kernel<<<NB / 4, 256, 0, stream>>>(Adj, ri[0], ri[1], ri[2], csr4, cnt, deg);

    // 5. Win GEMM, gathered Xb A-staging -> planar z/g bf16
    gemm_win_kernel<<<dim3(NRT / 128, 512 / 128), 256, 0, stream>>>(
        Xb, si[0], si[1], si[2], WinT1, WinT, zbuf, gbuf);

    // 6-7. batched scan (2 dims/thread; combine folded into apply) -> U4
    scan_carry_kernel<<<NBR * BB * NCH, 128, 0, stream>>>(zbuf, gm1_alog, gm_alog, carry);
    scan_apply_kernel<<<NBR * BB * NCH, 128, 0, stream>>>(zbuf, gbuf, gm1_alog, gm_alog, carry, U4);

    // 8. combined GEMM: rows [0,4NB) from U4, [4NB,5NB) from Xb;
    //    B: br<3 @Wc1T, br3 @WoutT, Xb-seg @WeT -> V5
    gemm_kernel<<<dim3(5 * NB / 128, 2), 256, 0, stream>>>(
        U4, Xb, 4 * NB, Wc1T, WoutT, WeT, 3 * NB, 4 * NB,
        (void*)V5, nullptr, 256, 256, 2);

    // 9. fused aggregation (relu + mask + br3 mamba add) -> Yin slots
    agg4_kernel<<<NRT / 8, 256, 0, stream>>>(V5, csr4, cnt, deg, maskp, Yin);

    // 10. Wv GEMM: [NB,1024] @ [1024,256] -> tmpY f32
    gemm_kernel<<<dim3(NB / 128, 2), 256, 0, stream>>>(
        Yin, Yin, 1 << 30, WvT, WvT, WvT, 1 << 30, 1 << 30,
        (void*)tmpY, nullptr, 256, 1024, 0);

    // 11. LN1 (+bv fold, +X residual), wave-per-row
    ln1_kernel<<<NB / 4, 256, 0, stream>>>(tmpY, bv, X, ln1_g, ln1_b, X1f, X1b);

    // 12. FFN1: [NB,256] @ [256,1024] +b1, relu -> H bf16
    gemm_kernel<<<dim3(NB / 128, 8), 256, 0, stream>>>(
        X1b, X1b, 1 << 30, W1T, W1T, W1T, 1 << 30, 1 << 30,
        (void*)H, ffn_b1, 1024, 256, 1);

    // 13. FFN2: [NB,1024] @ [1024,256] -> tmpY2 f32
    gemm_kernel<<<dim3(NB / 128, 2), 256, 0, stream>>>(
        H, H, 1 << 30, W2T, W2T, W2T, 1 << 30, 1 << 30,
        (void*)tmpY2, nullptr, 256, 1024, 0);

    // 14. LN2 (+b2 fold, +X1 residual) -> Out f32
    ln2_kernel<<<NB / 4, 256, 0, stream>>>(tmpY2, ffn_b2, X1f, ln2_g, ln2_b, Out);
}

// Round 9
// 257.510 us; speedup vs baseline: 3.0065x; 1.0707x over previous
//
#include <hip/hip_runtime.h>

typedef unsigned short u16;
typedef unsigned int u32;
typedef unsigned long long u64;

#define BB 8
#define LL 2048
#define DD 256
#define NB (BB * LL)      // 16384 rows per branch
#define NBR 4
#define NRT (NBR * NB)    // 65536 batched rows
#define NCH 32
#define CHL (LL / NCH)    // 64
#define CAP 64

typedef __attribute__((ext_vector_type(8))) __bf16 bf16x8;
typedef __attribute__((ext_vector_type(4))) float f32x4;

__device__ __forceinline__ float b2f(u16 u) {
    union { u32 u; float f; } x; x.u = ((u32)u) << 16; return x.f;
}
__device__ __forceinline__ u16 f2b(float f) {
    union { float f; u32 u; } x; x.f = f;
    u32 r = (x.u >> 16) & 1u;
    x.u += 0x7FFFu + r;
    return (u16)(x.u >> 16);
}
__device__ __forceinline__ float sigm(float x) { return 1.f / (1.f + __expf(-x)); }

#define GLD(gp, lp) __builtin_amdgcn_global_load_lds( \
    (const __attribute__((address_space(1))) void*)(gp), \
    (__attribute__((address_space(3))) void*)(lp), 16, 0, 0)

// ---- batched weight transpose/copy + cast (jobs 0-8) + Xb mask-cast (job 9)
struct TrArgs {
    const float* s[9];
    u16* d[9];
    int K[9], N[9], tr[9];
    int beg[11];
    const float* xsrc;
    const int* maskp;
    u16* xdst;
};
__global__ void transpose_all(TrArgs a) {
    int blk = blockIdx.x;
    int i = 0;
    while (blk >= a.beg[i + 1]) ++i;
    if (i == 9) {                                  // Xb = mask(X) -> bf16
        int g = (blk - a.beg[9]) * 256 + threadIdx.x;
        int r = g >> 6;                            // 64 quads per row
        float4 v = a.maskp[r] ? *(const float4*)(a.xsrc + (size_t)g * 4)
                              : (float4){0.f, 0.f, 0.f, 0.f};
        union { u64 q; u16 h[4]; } pk;
        pk.h[0] = f2b(v.x); pk.h[1] = f2b(v.y); pk.h[2] = f2b(v.z); pk.h[3] = f2b(v.w);
        *(u64*)(a.xdst + (size_t)g * 4) = pk.q;
        return;
    }
    int idx = (blk - a.beg[i]) * 256 + threadIdx.x;
    int K = a.K[i], N = a.N[i];
    if (idx >= K * N) return;
    if (a.tr[i]) {
        int k = idx / N, n = idx - k * N;
        a.d[i][(size_t)n * K + k] = f2b(a.s[i][idx]);
    } else {
        a.d[i][idx] = f2b(a.s[i][idx]);
    }
}

// ---- CSR build; writes ri-composed index lists for br<3, raw for br3 -------
__global__ void csr_kernel(const float* __restrict__ Adj,
                           const int* __restrict__ ri0, const int* __restrict__ ri1,
                           const int* __restrict__ ri2,
                           int* __restrict__ csr4, int* __restrict__ cnt,
                           float* __restrict__ deg) {
    int w = threadIdx.x >> 6, lane = threadIdx.x & 63;
    int row = blockIdx.x * 4 + w;                 // 0..NB-1
    int rowb = row & ~(LL - 1);                   // (b<<11)
    const float* arow = Adj + (size_t)row * LL;
    int base = 0;
    for (int c = 0; c < LL / 256; ++c) {          // 8 iterations
        float4 v = *(const float4*)(arow + c * 256 + lane * 4);
#pragma unroll
        for (int e = 0; e < 4; ++e) {
            float f = (e == 0) ? v.x : (e == 1) ? v.y : (e == 2) ? v.z : v.w;
            bool nz = (f != 0.f);
            u64 m = __ballot(nz);
            if (nz) {
                int pos = base + __popcll(m & ((1ull << lane) - 1ull));
                if (pos < CAP) {
                    int j = c * 256 + lane * 4 + e;
                    csr4[((size_t)(3 * NB + row)) * CAP + pos] = j;
                    csr4[((size_t)(0 * NB + row)) * CAP + pos] = ri0[rowb + j];
                    csr4[((size_t)(1 * NB + row)) * CAP + pos] = ri1[rowb + j];
                    csr4[((size_t)(2 * NB + row)) * CAP + pos] = ri2[rowb + j];
                }
            }
            base += __popcll(m);
        }
    }
    if (lane == 0) {
        cnt[row] = base < CAP ? base : CAP;
        deg[row] = (float)(base < 1 ? 1 : base);
    }
}

// ------- Win GEMM, A = row-gathered Xb; 2-phase dbuf pipeline ---------------
__global__ __launch_bounds__(256)
void gemm_win_kernel(const u16* __restrict__ Xb,
                     const int* __restrict__ si0, const int* __restrict__ si1,
                     const int* __restrict__ si2,
                     const u16* __restrict__ Bt1, const u16* __restrict__ Bt2,
                     u16* __restrict__ zbuf, u16* __restrict__ gbuf)
{
    __shared__ __align__(16) u16 As[2][128 * 32];
    __shared__ __align__(16) u16 Bs[2][128 * 32];
    int tid = threadIdx.x, lane = tid & 63;
    int w = tid >> 6, wm = w >> 1, wn = w & 1;
    int rowBase = blockIdx.x * 128, colBase = blockIdx.y * 128;
    const u16* Bt = (rowBase < 3 * NB) ? Bt1 : Bt2;

    const u16* pa[2];
    const u16* pb[2];
#pragma unroll
    for (int rep = 0; rep < 2; ++rep) {
        int s = rep * 256 + tid;
        int row = s >> 2, kk = (s & 3) << 3;
        int rg = rowBase + row;
        int br = rg >> 14, r = rg & (NB - 1), b = r >> 11, l = r & (LL - 1);
        int src = (br == 0) ? si0[r] : (br == 1) ? si1[r] : (br == 2) ? si2[r] : l;
        pa[rep] = Xb + ((size_t)(b << 11) + src) * DD + kk;
        pb[rep] = Bt + (size_t)(colBase + row) * 256 + kk;
    }

    f32x4 acc[4][4];
#pragma unroll
    for (int m = 0; m < 4; ++m)
#pragma unroll
        for (int n = 0; n < 4; ++n) acc[m][n] = (f32x4){0.f, 0.f, 0.f, 0.f};

#pragma unroll
    for (int rep = 0; rep < 2; ++rep) {
        int s = rep * 256 + tid;
        GLD(pa[rep], As[0] + s * 8);
        GLD(pb[rep], Bs[0] + s * 8);
    }
    int p = 0;
    for (int t = 0; t < 8; ++t) {
        if (t + 1 < 8) {
            int k0 = (t + 1) * 32;
#pragma unroll
            for (int rep = 0; rep < 2; ++rep) {
                int s = rep * 256 + tid;
                GLD(pa[rep] + k0, As[p ^ 1] + s * 8);
                GLD(pb[rep] + k0, Bs[p ^ 1] + s * 8);
            }
            asm volatile("s_waitcnt vmcnt(4)" ::: "memory");
        } else {
            asm volatile("s_waitcnt vmcnt(0)" ::: "memory");
        }
        __builtin_amdgcn_s_barrier();
        int kq = (lane >> 4) << 3;
        bf16x8 av[4], bw[4];
#pragma unroll
        for (int m = 0; m < 4; ++m)
            av[m] = *(const bf16x8*)(As[p] + (wm * 64 + m * 16 + (lane & 15)) * 32 + kq);
#pragma unroll
        for (int n = 0; n < 4; ++n)
            bw[n] = *(const bf16x8*)(Bs[p] + (wn * 64 + n * 16 + (lane & 15)) * 32 + kq);
#pragma unroll
        for (int m = 0; m < 4; ++m)
#pragma unroll
            for (int n = 0; n < 4; ++n)
                acc[m][n] = __builtin_amdgcn_mfma_f32_16x16x32_bf16(av[m], bw[n], acc[m][n], 0, 0, 0);
        __builtin_amdgcn_s_barrier();
        p ^= 1;
    }

    u16* Cz;
    int cb;
    if (colBase < 256) { Cz = zbuf; cb = colBase; }
    else               { Cz = gbuf; cb = colBase - 256; }
    int cBase = cb + wn * 64 + (lane & 15);
    int rBase = rowBase + wm * 64 + ((lane >> 4) << 2);
#pragma unroll
    for (int m = 0; m < 4; ++m)
#pragma unroll
        for (int n = 0; n < 4; ++n)
#pragma unroll
            for (int r = 0; r < 4; ++r)
                Cz[(size_t)(rBase + m * 16 + r) * 256 + (cBase + n * 16)] = f2b(acc[m][n][r]);
}

// --------- generic GEMM: 2-way A row-split, 3-way B weights, dbuf pipeline --
// mode 1: bias(f32)+relu+bf16; mode 2: plain bf16
__global__ __launch_bounds__(256)
void gemm_kernel(const u16* __restrict__ A1, const u16* __restrict__ A2, int asplit,
                 const u16* __restrict__ Bt1, const u16* __restrict__ Bt2,
                 const u16* __restrict__ Bt3, int split1, int split2,
                 void* __restrict__ Cout, const float* __restrict__ bias,
                 int N, int K, int mode)
{
    __shared__ __align__(16) u16 As[2][128 * 32];
    __shared__ __align__(16) u16 Bs[2][128 * 32];
    int tid = threadIdx.x;
    int lane = tid & 63;
    int w = tid >> 6, wm = w >> 1, wn = w & 1;
    int rowBase = blockIdx.x * 128, colBase = blockIdx.y * 128;
    const u16* Bt = (rowBase < split1) ? Bt1 : (rowBase < split2) ? Bt2 : Bt3;
    const u16* Arow = (rowBase < asplit) ? A1 + (size_t)rowBase * K
                                         : A2 + (size_t)(rowBase - asplit) * K;

    const u16* pa[2];
    const u16* pb[2];
#pragma unroll
    for (int rep = 0; rep < 2; ++rep) {
        int s = rep * 256 + tid;
        int row = s >> 2, kk = (s & 3) << 3;
        pa[rep] = Arow + (size_t)row * K + kk;
        pb[rep] = Bt + (size_t)(colBase + row) * K + kk;
    }

    f32x4 acc[4][4];
#pragma unroll
    for (int m = 0; m < 4; ++m)
#pragma unroll
        for (int n = 0; n < 4; ++n) acc[m][n] = (f32x4){0.f, 0.f, 0.f, 0.f};

    int nt = K >> 5;
#pragma unroll
    for (int rep = 0; rep < 2; ++rep) {
        int s = rep * 256 + tid;
        GLD(pa[rep], As[0] + s * 8);
        GLD(pb[rep], Bs[0] + s * 8);
    }
    int p = 0;
    for (int t = 0; t < nt; ++t) {
        if (t + 1 < nt) {
            int k0 = (t + 1) << 5;
#pragma unroll
            for (int rep = 0; rep < 2; ++rep) {
                int s = rep * 256 + tid;
                GLD(pa[rep] + k0, As[p ^ 1] + s * 8);
                GLD(pb[rep] + k0, Bs[p ^ 1] + s * 8);
            }
            asm volatile("s_waitcnt vmcnt(4)" ::: "memory");
        } else {
            asm volatile("s_waitcnt vmcnt(0)" ::: "memory");
        }
        __builtin_amdgcn_s_barrier();
        int kq = (lane >> 4) << 3;
        bf16x8 av[4], bw[4];
#pragma unroll
        for (int m = 0; m < 4; ++m)
            av[m] = *(const bf16x8*)(As[p] + (wm * 64 + m * 16 + (lane & 15)) * 32 + kq);
#pragma unroll
        for (int n = 0; n < 4; ++n)
            bw[n] = *(const bf16x8*)(Bs[p] + (wn * 64 + n * 16 + (lane & 15)) * 32 + kq);
#pragma unroll
        for (int m = 0; m < 4; ++m)
#pragma unroll
            for (int n = 0; n < 4; ++n)
                acc[m][n] = __builtin_amdgcn_mfma_f32_16x16x32_bf16(av[m], bw[n], acc[m][n], 0, 0, 0);
        __builtin_amdgcn_s_barrier();
        p ^= 1;
    }

    int cBase = colBase + wn * 64 + (lane & 15);
    int rBase = rowBase + wm * 64 + ((lane >> 4) << 2);
    u16* C = (u16*)Cout;
    float bz[4];
#pragma unroll
    for (int n = 0; n < 4; ++n) bz[n] = bias ? bias[cBase + n * 16] : 0.f;
#pragma unroll
    for (int m = 0; m < 4; ++m)
#pragma unroll
        for (int n = 0; n < 4; ++n)
#pragma unroll
            for (int r = 0; r < 4; ++r) {
                float v = acc[m][n][r] + bz[n];
                if (mode == 1) v = v > 0.f ? v : 0.f;
                C[(size_t)(rBase + m * 16 + r) * N + (cBase + n * 16)] = f2b(v);
            }
}

// --------- split-K2 GEMM for K=1024 (lda=ldb=1024): z picks K-half + output -
__global__ __launch_bounds__(256)
void gemm_splitk2_kernel(const u16* __restrict__ A, const u16* __restrict__ Bt,
                         u16* __restrict__ C0, u16* __restrict__ C1)
{
    __shared__ __align__(16) u16 As[2][128 * 32];
    __shared__ __align__(16) u16 Bs[2][128 * 32];
    int tid = threadIdx.x;
    int lane = tid & 63;
    int w = tid >> 6, wm = w >> 1, wn = w & 1;
    int rowBase = blockIdx.x * 128, colBase = blockIdx.y * 128;
    int koff = blockIdx.z * 512;

    const u16* pa[2];
    const u16* pb[2];
#pragma unroll
    for (int rep = 0; rep < 2; ++rep) {
        int s = rep * 256 + tid;
        int row = s >> 2, kk = (s & 3) << 3;
        pa[rep] = A + (size_t)(rowBase + row) * 1024 + koff + kk;
        pb[rep] = Bt + (size_t)(colBase + row) * 1024 + koff + kk;
    }

    f32x4 acc[4][4];
#pragma unroll
    for (int m = 0; m < 4; ++m)
#pragma unroll
        for (int n = 0; n < 4; ++n) acc[m][n] = (f32x4){0.f, 0.f, 0.f, 0.f};

#pragma unroll
    for (int rep = 0; rep < 2; ++rep) {
        int s = rep * 256 + tid;
        GLD(pa[rep], As[0] + s * 8);
        GLD(pb[rep], Bs[0] + s * 8);
    }
    int p = 0;
    for (int t = 0; t < 16; ++t) {
        if (t + 1 < 16) {
            int k0 = (t + 1) << 5;
#pragma unroll
            for (int rep = 0; rep < 2; ++rep) {
                int s = rep * 256 + tid;
                GLD(pa[rep] + k0, As[p ^ 1] + s * 8);
                GLD(pb[rep] + k0, Bs[p ^ 1] + s * 8);
            }
            asm volatile("s_waitcnt vmcnt(4)" ::: "memory");
        } else {
            asm volatile("s_waitcnt vmcnt(0)" ::: "memory");
        }
        __builtin_amdgcn_s_barrier();
        int kq = (lane >> 4) << 3;
        bf16x8 av[4], bw[4];
#pragma unroll
        for (int m = 0; m < 4; ++m)
            av[m] = *(const bf16x8*)(As[p] + (wm * 64 + m * 16 + (lane & 15)) * 32 + kq);
#pragma unroll
        for (int n = 0; n < 4; ++n)
            bw[n] = *(const bf16x8*)(Bs[p] + (wn * 64 + n * 16 + (lane & 15)) * 32 + kq);
#pragma unroll
        for (int m = 0; m < 4; ++m)
#pragma unroll
            for (int n = 0; n < 4; ++n)
                acc[m][n] = __builtin_amdgcn_mfma_f32_16x16x32_bf16(av[m], bw[n], acc[m][n], 0, 0, 0);
        __builtin_amdgcn_s_barrier();
        p ^= 1;
    }

    u16* C = blockIdx.z ? C1 : C0;
    int cBase = colBase + wn * 64 + (lane & 15);
    int rBase = rowBase + wm * 64 + ((lane >> 4) << 2);
#pragma unroll
    for (int m = 0; m < 4; ++m)
#pragma unroll
        for (int n = 0; n < 4; ++n)
#pragma unroll
            for (int r = 0; r < 4; ++r)
                C[(size_t)(rBase + m * 16 + r) * 256 + (cBase + n * 16)] = f2b(acc[m][n][r]);
}

// ---------------- batched chunked EMA scan (planar z/g, 2 dims/thread) ------
__global__ void scan_carry_kernel(const u16* __restrict__ z4, const float* __restrict__ alog1,
                                  const float* __restrict__ alog2, float* __restrict__ carry) {
    int bid = blockIdx.x;                          // (br,b,c)
    int br = bid >> 8, b = (bid >> 5) & 7, c = bid & 31;
    int d0 = threadIdx.x * 2;                      // 128 threads
    const float* al = (br < 3) ? alog1 : alog2;
    float aA = sigm(al[d0]), aB = sigm(al[d0 + 1]);
    float hA = 0.f, hB = 0.f;
    const u16* zp = z4 + ((size_t)(br * NB + b * LL + c * CHL) * DD) + d0;
    for (int t = 0; t < CHL; ++t) {
        u32 v = *(const u32*)(zp + (size_t)t * DD);
        hA = aA * hA + (1.f - aA) * b2f((u16)v);
        hB = aB * hB + (1.f - aB) * b2f((u16)(v >> 16));
    }
    carry[(size_t)bid * DD + d0] = hA;
    carry[(size_t)bid * DD + d0 + 1] = hB;
}

// apply with inline chunk-combine (start recomputed from carries)
__global__ void scan_apply_kernel(const u16* __restrict__ z4, const u16* __restrict__ g4,
                                  const float* __restrict__ alog1, const float* __restrict__ alog2,
                                  const float* __restrict__ carry, u16* __restrict__ U4) {
    int bid = blockIdx.x;
    int br = bid >> 8, b = (bid >> 5) & 7, c = bid & 31;
    int d0 = threadIdx.x * 2;
    const float* al = (br < 3) ? alog1 : alog2;
    float aA = sigm(al[d0]), aB = sigm(al[d0 + 1]);
    float aPA = aA, aPB = aB;
#pragma unroll
    for (int i = 0; i < 6; ++i) { aPA *= aPA; aPB *= aPB; }   // a^64
    float hA = 0.f, hB = 0.f;
    const float* cp = carry + ((size_t)((br * 8 + b) * 32)) * DD + d0;
    for (int cc = 0; cc < c; ++cc) {
        float2 cv = *(const float2*)(cp + (size_t)cc * DD);
        hA = cv.x + aPA * hA;
        hB = cv.y + aPB * hB;
    }
    size_t rowOff = ((size_t)(br * NB + b * LL + c * CHL)) * DD + d0;
    const u16* zp = z4 + rowOff;
    const u16* gp = g4 + rowOff;
    u16* up = U4 + rowOff;
    for (int t = 0; t < CHL; ++t) {
        u32 zv = *(const u32*)(zp + (size_t)t * DD);
        u32 gv = *(const u32*)(gp + (size_t)t * DD);
        float gA = b2f((u16)gv), gB = b2f((u16)(gv >> 16));
        hA = aA * hA + (1.f - aA) * b2f((u16)zv);
        hB = aB * hB + (1.f - aB) * b2f((u16)(zv >> 16));
        u32 o = (u32)f2b(hA * gA * sigm(gA)) | ((u32)f2b(hB * gB * sigm(gB)) << 16);
        *(u32*)(up + (size_t)t * DD) = o;
    }
}

// --- batched agg (fused relu+mask+br3-mamba-add), int4 idx batching ---------
__global__ void agg4_kernel(const u16* __restrict__ V5, const int* __restrict__ csr4,
                            const int* __restrict__ cnt, const float* __restrict__ deg,
                            const int* __restrict__ maskp, u16* __restrict__ Yin) {
    int tr = threadIdx.x & 31;        // dims 8*tr..8*tr+7
    int rsub = threadIdx.x >> 5;      // 0..7
    int rg = blockIdx.x * 8 + rsub;   // 0..NRT-1
    int br = rg >> 14, r = rg & (NB - 1), b = r >> 11;
    int n = cnt[r];
    const int* lst = csr4 + ((size_t)(br * NB + r)) * CAP;
    const u16* srcB = V5 + ((size_t)((br < 3 ? br : 4) * NB + (b << 11))) * DD + tr * 8;
    float acc[8] = {0.f, 0.f, 0.f, 0.f, 0.f, 0.f, 0.f, 0.f};
    int i = 0;
    for (; i + 4 <= n; i += 4) {
        int4 il = *(const int4*)(lst + i);
        union { uint4 q; u16 h[8]; } v0, v1, v2, v3;
        v0.q = *(const uint4*)(srcB + (size_t)il.x * DD);
        v1.q = *(const uint4*)(srcB + (size_t)il.y * DD);
        v2.q = *(const uint4*)(srcB + (size_t)il.z * DD);
        v3.q = *(const uint4*)(srcB + (size_t)il.w * DD);
#pragma unroll
        for (int k = 0; k < 8; ++k)
            acc[k] += b2f(v0.h[k]) + b2f(v1.h[k]) + b2f(v2.h[k]) + b2f(v3.h[k]);
    }
    for (; i < n; ++i) {
        int idx = lst[i];
        union { uint4 q; u16 h[8]; } v;
        v.q = *(const uint4*)(srcB + (size_t)idx * DD);
#pragma unroll
        for (int k = 0; k < 8; ++k) acc[k] += b2f(v.h[k]);
    }
    float inv = 1.f / deg[r];
    int msk = maskp[r];
    union { uint4 q; u16 h[8]; } mo;
    if (br == 3) mo.q = *(const uint4*)(V5 + ((size_t)(3 * NB + r)) * DD + tr * 8);
    union { uint4 q; u16 h[8]; } o;
#pragma unroll
    for (int k = 0; k < 8; ++k) {
        float v = acc[k] * inv;
        v = v > 0.f ? v : 0.f;
        if (br == 3) v += b2f(mo.h[k]);
        v = msk ? v : 0.f;
        o.h[k] = f2b(v);
    }
    *(uint4*)(Yin + (size_t)r * 1024 + (br << 8) + tr * 8) = o.q;
}

// ---------------- layernorm, wave-per-row; Y = sum of two bf16 partials -----
__global__ void ln1_kernel(const u16* __restrict__ Ya, const u16* __restrict__ Yb,
                           const float* __restrict__ bvp,
                           const float* __restrict__ X, const float* __restrict__ gp,
                           const float* __restrict__ bp, float* __restrict__ X1f,
                           u16* __restrict__ X1b) {
    int wv = threadIdx.x >> 6, lane = threadIdx.x & 63;
    int r = blockIdx.x * 4 + wv;
    int d0 = lane << 2;
    union { u64 q; u16 h[4]; } ya, yb;
    ya.q = *(const u64*)(Ya + (size_t)r * DD + d0);
    yb.q = *(const u64*)(Yb + (size_t)r * DD + d0);
    float4 bb = *(const float4*)(bvp + d0);
    float x[4];
#pragma unroll
    for (int k = 0; k < 4; ++k) x[k] = b2f(ya.h[k]) + b2f(yb.h[k]) + (&bb.x)[k];
    float s = x[0] + x[1] + x[2] + x[3];
#pragma unroll
    for (int o = 32; o > 0; o >>= 1) s += __shfl_xor(s, o, 64);
    float mu = s * (1.f / DD);
    float dx[4], ss = 0.f;
#pragma unroll
    for (int k = 0; k < 4; ++k) { dx[k] = x[k] - mu; ss += dx[k] * dx[k]; }
#pragma unroll
    for (int o = 32; o > 0; o >>= 1) ss += __shfl_xor(ss, o, 64);
    float rstd = rsqrtf(ss * (1.f / DD) + 1e-5f);
    float4 g4 = *(const float4*)(gp + d0);
    float4 b4 = *(const float4*)(bp + d0);
    float4 xv = *(const float4*)(X + (size_t)r * DD + d0);
    float o4[4];
    union { u64 q; u16 h[4]; } pk;
#pragma unroll
    for (int k = 0; k < 4; ++k) {
        float y = dx[k] * rstd * (&g4.x)[k] + (&b4.x)[k];
        o4[k] = (&xv.x)[k] + y;
        pk.h[k] = f2b(o4[k]);
    }
    *(float4*)(X1f + (size_t)r * DD + d0) = (float4){o4[0], o4[1], o4[2], o4[3]};
    *(u64*)(X1b + (size_t)r * DD + d0) = pk.q;
}

__global__ void ln2_kernel(const u16* __restrict__ Ya, const u16* __restrict__ Yb,
                           const float* __restrict__ b2p,
                           const float* __restrict__ X1f, const float* __restrict__ gp,
                           const float* __restrict__ bp, float* __restrict__ Out) {
    int wv = threadIdx.x >> 6, lane = threadIdx.x & 63;
    int r = blockIdx.x * 4 + wv;
    int d0 = lane << 2;
    union { u64 q; u16 h[4]; } ya, yb;
    ya.q = *(const u64*)(Ya + (size_t)r * DD + d0);
    yb.q = *(const u64*)(Yb + (size_t)r * DD + d0);
    float4 bb = *(const float4*)(b2p + d0);
    float x[4];
#pragma unroll
    for (int k = 0; k < 4; ++k) x[k] = b2f(ya.h[k]) + b2f(yb.h[k]) + (&bb.x)[k];
    float s = x[0] + x[1] + x[2] + x[3];
#pragma unroll
    for (int o = 32; o > 0; o >>= 1) s += __shfl_xor(s, o, 64);
    float mu = s * (1.f / DD);
    float dx[4], ss = 0.f;
#pragma unroll
    for (int k = 0; k < 4; ++k) { dx[k] = x[k] - mu; ss += dx[k] * dx[k]; }
#pragma unroll
    for (int o = 32; o > 0; o >>= 1) ss += __shfl_xor(ss, o, 64);
    float rstd = rsqrtf(ss * (1.f / DD) + 1e-5f);
    float4 g4 = *(const float4*)(gp + d0);
    float4 b4 = *(const float4*)(bp + d0);
    float4 xv = *(const float4*)(X1f + (size_t)r * DD + d0);
    float o4[4];
#pragma unroll
    for (int k = 0; k < 4; ++k)
        o4[k] = (&xv.x)[k] + dx[k] * rstd * (&g4.x)[k] + (&b4.x)[k];
    *(float4*)(Out + (size_t)r * DD + d0) = (float4){o4[0], o4[1], o4[2], o4[3]};
}

// ============================================================================
extern "C" void kernel_launch(void* const* d_in, const int* in_sizes, int n_in,
                              void* d_out, int out_size, void* d_ws, size_t ws_size,
                              hipStream_t stream) {
    const float* X      = (const float*)d_in[0];
    const int* maskp    = (const int*)d_in[1];
    const float* Adj    = (const float*)d_in[2];
    const int* si[3]    = { (const int*)d_in[3], (const int*)d_in[5], (const int*)d_in[7] };
    const int* ri[3]    = { (const int*)d_in[4], (const int*)d_in[6], (const int*)d_in[8] };
    const float* gm1_Win  = (const float*)d_in[9];
    const float* gm1_alog = (const float*)d_in[10];
    const float* gm1_Wout = (const float*)d_in[11];
    const float* gm2_We   = (const float*)d_in[12];
    const float* gm_Win   = (const float*)d_in[13];
    const float* gm_alog  = (const float*)d_in[14];
    const float* gm_Wout  = (const float*)d_in[15];
    const float* gm_We    = (const float*)d_in[16];
    const float* ln1_g    = (const float*)d_in[17];
    const float* ln1_b    = (const float*)d_in[18];
    const float* ln2_g    = (const float*)d_in[19];
    const float* ln2_b    = (const float*)d_in[20];
    const float* ffn_W1   = (const float*)d_in[21];
    const float* ffn_b1   = (const float*)d_in[22];
    const float* ffn_W2   = (const float*)d_in[23];
    const float* ffn_b2   = (const float*)d_in[24];
    const float* Wv       = (const float*)d_in[25];
    const float* bv       = (const float*)d_in[26];
    float* Out = (float*)d_out;

    char* ws = (char*)d_ws;
    size_t off = 0;
    auto alloc = [&](size_t bytes) { size_t o = off; off += (bytes + 255) & ~(size_t)255; return o; };

    u16* WinT1  = (u16*)(ws + alloc((size_t)512 * 256 * 2));
    u16* WinT   = (u16*)(ws + alloc((size_t)512 * 256 * 2));
    u16* WoutT  = (u16*)(ws + alloc((size_t)256 * 256 * 2));
    u16* WeT1   = (u16*)(ws + alloc((size_t)256 * 256 * 2));
    u16* WeT    = (u16*)(ws + alloc((size_t)256 * 256 * 2));
    u16* WvT    = (u16*)(ws + alloc((size_t)256 * 1024 * 2));
    u16* W1T    = (u16*)(ws + alloc((size_t)1024 * 256 * 2));
    u16* W2T    = (u16*)(ws + alloc((size_t)256 * 1024 * 2));
    u16* WoutL  = (u16*)(ws + alloc((size_t)256 * 256 * 2));   // gm1_Wout linear bf16
    u16* Wc1T   = (u16*)(ws + alloc((size_t)256 * 256 * 2));   // (Wout1@We1)^T
    u16* Xb     = (u16*)(ws + alloc((size_t)NB * DD * 2));     // masked X bf16
    int* csr4 = (int*)(ws + alloc((size_t)4 * NB * CAP * 4));  // 16.8 MB
    int* cnt = (int*)(ws + alloc((size_t)NB * 4));
    float* deg = (float*)(ws + alloc((size_t)NB * 4));
    float* carry = (float*)(ws + alloc((size_t)NBR * BB * NCH * DD * 4));
    u16* zbuf = (u16*)(ws + alloc((size_t)NRT * DD * 2));      // 33.6 MB
    u16* gbuf = (u16*)(ws + alloc((size_t)NRT * DD * 2));
    u16* U4   = (u16*)(ws + alloc((size_t)4 * NB * DD * 2));
    u16* V5   = (u16*)(ws + alloc((size_t)5 * NB * DD * 2));
    u16* Yin  = (u16*)(ws + alloc((size_t)NB * 1024 * 2));
    u16* tmpYa  = (u16*)(ws + alloc((size_t)NB * DD * 2));
    u16* tmpYb  = (u16*)(ws + alloc((size_t)NB * DD * 2));
    float* X1f   = (float*)(ws + alloc((size_t)NB * DD * 4));
    u16* X1b     = (u16*)(ws + alloc((size_t)NB * DD * 2));
    u16* H       = (u16*)(ws + alloc((size_t)NB * 1024 * 2));
    u16* tmpY2a  = (u16*)(ws + alloc((size_t)NB * DD * 2));
    u16* tmpY2b  = (u16*)(ws + alloc((size_t)NB * DD * 2));
    (void)ws_size; (void)in_sizes; (void)n_in; (void)out_size;

    // 1. weight transposes/copies + Xb mask-cast, one launch
    TrArgs ta;
    const float* srcs[9] = { gm1_Win, gm_Win, gm_Wout, gm2_We, gm_We, Wv, ffn_W1, ffn_W2, gm1_Wout };
    u16* dsts[9]         = { WinT1,   WinT,   WoutT,   WeT1,   WeT,   WvT, W1T,   W2T,    WoutL };
    int Ks[9] = { 256, 256, 256, 256, 256, 1024, 256, 1024, 256 };
    int Ns[9] = { 512, 512, 256, 256, 256, 256, 1024, 256, 256 };
    int trs[9] = { 1, 1, 1, 1, 1, 1, 1, 1, 0 };
    int cum = 0;
    for (int i = 0; i < 9; ++i) {
        ta.s[i] = srcs[i]; ta.d[i] = dsts[i]; ta.K[i] = Ks[i]; ta.N[i] = Ns[i]; ta.tr[i] = trs[i];
        ta.beg[i] = cum; cum += (Ks[i] * Ns[i]) / 256;
    }
    ta.beg[9] = cum; cum += NB * DD / 4 / 256;     // xb job: 4096 blocks
    ta.beg[10] = cum;
    ta.xsrc = X; ta.maskp = maskp; ta.xdst = Xb;
    transpose_all<<<cum, 256, 0, stream>>>(ta);

    // 2. Wc1T = WeT1 @ WoutL  (==(Wout1@We1)^T)
    gemm_kernel<<<dim3(2, 2), 256, 0, stream>>>(
        WeT1, WeT1, 1 << 30, WoutL, WoutL, WoutL, 1 << 30, 1 << 30,
        (void*)Wc1T, nullptr, 256, 256, 2);

    // 3. CSR (+ri-composed lists)
    csr_kernel<<<NB / 4, 256, 0, stream>>>(Adj, ri[0], ri[1], ri[2], csr4, cnt, deg);

    // 4. Win GEMM, gathered Xb A-staging -> planar z/g bf16
    gemm_win_kernel<<<dim3(NRT / 128, 512 / 128), 256, 0, stream>>>(
        Xb, si[0], si[1], si[2], WinT1, WinT, zbuf, gbuf);

    // 5-6. batched scan (2 dims/thread; combine folded into apply) -> U4
    scan_carry_kernel<<<NBR * BB * NCH, 128, 0, stream>>>(zbuf, gm1_alog, gm_alog, carry);
    scan_apply_kernel<<<NBR * BB * NCH, 128, 0, stream>>>(zbuf, gbuf, gm1_alog, gm_alog, carry, U4);

    // 7. combined GEMM: rows [0,4NB) from U4, [4NB,5NB) from Xb -> V5
    gemm_kernel<<<dim3(5 * NB / 128, 2), 256, 0, stream>>>(
        U4, Xb, 4 * NB, Wc1T, WoutT, WeT, 3 * NB, 4 * NB,
        (void*)V5, nullptr, 256, 256, 2);

    // 8. fused aggregation (relu + mask + br3 mamba add) -> Yin slots
    agg4_kernel<<<NRT / 8, 256, 0, stream>>>(V5, csr4, cnt, deg, maskp, Yin);

    // 9. Wv GEMM split-K2: [NB,1024]@[1024,256] -> tmpYa + tmpYb (bf16)
    gemm_splitk2_kernel<<<dim3(NB / 128, 2, 2), 256, 0, stream>>>(Yin, WvT, tmpYa, tmpYb);

    // 10. LN1 (+bv fold, +partial-sum add, +X residual), wave-per-row
    ln1_kernel<<<NB / 4, 256, 0, stream>>>(tmpYa, tmpYb, bv, X, ln1_g, ln1_b, X1f, X1b);

    // 11. FFN1: [NB,256] @ [256,1024] +b1, relu -> H bf16
    gemm_kernel<<<dim3(NB / 128, 8), 256, 0, stream>>>(
        X1b, X1b, 1 << 30, W1T, W1T, W1T, 1 << 30, 1 << 30,
        (void*)H, ffn_b1, 1024, 256, 1);

    // 12. FFN2 split-K2: [NB,1024]@[1024,256] -> tmpY2a + tmpY2b (bf16)
    gemm_splitk2_kernel<<<dim3(NB / 128, 2, 2), 256, 0, stream>>>(H, W2T, tmpY2a, tmpY2b);

    // 13. LN2 (+b2 fold, +partial-sum add, +X1 residual) -> Out f32
    ln2_kernel<<<NB / 4, 256, 0, stream>>>(tmpY2a, tmpY2b, ffn_b2, X1f, ln2_g, ln2_b, Out);
}